// Round 1
// baseline (1236.386 us; speedup 1.0000x reference)
//
#include <hip/hip_runtime.h>
#include <math.h>

// ---- problem constants ----
#define BN    28800      // B*N tokens total
#define CC    256        // channels
#define HIDN  1024       // MLP hidden
#define WINS  512        // total windows (8 frames * 64)
#define LW    64         // tokens per window
#define WROWS (WINS*LW)  // 32768 window rows
#define NHD   8          // heads
#define HDD   32         // head dim
#define ATT_SCALE 0.17676766953f

// corrected scale = 32^-0.5
#undef ATT_SCALE
#define ATT_SCALE 0.1767766952966369f

// ---------------- LayerNorm: one 64-lane wave per token ----------------
__global__ void ln_kernel(const float* __restrict__ x, const float* __restrict__ w,
                          const float* __restrict__ b, float* __restrict__ out, int ntok) {
    int tok  = (int)((blockIdx.x * blockDim.x + threadIdx.x) >> 6);
    int lane = threadIdx.x & 63;
    if (tok >= ntok) return;
    float4 v = reinterpret_cast<const float4*>(x + (size_t)tok * CC)[lane];
    float s  = v.x + v.y + v.z + v.w;
    float s2 = v.x*v.x + v.y*v.y + v.z*v.z + v.w*v.w;
#pragma unroll
    for (int off = 32; off >= 1; off >>= 1) {
        s  += __shfl_xor(s, off);
        s2 += __shfl_xor(s2, off);
    }
    float mean = s * (1.0f / CC);
    float var  = s2 * (1.0f / CC) - mean * mean;
    float rs   = rsqrtf(var + 1e-5f);
    float4 wv = reinterpret_cast<const float4*>(w)[lane];
    float4 bv = reinterpret_cast<const float4*>(b)[lane];
    float4 o;
    o.x = (v.x - mean) * rs * wv.x + bv.x;
    o.y = (v.y - mean) * rs * wv.y + bv.y;
    o.z = (v.z - mean) * rs * wv.z + bv.z;
    o.w = (v.w - mean) * rs * wv.w + bv.w;
    reinterpret_cast<float4*>(out + (size_t)tok * CC)[lane] = o;
}

// ---------------- window gather: roll(-4,-4) + pad to 64x64 + partition ----------------
// dst[win*64 + l, c] ; win = f*64 + wih*8 + wiw ; l = r*8 + s ; pad rows -> 0
__global__ void gather_win(const float* __restrict__ src, float* __restrict__ dst) {
    int row  = (int)((blockIdx.x * blockDim.x + threadIdx.x) >> 6);
    int lane = threadIdx.x & 63;
    if (row >= WROWS) return;
    int win = row >> 6, l = row & 63;
    int f   = win >> 6;               // frame = b*4 + t
    int wih = (win >> 3) & 7, wiw = win & 7;
    int r = l >> 3, s = l & 7;
    int h = wih * 8 + r, w = wiw * 8 + s;
    float4 val = make_float4(0.f, 0.f, 0.f, 0.f);
    if (h < 60 && w < 60) {
        int oh = (h + 4) % 60;        // roll by -SHIFT
        int ow = (w + 4) % 60;
        size_t tok = (size_t)f * 3600 + (size_t)oh * 60 + ow;
        val = reinterpret_cast<const float4*>(src + tok * CC)[lane];
    }
    reinterpret_cast<float4*>(dst + (size_t)row * CC)[lane] = val;
}

// ---------------- fp32 GEMM: out[M,N] = A[M,K] @ W[N,K]^T + bias, optional exact GELU ----------------
template <bool GELU>
__global__ __launch_bounds__(256) void gemm_tn(const float* __restrict__ A, const float* __restrict__ W,
                                               const float* __restrict__ bias, float* __restrict__ out,
                                               int M, int Nn, int K) {
    __shared__ float As[16][68];
    __shared__ float Ws[16][68];
    const int m0 = blockIdx.x * 64, n0 = blockIdx.y * 64;
    const int t = threadIdx.x;
    const int tm = t >> 4, tn = t & 15;
    const int lrow = t >> 2, lkq = (t & 3) * 4;
    float acc[4][4] = {{0.f}};
    const float* Ap = A + (size_t)(m0 + lrow) * K + lkq;
    const float* Wp = W + (size_t)(n0 + lrow) * K + lkq;
    for (int k0 = 0; k0 < K; k0 += 16) {
        float4 av = *reinterpret_cast<const float4*>(Ap + k0);
        float4 wv = *reinterpret_cast<const float4*>(Wp + k0);
        __syncthreads();
        As[lkq + 0][lrow] = av.x; As[lkq + 1][lrow] = av.y;
        As[lkq + 2][lrow] = av.z; As[lkq + 3][lrow] = av.w;
        Ws[lkq + 0][lrow] = wv.x; Ws[lkq + 1][lrow] = wv.y;
        Ws[lkq + 2][lrow] = wv.z; Ws[lkq + 3][lrow] = wv.w;
        __syncthreads();
#pragma unroll
        for (int kk = 0; kk < 16; ++kk) {
            float4 a4 = *reinterpret_cast<const float4*>(&As[kk][tm * 4]);
            float4 b4 = *reinterpret_cast<const float4*>(&Ws[kk][tn * 4]);
            float av_[4] = {a4.x, a4.y, a4.z, a4.w};
            float bv_[4] = {b4.x, b4.y, b4.z, b4.w};
#pragma unroll
            for (int i = 0; i < 4; ++i)
#pragma unroll
                for (int j = 0; j < 4; ++j)
                    acc[i][j] = fmaf(av_[i], bv_[j], acc[i][j]);
        }
    }
#pragma unroll
    for (int i = 0; i < 4; ++i) {
        int m = m0 + tm * 4 + i;
#pragma unroll
        for (int j = 0; j < 4; ++j) {
            int n = n0 + tn * 4 + j;
            float c = acc[i][j] + bias[n];
            if (GELU) c = 0.5f * c * (1.0f + erff(c * 0.7071067811865475f));
            out[(size_t)m * Nn + n] = c;
        }
    }
}

// ---------------- attention per (window, head): block = 64 threads ----------------
__global__ __launch_bounds__(64) void attn_kernel(const float* __restrict__ Q, const float* __restrict__ Kin,
                                                  const float* __restrict__ Vin, const float* __restrict__ btab,
                                                  float* __restrict__ AO) {
    const int win = blockIdx.x >> 3;
    const int h   = blockIdx.x & 7;
    const int i   = threadIdx.x;
    __shared__ float Ks[64][32];
    __shared__ float Vs[64][32];
    __shared__ float Ss[64][65];
    __shared__ float bi[225];
    const size_t base = (size_t)win * 64 * CC + (size_t)h * HDD;
#pragma unroll
    for (int it = 0; it < 8; ++it) {
        int idx = it * 64 + i;        // 0..511
        int r = idx >> 3, dq = idx & 7;
        float4 kv = reinterpret_cast<const float4*>(Kin + base + (size_t)r * CC)[dq];
        float4 vv = reinterpret_cast<const float4*>(Vin + base + (size_t)r * CC)[dq];
        reinterpret_cast<float4*>(&Ks[r][0])[dq] = kv;
        reinterpret_cast<float4*>(&Vs[r][0])[dq] = vv;
    }
    for (int idx = i; idx < 225; idx += 64) bi[idx] = btab[idx * NHD + h];
    __syncthreads();
    float4 q4[8];
#pragma unroll
    for (int dq = 0; dq < 8; ++dq)
        q4[dq] = reinterpret_cast<const float4*>(Q + base + (size_t)i * CC)[dq];
    const int wih = (win >> 3) & 7, wiw = win & 7;
    const int ri = i >> 3, si = i & 7;
    for (int j = 0; j < 64; ++j) {
        int rj = j >> 3, sj = j & 7;
        bool masked = (wih * 8 + rj >= 60) || (wiw * 8 + sj >= 60);
        float s = 0.f;
#pragma unroll
        for (int dq = 0; dq < 8; ++dq) {
            float4 kv = reinterpret_cast<const float4*>(&Ks[j][0])[dq];
            s += q4[dq].x * kv.x + q4[dq].y * kv.y + q4[dq].z * kv.z + q4[dq].w * kv.w;
        }
        s = s * ATT_SCALE + bi[(ri - rj + 7) * 15 + (si - sj + 7)];
        Ss[i][j] = masked ? -1e30f : s;
    }
    float m = -1e30f;
    for (int j = 0; j < 64; ++j) m = fmaxf(m, Ss[i][j]);
    float sum = 0.f;
    for (int j = 0; j < 64; ++j) {
        float p = __expf(Ss[i][j] - m);
        Ss[i][j] = p;
        sum += p;
    }
    float rinv = 1.0f / sum;
    float acc[HDD];
#pragma unroll
    for (int d = 0; d < HDD; ++d) acc[d] = 0.f;
    for (int j = 0; j < 64; ++j) {
        float p = Ss[i][j];
#pragma unroll
        for (int d = 0; d < HDD; ++d) acc[d] = fmaf(p, Vs[j][d], acc[d]);
    }
#pragma unroll
    for (int dq = 0; dq < 8; ++dq) {
        float4 o = make_float4(acc[dq*4+0] * rinv, acc[dq*4+1] * rinv,
                               acc[dq*4+2] * rinv, acc[dq*4+3] * rinv);
        reinterpret_cast<float4*>(AO + base + (size_t)i * CC)[dq] = o;
    }
}

// ---------------- residual add with inverse-window gather ----------------
__global__ void add_win_kernel(const float* __restrict__ xin, const float* __restrict__ OP,
                               const float* __restrict__ gamma, float* __restrict__ xout) {
    int tok  = (int)((blockIdx.x * blockDim.x + threadIdx.x) >> 6);
    int lane = threadIdx.x & 63;
    if (tok >= BN) return;
    int f  = tok / 3600;
    int p  = tok % 3600;
    int hi = p / 60, wi = p % 60;
    int hp = (hi + 56) % 60, wp = (wi + 56) % 60;   // inverse roll (+SHIFT at the end)
    int wih = hp >> 3, r = hp & 7, wiw = wp >> 3, s = wp & 7;
    size_t row = ((size_t)f * 64 + (size_t)(wih * 8 + wiw)) * 64 + (size_t)(r * 8 + s);
    float g = gamma[0];
    float4 a = reinterpret_cast<const float4*>(xin + (size_t)tok * CC)[lane];
    float4 o = reinterpret_cast<const float4*>(OP + row * CC)[lane];
    float4 y = make_float4(a.x + g * o.x, a.y + g * o.y, a.z + g * o.z, a.w + g * o.w);
    reinterpret_cast<float4*>(xout + (size_t)tok * CC)[lane] = y;
}

__global__ void add_plain_kernel(const float* __restrict__ xin, const float* __restrict__ hh,
                                 const float* __restrict__ gamma, float* __restrict__ xout, int nvec4) {
    int idx = (int)(blockIdx.x * blockDim.x + threadIdx.x);
    if (idx >= nvec4) return;
    float g = gamma[0];
    float4 a = reinterpret_cast<const float4*>(xin)[idx];
    float4 o = reinterpret_cast<const float4*>(hh)[idx];
    reinterpret_cast<float4*>(xout)[idx] =
        make_float4(a.x + g * o.x, a.y + g * o.y, a.z + g * o.z, a.w + g * o.w);
}

extern "C" void kernel_launch(void* const* d_in, const int* in_sizes, int n_in,
                              void* d_out, int out_size, void* d_ws, size_t ws_size,
                              hipStream_t stream) {
    const float* x    = (const float*)d_in[0];
    const float* ctx  = (const float*)d_in[1];
    const float* ln1w = (const float*)d_in[2];
    const float* ln1b = (const float*)d_in[3];
    const float* ln2w = (const float*)d_in[4];
    const float* ln2b = (const float*)d_in[5];
    const float* ln3w = (const float*)d_in[6];
    const float* ln3b = (const float*)d_in[7];
    const float* lncw = (const float*)d_in[8];
    const float* lncb = (const float*)d_in[9];
    const float* saqw = (const float*)d_in[10];
    const float* saqb = (const float*)d_in[11];
    const float* sakw = (const float*)d_in[12];
    const float* sakb = (const float*)d_in[13];
    const float* savw = (const float*)d_in[14];
    const float* savb = (const float*)d_in[15];
    const float* saow = (const float*)d_in[16];
    const float* saob = (const float*)d_in[17];
    const float* sabias = (const float*)d_in[18];
    const float* caqw = (const float*)d_in[19];
    const float* caqb = (const float*)d_in[20];
    const float* cakw = (const float*)d_in[21];
    const float* cakb = (const float*)d_in[22];
    const float* cavw = (const float*)d_in[23];
    const float* cavb = (const float*)d_in[24];
    const float* caow = (const float*)d_in[25];
    const float* caob = (const float*)d_in[26];
    const float* cabias = (const float*)d_in[27];
    const float* gamma1 = (const float*)d_in[28];
    const float* gamma2 = (const float*)d_in[29];
    const float* gammam = (const float*)d_in[30];
    const float* mw1 = (const float*)d_in[31];
    const float* mb1 = (const float*)d_in[32];
    const float* mw2 = (const float*)d_in[33];
    const float* mb2 = (const float*)d_in[34];

    float* ws = (float*)d_ws;
    float* LNb = ws;                        // 7,372,800
    float* X1  = ws + 7372800;              // 7,372,800
    float* G0  = ws + 14745600;             // 8,388,608
    float* G1  = G0 + 8388608;
    float* Qb  = G1 + 8388608;
    float* Kb  = Qb + 8388608;
    float* Vb  = Kb + 8388608;              // ends at 48,300,032
    float* AO  = G0;                        // alias (gathered q-src dead after proj)
    float* OPb = G1;                        // alias (gathered kv-src dead after proj)
    float* H1  = G0;                        // alias region G0..K (29,491,200 floats)
    float* H2  = ws + 48300032;             // 7,372,800 ; total 55,672,832 floats

    float* OUT = (float*)d_out;

    dim3 blk(256);
    dim3 gLN(BN / 4);
    dim3 gGather(WROWS / 4);
    dim3 gProj(WROWS / 64, CC / 64);
    dim3 gAttn(WINS * NHD);

    // ---- self attention ----
    ln_kernel<<<gLN, blk, 0, stream>>>(x, ln1w, ln1b, LNb, BN);
    gather_win<<<gGather, blk, 0, stream>>>(LNb, G0);
    gemm_tn<false><<<gProj, blk, 0, stream>>>(G0, saqw, saqb, Qb, WROWS, CC, CC);
    gemm_tn<false><<<gProj, blk, 0, stream>>>(G0, sakw, sakb, Kb, WROWS, CC, CC);
    gemm_tn<false><<<gProj, blk, 0, stream>>>(G0, savw, savb, Vb, WROWS, CC, CC);
    attn_kernel<<<gAttn, dim3(64), 0, stream>>>(Qb, Kb, Vb, sabias, AO);
    gemm_tn<false><<<gProj, blk, 0, stream>>>(AO, saow, saob, OPb, WROWS, CC, CC);
    add_win_kernel<<<gLN, blk, 0, stream>>>(x, OPb, gamma1, X1);

    // ---- cross attention ----
    ln_kernel<<<gLN, blk, 0, stream>>>(X1, ln2w, ln2b, LNb, BN);
    gather_win<<<gGather, blk, 0, stream>>>(LNb, G0);
    ln_kernel<<<gLN, blk, 0, stream>>>(ctx, lncw, lncb, LNb, BN);
    gather_win<<<gGather, blk, 0, stream>>>(LNb, G1);
    gemm_tn<false><<<gProj, blk, 0, stream>>>(G0, caqw, caqb, Qb, WROWS, CC, CC);
    gemm_tn<false><<<gProj, blk, 0, stream>>>(G1, cakw, cakb, Kb, WROWS, CC, CC);
    gemm_tn<false><<<gProj, blk, 0, stream>>>(G1, cavw, cavb, Vb, WROWS, CC, CC);
    attn_kernel<<<gAttn, dim3(64), 0, stream>>>(Qb, Kb, Vb, cabias, AO);
    gemm_tn<false><<<gProj, blk, 0, stream>>>(AO, caow, caob, OPb, WROWS, CC, CC);
    add_win_kernel<<<gLN, blk, 0, stream>>>(X1, OPb, gamma2, X1);

    // ---- MLP ----
    ln_kernel<<<gLN, blk, 0, stream>>>(X1, ln3w, ln3b, LNb, BN);
    gemm_tn<true><<<dim3(BN / 64, HIDN / 64), blk, 0, stream>>>(LNb, mw1, mb1, H1, BN, HIDN, CC);
    gemm_tn<false><<<dim3(BN / 64, CC / 64), blk, 0, stream>>>(H1, mw2, mb2, H2, BN, CC, HIDN);
    add_plain_kernel<<<dim3(BN * CC / 4 / 256), blk, 0, stream>>>(X1, H2, gammam, OUT, BN * CC / 4);
}

// Round 2
// 576.959 us; speedup vs baseline: 2.1429x; 2.1429x over previous
//
#include <hip/hip_runtime.h>
#include <math.h>

// ---- problem constants ----
#define BN    28800      // B*N tokens total
#define CC    256        // channels
#define HIDN  1024       // MLP hidden
#define WINS  512        // total windows (8 frames * 64)
#define WROWS (WINS*64)  // 32768 window rows
#define ATT_SCALE 0.1767766952966369f

typedef __bf16 bf16x8 __attribute__((ext_vector_type(8)));
typedef float  f32x4  __attribute__((ext_vector_type(4)));

__device__ __forceinline__ unsigned short f2bf(float f) {
    unsigned u = __float_as_uint(f);
    unsigned r = (u + 0x7FFFu + ((u >> 16) & 1u)) >> 16;
    return (unsigned short)r;
}

__device__ __forceinline__ void gl_lds16(const void* g, void* l) {
    __builtin_amdgcn_global_load_lds(
        (const __attribute__((address_space(1))) void*)g,
        (__attribute__((address_space(3))) void*)l, 16, 0, 0);
}

// ---------------- LayerNorm: one 64-lane wave per token, bf16 out ----------------
__global__ void ln_kernel(const float* __restrict__ x, const float* __restrict__ w,
                          const float* __restrict__ b, unsigned short* __restrict__ out, int ntok) {
    int tok  = (int)((blockIdx.x * blockDim.x + threadIdx.x) >> 6);
    int lane = threadIdx.x & 63;
    if (tok >= ntok) return;
    float4 v = reinterpret_cast<const float4*>(x + (size_t)tok * CC)[lane];
    float s  = v.x + v.y + v.z + v.w;
    float s2 = v.x*v.x + v.y*v.y + v.z*v.z + v.w*v.w;
#pragma unroll
    for (int off = 32; off >= 1; off >>= 1) {
        s  += __shfl_xor(s, off);
        s2 += __shfl_xor(s2, off);
    }
    float mean = s * (1.0f / CC);
    float var  = s2 * (1.0f / CC) - mean * mean;
    float rs   = rsqrtf(var + 1e-5f);
    float4 wv = reinterpret_cast<const float4*>(w)[lane];
    float4 bv = reinterpret_cast<const float4*>(b)[lane];
    ushort4 o;
    o.x = f2bf((v.x - mean) * rs * wv.x + bv.x);
    o.y = f2bf((v.y - mean) * rs * wv.y + bv.y);
    o.z = f2bf((v.z - mean) * rs * wv.z + bv.z);
    o.w = f2bf((v.w - mean) * rs * wv.w + bv.w);
    reinterpret_cast<ushort4*>(out + (size_t)tok * CC)[lane] = o;
}

// ---------------- window gather (bf16): roll(-4,-4) + pad + partition ----------------
__global__ void gather_win(const unsigned short* __restrict__ src, unsigned short* __restrict__ dst) {
    int row  = (int)((blockIdx.x * blockDim.x + threadIdx.x) >> 6);
    int lane = threadIdx.x & 63;
    if (row >= WROWS) return;
    int win = row >> 6, l = row & 63;
    int f   = win >> 6;
    int wih = (win >> 3) & 7, wiw = win & 7;
    int r = l >> 3, s = l & 7;
    int h = wih * 8 + r, w = wiw * 8 + s;
    ushort4 val = {0, 0, 0, 0};
    if (h < 60 && w < 60) {
        int oh = (h + 4) % 60;
        int ow = (w + 4) % 60;
        size_t tok = (size_t)f * 3600 + (size_t)oh * 60 + ow;
        val = reinterpret_cast<const ushort4*>(src + tok * CC)[lane];
    }
    reinterpret_cast<ushort4*>(dst + (size_t)row * CC)[lane] = val;
}

// ---------------- bf16 MFMA GEMM: out[M,N] = A[M,K] @ W[N,K]^T + bias ----------------
// 128x128 tile, BK=32, 4 waves, 4x4 16x16x32 fragments per wave.
// LDS layout: row-major [128][32] bf16 (64B rows), phys kchunk gp = g ^ ((row>>1)&3)
// (swizzle applied on the *global source* address since global_load_lds dest is linear).
template <bool GELU, bool OUTBF>
__global__ __launch_bounds__(256) void gemm_bf16(const unsigned short* __restrict__ A,
        const unsigned short* __restrict__ W, const float* __restrict__ bias,
        void* __restrict__ outv, int M, int Nn, int K) {
    __shared__ __align__(16) unsigned short As[128 * 32];
    __shared__ __align__(16) unsigned short Ws[128 * 32];
    const int t = threadIdx.x;
    const int w = t >> 6, l = t & 63;
    const int m0 = blockIdx.x * 128, n0 = blockIdx.y * 128;
    const int wr = w >> 1, wc = w & 1;
    const int r = l & 15, g = l >> 4;
    const int sw = (r >> 1) & 3;          // read-side swizzle key
    const int gp = (g ^ sw) * 8;          // phys kchunk offset in ushorts
    f32x4 acc[4][4];
#pragma unroll
    for (int i = 0; i < 4; ++i)
#pragma unroll
        for (int j = 0; j < 4; ++j) { acc[i][j][0]=0.f; acc[i][j][1]=0.f; acc[i][j][2]=0.f; acc[i][j][3]=0.f; }

    for (int k0 = 0; k0 < K; k0 += 32) {
        __syncthreads();
#pragma unroll
        for (int p = 0; p < 2; ++p) {
            int c   = p * 256 + t;
            int row = c >> 2;
            int gl  = (c & 3) ^ ((row >> 1) & 3);   // logical kchunk stored at this phys slot
            gl_lds16(A + (size_t)(m0 + row) * K + k0 + gl * 8,
                     (char*)As + (p * 256 + w * 64) * 16);
            gl_lds16(W + (size_t)(n0 + row) * K + k0 + gl * 8,
                     (char*)Ws + (p * 256 + w * 64) * 16);
        }
        __syncthreads();
        bf16x8 af[4], bw[4];
#pragma unroll
        for (int m = 0; m < 4; ++m)
            af[m] = *reinterpret_cast<const bf16x8*>(&As[(wr * 64 + m * 16 + r) * 32 + gp]);
#pragma unroll
        for (int n = 0; n < 4; ++n)
            bw[n] = *reinterpret_cast<const bf16x8*>(&Ws[(wc * 64 + n * 16 + r) * 32 + gp]);
#pragma unroll
        for (int m = 0; m < 4; ++m)
#pragma unroll
            for (int n = 0; n < 4; ++n)
                acc[m][n] = __builtin_amdgcn_mfma_f32_16x16x32_bf16(af[m], bw[n], acc[m][n], 0, 0, 0);
    }
#pragma unroll
    for (int m = 0; m < 4; ++m) {
#pragma unroll
        for (int n = 0; n < 4; ++n) {
            int col = n0 + wc * 64 + n * 16 + r;
            float bb = bias[col];
#pragma unroll
            for (int j = 0; j < 4; ++j) {
                int rowg = m0 + wr * 64 + m * 16 + g * 4 + j;
                float cv = acc[m][n][j] + bb;
                if (GELU) cv = 0.5f * cv * (1.0f + erff(cv * 0.70710678118654752f));
                if (OUTBF) ((unsigned short*)outv)[(size_t)rowg * Nn + col] = f2bf(cv);
                else       ((float*)outv)[(size_t)rowg * Nn + col] = cv;
            }
        }
    }
}

// ---------------- attention per (window, head): 64 threads, scores in registers ----------------
__global__ __launch_bounds__(64) void attn_kernel(const float* __restrict__ Q, const float* __restrict__ Kin,
                                                  const float* __restrict__ Vin, const float* __restrict__ btab,
                                                  unsigned short* __restrict__ AO) {
    const int win = blockIdx.x >> 3;
    const int h   = blockIdx.x & 7;
    const int i   = threadIdx.x;
    __shared__ float Ks[64][32];
    __shared__ float Vs[64][32];
    __shared__ float bi[225];
    const size_t base = (size_t)win * 64 * CC + (size_t)h * 32;
#pragma unroll
    for (int it = 0; it < 8; ++it) {
        int idx = it * 64 + i;
        int rr = idx >> 3, dq = idx & 7;
        float4 kv = reinterpret_cast<const float4*>(Kin + base + (size_t)rr * CC)[dq];
        float4 vv = reinterpret_cast<const float4*>(Vin + base + (size_t)rr * CC)[dq];
        reinterpret_cast<float4*>(&Ks[rr][0])[dq] = kv;
        reinterpret_cast<float4*>(&Vs[rr][0])[dq] = vv;
    }
    for (int idx = i; idx < 225; idx += 64) bi[idx] = btab[idx * 8 + h];
    __syncthreads();
    float4 q4[8];
#pragma unroll
    for (int dq = 0; dq < 8; ++dq)
        q4[dq] = reinterpret_cast<const float4*>(Q + base + (size_t)i * CC)[dq];
    const int wih = (win >> 3) & 7, wiw = win & 7;
    const int ri = i >> 3, si = i & 7;
    float sc[64];
#pragma unroll
    for (int j = 0; j < 64; ++j) {
        int rj = j >> 3, sj = j & 7;
        bool masked = (wih * 8 + rj >= 60) || (wiw * 8 + sj >= 60);
        float s = 0.f;
#pragma unroll
        for (int dq = 0; dq < 8; ++dq) {
            float4 kv = reinterpret_cast<const float4*>(&Ks[j][0])[dq];
            s += q4[dq].x * kv.x + q4[dq].y * kv.y + q4[dq].z * kv.z + q4[dq].w * kv.w;
        }
        sc[j] = masked ? -1e30f : (s * ATT_SCALE + bi[(ri - rj + 7) * 15 + (si - sj + 7)]);
    }
    float mx = -1e30f;
#pragma unroll
    for (int j = 0; j < 64; ++j) mx = fmaxf(mx, sc[j]);
    float sum = 0.f;
#pragma unroll
    for (int j = 0; j < 64; ++j) { float p = __expf(sc[j] - mx); sc[j] = p; sum += p; }
    float rinv = 1.0f / sum;
    float acc[32];
#pragma unroll
    for (int d = 0; d < 32; ++d) acc[d] = 0.f;
#pragma unroll
    for (int j = 0; j < 64; ++j) {
        float p = sc[j];
#pragma unroll
        for (int d = 0; d < 32; ++d) acc[d] = fmaf(p, Vs[j][d], acc[d]);
    }
#pragma unroll
    for (int dq = 0; dq < 8; ++dq) {
        ushort4 o;
        o.x = f2bf(acc[dq*4+0] * rinv); o.y = f2bf(acc[dq*4+1] * rinv);
        o.z = f2bf(acc[dq*4+2] * rinv); o.w = f2bf(acc[dq*4+3] * rinv);
        *reinterpret_cast<ushort4*>(AO + base + (size_t)i * CC + dq * 4) = o;
    }
}

// ---------------- residual add with inverse-window gather (fp32) ----------------
__global__ void add_win_kernel(const float* __restrict__ xin, const float* __restrict__ OP,
                               const float* __restrict__ gamma, float* __restrict__ xout) {
    int tok  = (int)((blockIdx.x * blockDim.x + threadIdx.x) >> 6);
    int lane = threadIdx.x & 63;
    if (tok >= BN) return;
    int f  = tok / 3600;
    int p  = tok % 3600;
    int hi = p / 60, wi = p % 60;
    int hp = (hi + 56) % 60, wp = (wi + 56) % 60;
    int wih = hp >> 3, r = hp & 7, wiw = wp >> 3, s = wp & 7;
    size_t row = ((size_t)f * 64 + (size_t)(wih * 8 + wiw)) * 64 + (size_t)(r * 8 + s);
    float g = gamma[0];
    float4 a = reinterpret_cast<const float4*>(xin + (size_t)tok * CC)[lane];
    float4 o = reinterpret_cast<const float4*>(OP + row * CC)[lane];
    float4 y = make_float4(a.x + g * o.x, a.y + g * o.y, a.z + g * o.z, a.w + g * o.w);
    reinterpret_cast<float4*>(xout + (size_t)tok * CC)[lane] = y;
}

__global__ void add_plain_kernel(const float* __restrict__ xin, const float* __restrict__ hh,
                                 const float* __restrict__ gamma, float* __restrict__ xout, int nvec4) {
    int idx = (int)(blockIdx.x * blockDim.x + threadIdx.x);
    if (idx >= nvec4) return;
    float g = gamma[0];
    float4 a = reinterpret_cast<const float4*>(xin)[idx];
    float4 o = reinterpret_cast<const float4*>(hh)[idx];
    reinterpret_cast<float4*>(xout)[idx] =
        make_float4(a.x + g * o.x, a.y + g * o.y, a.z + g * o.z, a.w + g * o.w);
}

// ---------------- weight fp32 -> bf16 conversion (all 10 weights, one kernel) ----------------
// pool layout (elems): w0..w7 at i*65536 (8x 256x256), mw1 at 524288 (262144), mw2 at 786432 (262144)
__global__ void cvt_all(const float* s0, const float* s1, const float* s2, const float* s3,
                        const float* s4, const float* s5, const float* s6, const float* s7,
                        const float* s8, const float* s9, unsigned short* __restrict__ dst) {
    const float* srcs[10] = {s0, s1, s2, s3, s4, s5, s6, s7, s8, s9};
    int blk = blockIdx.x;
    int wi = (blk < 512) ? (blk >> 6) : (blk < 768 ? 8 : 9);
    size_t start = (wi < 8) ? (size_t)wi * 65536 : (wi == 8 ? (size_t)524288 : (size_t)786432);
    size_t gidx = (size_t)blk * 1024 + (size_t)threadIdx.x * 4;
    float4 v = *reinterpret_cast<const float4*>(srcs[wi] + (gidx - start));
    ushort4 o;
    o.x = f2bf(v.x); o.y = f2bf(v.y); o.z = f2bf(v.z); o.w = f2bf(v.w);
    *reinterpret_cast<ushort4*>(dst + gidx) = o;
}

extern "C" void kernel_launch(void* const* d_in, const int* in_sizes, int n_in,
                              void* d_out, int out_size, void* d_ws, size_t ws_size,
                              hipStream_t stream) {
    const float* x    = (const float*)d_in[0];
    const float* ctx  = (const float*)d_in[1];
    const float* ln1w = (const float*)d_in[2];
    const float* ln1b = (const float*)d_in[3];
    const float* ln2w = (const float*)d_in[4];
    const float* ln2b = (const float*)d_in[5];
    const float* ln3w = (const float*)d_in[6];
    const float* ln3b = (const float*)d_in[7];
    const float* lncw = (const float*)d_in[8];
    const float* lncb = (const float*)d_in[9];
    const float* saqw = (const float*)d_in[10];
    const float* saqb = (const float*)d_in[11];
    const float* sakw = (const float*)d_in[12];
    const float* sakb = (const float*)d_in[13];
    const float* savw = (const float*)d_in[14];
    const float* savb = (const float*)d_in[15];
    const float* saow = (const float*)d_in[16];
    const float* saob = (const float*)d_in[17];
    const float* sabias = (const float*)d_in[18];
    const float* caqw = (const float*)d_in[19];
    const float* caqb = (const float*)d_in[20];
    const float* cakw = (const float*)d_in[21];
    const float* cakb = (const float*)d_in[22];
    const float* cavw = (const float*)d_in[23];
    const float* cavb = (const float*)d_in[24];
    const float* caow = (const float*)d_in[25];
    const float* caob = (const float*)d_in[26];
    const float* cabias = (const float*)d_in[27];
    const float* gamma1 = (const float*)d_in[28];
    const float* gamma2 = (const float*)d_in[29];
    const float* gammam = (const float*)d_in[30];
    const float* mw1 = (const float*)d_in[31];
    const float* mb1 = (const float*)d_in[32];
    const float* mw2 = (const float*)d_in[33];
    const float* mb2 = (const float*)d_in[34];

    float* ws = (float*)d_ws;
    unsigned short* LNbf = (unsigned short*)(ws);                 // 28800*256 bf16 = 3,686,400 f
    unsigned short* Gq   = (unsigned short*)(ws + 3686400);       // 32768*256 bf16 = 4,194,304 f
    unsigned short* Gkv  = (unsigned short*)(ws + 7880704);       // 4,194,304 f
    float* Qb  = ws + 12075008;                                   // 8,388,608 f
    float* Kb  = ws + 20463616;                                   // 8,388,608 f
    float* Vb  = ws + 28852224;                                   // 8,388,608 f
    float* OPf = ws + 37240832;                                   // 8,388,608 f
    float* X1  = ws + 45629440;                                   // 7,372,800 f
    unsigned short* Wp = (unsigned short*)(ws + 53002240);        // 1,048,576 bf16 = 524,288 f
    unsigned short* AObf = Gq;                                    // alias: gathered q dead after projections
    unsigned short* H1bf = (unsigned short*)Qb;                   // alias: 29,491,200 bf16 fits Qb+Kb
    float* H2f = Vb;                                              // alias: V dead in MLP phase

    unsigned short* w_saq = Wp;            unsigned short* w_sak = Wp + 65536;
    unsigned short* w_sav = Wp + 131072;   unsigned short* w_sao = Wp + 196608;
    unsigned short* w_caq = Wp + 262144;   unsigned short* w_cak = Wp + 327680;
    unsigned short* w_cav = Wp + 393216;   unsigned short* w_cao = Wp + 458752;
    unsigned short* w_m1  = Wp + 524288;   unsigned short* w_m2  = Wp + 786432;

    float* OUT = (float*)d_out;

    dim3 blk(256);
    dim3 gLN(BN / 4);
    dim3 gGather(WROWS / 4);
    dim3 gProj(WROWS / 128, CC / 128);       // (256, 2)
    dim3 gAttn(WINS * 8);

    cvt_all<<<dim3(1024), blk, 0, stream>>>(saqw, sakw, savw, saow, caqw, cakw, cavw, caow, mw1, mw2, Wp);

    // ---- self attention ----
    ln_kernel<<<gLN, blk, 0, stream>>>(x, ln1w, ln1b, LNbf, BN);
    gather_win<<<gGather, blk, 0, stream>>>(LNbf, Gq);
    gemm_bf16<false,false><<<gProj, blk, 0, stream>>>(Gq, w_saq, saqb, Qb, WROWS, CC, CC);
    gemm_bf16<false,false><<<gProj, blk, 0, stream>>>(Gq, w_sak, sakb, Kb, WROWS, CC, CC);
    gemm_bf16<false,false><<<gProj, blk, 0, stream>>>(Gq, w_sav, savb, Vb, WROWS, CC, CC);
    attn_kernel<<<gAttn, dim3(64), 0, stream>>>(Qb, Kb, Vb, sabias, AObf);
    gemm_bf16<false,false><<<gProj, blk, 0, stream>>>(AObf, w_sao, saob, OPf, WROWS, CC, CC);
    add_win_kernel<<<gLN, blk, 0, stream>>>(x, OPf, gamma1, X1);

    // ---- cross attention ----
    ln_kernel<<<gLN, blk, 0, stream>>>(X1, ln2w, ln2b, LNbf, BN);
    gather_win<<<gGather, blk, 0, stream>>>(LNbf, Gq);
    ln_kernel<<<gLN, blk, 0, stream>>>(ctx, lncw, lncb, LNbf, BN);
    gather_win<<<gGather, blk, 0, stream>>>(LNbf, Gkv);
    gemm_bf16<false,false><<<gProj, blk, 0, stream>>>(Gq,  w_caq, caqb, Qb, WROWS, CC, CC);
    gemm_bf16<false,false><<<gProj, blk, 0, stream>>>(Gkv, w_cak, cakb, Kb, WROWS, CC, CC);
    gemm_bf16<false,false><<<gProj, blk, 0, stream>>>(Gkv, w_cav, cavb, Vb, WROWS, CC, CC);
    attn_kernel<<<gAttn, dim3(64), 0, stream>>>(Qb, Kb, Vb, cabias, AObf);
    gemm_bf16<false,false><<<gProj, blk, 0, stream>>>(AObf, w_cao, caob, OPf, WROWS, CC, CC);
    add_win_kernel<<<gLN, blk, 0, stream>>>(X1, OPf, gamma2, X1);

    // ---- MLP ----
    ln_kernel<<<gLN, blk, 0, stream>>>(X1, ln3w, ln3b, LNbf, BN);
    gemm_bf16<true,true><<<dim3(BN/128, HIDN/128), blk, 0, stream>>>(LNbf, w_m1, mb1, H1bf, BN, HIDN, CC);
    gemm_bf16<false,false><<<dim3(BN/128, CC/128), blk, 0, stream>>>(H1bf, w_m2, mb2, H2f, BN, CC, HIDN);
    add_plain_kernel<<<dim3(BN * CC / 4 / 256), blk, 0, stream>>>(X1, H2f, gammam, OUT, BN * CC / 4);
}

// Round 3
// 315.626 us; speedup vs baseline: 3.9172x; 1.8280x over previous
//
#include <hip/hip_runtime.h>
#include <math.h>

// ---- problem constants ----
#define BN    28800      // B*N tokens total
#define CC    256        // channels
#define HIDN  1024       // MLP hidden
#define WINS  512        // total windows (8 frames * 64)
#define WROWS (WINS*64)  // 32768 window rows
#define ATT_SCALE 0.1767766952966369f

typedef __bf16 bf16x8 __attribute__((ext_vector_type(8)));
typedef float  f32x4  __attribute__((ext_vector_type(4)));

__device__ __forceinline__ unsigned short f2bf(float f) {
    unsigned u = __float_as_uint(f);
    unsigned r = (u + 0x7FFFu + ((u >> 16) & 1u)) >> 16;
    return (unsigned short)r;
}
__device__ __forceinline__ float bf2f(unsigned short u) {
    return __uint_as_float((unsigned)u << 16);
}

__device__ __forceinline__ void gl_lds16(const void* g, void* l) {
    __builtin_amdgcn_global_load_lds(
        (const __attribute__((address_space(1))) void*)g,
        (__attribute__((address_space(3))) void*)l, 16, 0, 0);
}

// ---------------- LayerNorm: one 64-lane wave per token, bf16 out ----------------
__global__ void ln_kernel(const float* __restrict__ x, const float* __restrict__ w,
                          const float* __restrict__ b, unsigned short* __restrict__ out, int ntok) {
    int tok  = (int)((blockIdx.x * blockDim.x + threadIdx.x) >> 6);
    int lane = threadIdx.x & 63;
    if (tok >= ntok) return;
    float4 v = reinterpret_cast<const float4*>(x + (size_t)tok * CC)[lane];
    float s  = v.x + v.y + v.z + v.w;
    float s2 = v.x*v.x + v.y*v.y + v.z*v.z + v.w*v.w;
#pragma unroll
    for (int off = 32; off >= 1; off >>= 1) {
        s  += __shfl_xor(s, off);
        s2 += __shfl_xor(s2, off);
    }
    float mean = s * (1.0f / CC);
    float var  = s2 * (1.0f / CC) - mean * mean;
    float rs   = rsqrtf(var + 1e-5f);
    float4 wv = reinterpret_cast<const float4*>(w)[lane];
    float4 bv = reinterpret_cast<const float4*>(b)[lane];
    ushort4 o;
    o.x = f2bf((v.x - mean) * rs * wv.x + bv.x);
    o.y = f2bf((v.y - mean) * rs * wv.y + bv.y);
    o.z = f2bf((v.z - mean) * rs * wv.z + bv.z);
    o.w = f2bf((v.w - mean) * rs * wv.w + bv.w);
    reinterpret_cast<ushort4*>(out + (size_t)tok * CC)[lane] = o;
}

// ---------------- window gather (bf16): roll(-4,-4) + pad + partition ----------------
__global__ void gather_win(const unsigned short* __restrict__ src, unsigned short* __restrict__ dst) {
    int row  = (int)((blockIdx.x * blockDim.x + threadIdx.x) >> 6);
    int lane = threadIdx.x & 63;
    if (row >= WROWS) return;
    int win = row >> 6, l = row & 63;
    int f   = win >> 6;
    int wih = (win >> 3) & 7, wiw = win & 7;
    int r = l >> 3, s = l & 7;
    int h = wih * 8 + r, w = wiw * 8 + s;
    ushort4 val = {0, 0, 0, 0};
    if (h < 60 && w < 60) {
        int oh = (h + 4) % 60;
        int ow = (w + 4) % 60;
        size_t tok = (size_t)f * 3600 + (size_t)oh * 60 + ow;
        val = reinterpret_cast<const ushort4*>(src + tok * CC)[lane];
    }
    reinterpret_cast<ushort4*>(dst + (size_t)row * CC)[lane] = val;
}

// ---------------- bf16 MFMA GEMM: out[M,N] = A[M,K] @ W[N,K]^T + bias ----------------
// OSEL: 0 = f32 out [M][N], 1 = bf16 out [M][N], 2 = bf16 transposed out [N][32768]
template <bool GELU, int OSEL>
__global__ __launch_bounds__(256) void gemm_bf16(const unsigned short* __restrict__ A,
        const unsigned short* __restrict__ W, const float* __restrict__ bias,
        void* __restrict__ outv, int M, int Nn, int K) {
    __shared__ __align__(16) unsigned short As[128 * 32];
    __shared__ __align__(16) unsigned short Ws[128 * 32];
    const int t = threadIdx.x;
    const int w = t >> 6, l = t & 63;
    const int m0 = blockIdx.x * 128, n0 = blockIdx.y * 128;
    const int wr = w >> 1, wc = w & 1;
    const int r = l & 15, g = l >> 4;
    const int sw = (r >> 1) & 3;
    const int gp = (g ^ sw) * 8;
    f32x4 acc[4][4];
#pragma unroll
    for (int i = 0; i < 4; ++i)
#pragma unroll
        for (int j = 0; j < 4; ++j) { acc[i][j][0]=0.f; acc[i][j][1]=0.f; acc[i][j][2]=0.f; acc[i][j][3]=0.f; }

    for (int k0 = 0; k0 < K; k0 += 32) {
        __syncthreads();
#pragma unroll
        for (int p = 0; p < 2; ++p) {
            int c   = p * 256 + t;
            int row = c >> 2;
            int gl  = (c & 3) ^ ((row >> 1) & 3);
            gl_lds16(A + (size_t)(m0 + row) * K + k0 + gl * 8,
                     (char*)As + (p * 256 + w * 64) * 16);
            gl_lds16(W + (size_t)(n0 + row) * K + k0 + gl * 8,
                     (char*)Ws + (p * 256 + w * 64) * 16);
        }
        __syncthreads();
        bf16x8 af[4], bw[4];
#pragma unroll
        for (int m = 0; m < 4; ++m)
            af[m] = *reinterpret_cast<const bf16x8*>(&As[(wr * 64 + m * 16 + r) * 32 + gp]);
#pragma unroll
        for (int n = 0; n < 4; ++n)
            bw[n] = *reinterpret_cast<const bf16x8*>(&Ws[(wc * 64 + n * 16 + r) * 32 + gp]);
#pragma unroll
        for (int m = 0; m < 4; ++m)
#pragma unroll
            for (int n = 0; n < 4; ++n)
                acc[m][n] = __builtin_amdgcn_mfma_f32_16x16x32_bf16(af[m], bw[n], acc[m][n], 0, 0, 0);
    }
#pragma unroll
    for (int m = 0; m < 4; ++m) {
#pragma unroll
        for (int n = 0; n < 4; ++n) {
            int col = n0 + wc * 64 + n * 16 + r;
            float bb = bias[col];
            float cv[4];
#pragma unroll
            for (int j = 0; j < 4; ++j) {
                cv[j] = acc[m][n][j] + bb;
                if (GELU) cv[j] = 0.5f * cv[j] * (1.0f + erff(cv[j] * 0.70710678118654752f));
            }
            int rowg0 = m0 + wr * 64 + m * 16 + g * 4;
            if (OSEL == 0) {
#pragma unroll
                for (int j = 0; j < 4; ++j)
                    ((float*)outv)[(size_t)(rowg0 + j) * Nn + col] = cv[j];
            } else if (OSEL == 1) {
#pragma unroll
                for (int j = 0; j < 4; ++j)
                    ((unsigned short*)outv)[(size_t)(rowg0 + j) * Nn + col] = f2bf(cv[j]);
            } else {
                ushort4 pk;
                pk.x = f2bf(cv[0]); pk.y = f2bf(cv[1]); pk.z = f2bf(cv[2]); pk.w = f2bf(cv[3]);
                *reinterpret_cast<ushort4*>((unsigned short*)outv + (size_t)col * 32768 + rowg0) = pk;
            }
        }
    }
}

// ---------------- bias table expansion: biasx[2][8][64][64] ----------------
__global__ void expand_bias(const float* __restrict__ sa, const float* __restrict__ ca,
                            float* __restrict__ dst) {
    int e = (int)(blockIdx.x * blockDim.x + threadIdx.x);   // 0..32767
    const float* src = (e < 16384) ? sa : ca;
    int e2 = e & 16383;
    int h = e2 >> 12, ij = e2 & 4095, i = ij >> 6, j = ij & 63;
    int ri = i >> 3, si = i & 7, rj = j >> 3, sj = j & 7;
    dst[e] = src[((ri - rj + 7) * 15 + (si - sj + 7)) * 8 + h];
}

// ---------------- MFMA attention: one wave per (window, head) ----------------
// S^T = mfma(K, Q) so each lane holds full q-rows' scores; P rescaled in-reg,
// written bf16 to swizzled LDS, read back as A-frags for O = P @ V (V from VT).
__global__ __launch_bounds__(256) void attn_mfma(
        const unsigned short* __restrict__ Q,   // [32768][256] bf16
        const unsigned short* __restrict__ K,   // [32768][256] bf16
        const unsigned short* __restrict__ VT,  // [256][32768] bf16
        const float* __restrict__ biasx,        // [8][64][64] f32
        unsigned short* __restrict__ AO) {      // [32768][256] bf16
    __shared__ __align__(16) unsigned short Pl[4][64 * 64];
    const int t = threadIdx.x;
    const int w = t >> 6, l = t & 63;
    const int win = blockIdx.x >> 1;
    const int h   = (blockIdx.x & 1) * 4 + w;
    const int c = l & 15, g = l >> 4;
    const int wih = (win >> 3) & 7, wiw = win & 7;
    const size_t qkbase = (size_t)win * 64 * CC + (size_t)h * 32;

    // ---- QK^T (swapped): S^T[j][i], A = K rows, B = Q rows ----
    bf16x8 ka[4], qb[4];
#pragma unroll
    for (int mj = 0; mj < 4; ++mj)
        ka[mj] = *reinterpret_cast<const bf16x8*>(K + qkbase + (size_t)(mj * 16 + c) * CC + g * 8);
#pragma unroll
    for (int ni = 0; ni < 4; ++ni)
        qb[ni] = *reinterpret_cast<const bf16x8*>(Q + qkbase + (size_t)(ni * 16 + c) * CC + g * 8);
    f32x4 s[4][4];
#pragma unroll
    for (int mj = 0; mj < 4; ++mj)
#pragma unroll
        for (int ni = 0; ni < 4; ++ni) { s[mj][ni][0]=0.f; s[mj][ni][1]=0.f; s[mj][ni][2]=0.f; s[mj][ni][3]=0.f; }
#pragma unroll
    for (int mj = 0; mj < 4; ++mj)
#pragma unroll
        for (int ni = 0; ni < 4; ++ni)
            s[mj][ni] = __builtin_amdgcn_mfma_f32_16x16x32_bf16(ka[mj], qb[ni], s[mj][ni], 0, 0, 0);

    // ---- scale + bias + mask ----
    const float* bx = biasx + h * 4096;
    const bool modd = (wiw == 7) && (g & 1);          // sj >= 4
#pragma unroll
    for (int mj = 0; mj < 4; ++mj) {
        const bool mmj = (wih == 7) && (mj >= 2);     // rj >= 4
#pragma unroll
        for (int ni = 0; ni < 4; ++ni) {
            float4 b4 = *reinterpret_cast<const float4*>(bx + (ni * 16 + c) * 64 + mj * 16 + g * 4);
            const float bb[4] = {b4.x, b4.y, b4.z, b4.w};
#pragma unroll
            for (int jj = 0; jj < 4; ++jj) {
                float v = s[mj][ni][jj] * ATT_SCALE + bb[jj];
                s[mj][ni][jj] = (mmj || modd) ? -1e30f : v;
            }
        }
    }

    // ---- softmax per q-row (rows i = ni*16 + c; reduce in-lane + shfl 16/32) ----
#pragma unroll
    for (int ni = 0; ni < 4; ++ni) {
        float mx = -1e30f;
#pragma unroll
        for (int mj = 0; mj < 4; ++mj)
#pragma unroll
            for (int jj = 0; jj < 4; ++jj) mx = fmaxf(mx, s[mj][ni][jj]);
        mx = fmaxf(mx, __shfl_xor(mx, 16));
        mx = fmaxf(mx, __shfl_xor(mx, 32));
        float sum = 0.f;
#pragma unroll
        for (int mj = 0; mj < 4; ++mj)
#pragma unroll
            for (int jj = 0; jj < 4; ++jj) {
                float p = __expf(s[mj][ni][jj] - mx);
                s[mj][ni][jj] = p;
                sum += p;
            }
        sum += __shfl_xor(sum, 16);
        sum += __shfl_xor(sum, 32);
        float rinv = 1.0f / sum;
        // pack P rows i, scaled by rinv, into swizzled LDS
        const int i  = ni * 16 + c;
        const int ik = i & 7;
#pragma unroll
        for (int mj = 0; mj < 4; ++mj) {
            ushort4 pk;
            pk.x = f2bf(s[mj][ni][0] * rinv);
            pk.y = f2bf(s[mj][ni][1] * rinv);
            pk.z = f2bf(s[mj][ni][2] * rinv);
            pk.w = f2bf(s[mj][ni][3] * rinv);
            int chunk = (mj * 2 + (g >> 1)) ^ ik;
            *reinterpret_cast<ushort4*>((char*)&Pl[w][0] + i * 128 + chunk * 16 + (g & 1) * 8) = pk;
        }
    }

    // ---- O = P @ V : A = P from LDS, B = V via VT direct global ----
    bf16x8 vb[2][2];
#pragma unroll
    for (int nd = 0; nd < 2; ++nd)
#pragma unroll
        for (int kt = 0; kt < 2; ++kt)
            vb[nd][kt] = *reinterpret_cast<const bf16x8*>(
                VT + (size_t)(h * 32 + nd * 16 + c) * 32768 + win * 64 + kt * 32 + g * 8);
    f32x4 o[4][2];
#pragma unroll
    for (int mi = 0; mi < 4; ++mi)
#pragma unroll
        for (int nd = 0; nd < 2; ++nd) { o[mi][nd][0]=0.f; o[mi][nd][1]=0.f; o[mi][nd][2]=0.f; o[mi][nd][3]=0.f; }
#pragma unroll
    for (int mi = 0; mi < 4; ++mi) {
        const int i  = mi * 16 + c;
        const int ik = i & 7;
#pragma unroll
        for (int kt = 0; kt < 2; ++kt) {
            int chunk = (kt * 4 + g) ^ ik;
            bf16x8 pa = *reinterpret_cast<const bf16x8*>((char*)&Pl[w][0] + i * 128 + chunk * 16);
#pragma unroll
            for (int nd = 0; nd < 2; ++nd)
                o[mi][nd] = __builtin_amdgcn_mfma_f32_16x16x32_bf16(pa, vb[nd][kt], o[mi][nd], 0, 0, 0);
        }
    }

    // ---- store O (bf16, [token][256]) ----
    unsigned short* aop = AO + qkbase;
#pragma unroll
    for (int mi = 0; mi < 4; ++mi)
#pragma unroll
        for (int nd = 0; nd < 2; ++nd)
#pragma unroll
            for (int jj = 0; jj < 4; ++jj)
                aop[(size_t)(mi * 16 + g * 4 + jj) * CC + nd * 16 + c] = f2bf(o[mi][nd][jj]);
}

// ---------------- residual add with inverse-window gather (bf16 delta) ----------------
__global__ void add_win_kernel(const float* __restrict__ xin, const unsigned short* __restrict__ OP,
                               const float* __restrict__ gamma, float* __restrict__ xout) {
    int tok  = (int)((blockIdx.x * blockDim.x + threadIdx.x) >> 6);
    int lane = threadIdx.x & 63;
    if (tok >= BN) return;
    int f  = tok / 3600;
    int p  = tok % 3600;
    int hi = p / 60, wi = p % 60;
    int hp = (hi + 56) % 60, wp = (wi + 56) % 60;
    int wih = hp >> 3, r = hp & 7, wiw = wp >> 3, s = wp & 7;
    size_t row = ((size_t)f * 64 + (size_t)(wih * 8 + wiw)) * 64 + (size_t)(r * 8 + s);
    float g = gamma[0];
    float4 a = reinterpret_cast<const float4*>(xin + (size_t)tok * CC)[lane];
    ushort4 ov = reinterpret_cast<const ushort4*>(OP + row * CC)[lane];
    float4 y = make_float4(a.x + g * bf2f(ov.x), a.y + g * bf2f(ov.y),
                           a.z + g * bf2f(ov.z), a.w + g * bf2f(ov.w));
    reinterpret_cast<float4*>(xout + (size_t)tok * CC)[lane] = y;
}

__global__ void add_plain_kernel(const float* __restrict__ xin, const unsigned short* __restrict__ hh,
                                 const float* __restrict__ gamma, float* __restrict__ xout, int nvec4) {
    int idx = (int)(blockIdx.x * blockDim.x + threadIdx.x);
    if (idx >= nvec4) return;
    float g = gamma[0];
    float4 a = reinterpret_cast<const float4*>(xin)[idx];
    ushort4 ov = reinterpret_cast<const ushort4*>(hh)[idx];
    reinterpret_cast<float4*>(xout)[idx] =
        make_float4(a.x + g * bf2f(ov.x), a.y + g * bf2f(ov.y),
                    a.z + g * bf2f(ov.z), a.w + g * bf2f(ov.w));
}

// ---------------- weight fp32 -> bf16 conversion ----------------
__global__ void cvt_all(const float* s0, const float* s1, const float* s2, const float* s3,
                        const float* s4, const float* s5, const float* s6, const float* s7,
                        const float* s8, const float* s9, unsigned short* __restrict__ dst) {
    const float* srcs[10] = {s0, s1, s2, s3, s4, s5, s6, s7, s8, s9};
    int blk = blockIdx.x;
    int wi = (blk < 512) ? (blk >> 6) : (blk < 768 ? 8 : 9);
    size_t start = (wi < 8) ? (size_t)wi * 65536 : (wi == 8 ? (size_t)524288 : (size_t)786432);
    size_t gidx = (size_t)blk * 1024 + (size_t)threadIdx.x * 4;
    float4 v = *reinterpret_cast<const float4*>(srcs[wi] + (gidx - start));
    ushort4 o;
    o.x = f2bf(v.x); o.y = f2bf(v.y); o.z = f2bf(v.z); o.w = f2bf(v.w);
    *reinterpret_cast<ushort4*>(dst + gidx) = o;
}

extern "C" void kernel_launch(void* const* d_in, const int* in_sizes, int n_in,
                              void* d_out, int out_size, void* d_ws, size_t ws_size,
                              hipStream_t stream) {
    const float* x    = (const float*)d_in[0];
    const float* ctx  = (const float*)d_in[1];
    const float* ln1w = (const float*)d_in[2];
    const float* ln1b = (const float*)d_in[3];
    const float* ln2w = (const float*)d_in[4];
    const float* ln2b = (const float*)d_in[5];
    const float* ln3w = (const float*)d_in[6];
    const float* ln3b = (const float*)d_in[7];
    const float* lncw = (const float*)d_in[8];
    const float* lncb = (const float*)d_in[9];
    const float* saqw = (const float*)d_in[10];
    const float* saqb = (const float*)d_in[11];
    const float* sakw = (const float*)d_in[12];
    const float* sakb = (const float*)d_in[13];
    const float* savw = (const float*)d_in[14];
    const float* savb = (const float*)d_in[15];
    const float* saow = (const float*)d_in[16];
    const float* saob = (const float*)d_in[17];
    const float* sabias = (const float*)d_in[18];
    const float* caqw = (const float*)d_in[19];
    const float* caqb = (const float*)d_in[20];
    const float* cakw = (const float*)d_in[21];
    const float* cakb = (const float*)d_in[22];
    const float* cavw = (const float*)d_in[23];
    const float* cavb = (const float*)d_in[24];
    const float* caow = (const float*)d_in[25];
    const float* caob = (const float*)d_in[26];
    const float* cabias = (const float*)d_in[27];
    const float* gamma1 = (const float*)d_in[28];
    const float* gamma2 = (const float*)d_in[29];
    const float* gammam = (const float*)d_in[30];
    const float* mw1 = (const float*)d_in[31];
    const float* mb1 = (const float*)d_in[32];
    const float* mw2 = (const float*)d_in[33];
    const float* mb2 = (const float*)d_in[34];

    float* ws = (float*)d_ws;
    unsigned short* LNbf = (unsigned short*)(ws);                 // 3,686,400 f
    unsigned short* Gq   = (unsigned short*)(ws + 3686400);       // 4,194,304 f
    unsigned short* Gkv  = (unsigned short*)(ws + 7880704);       // 4,194,304 f
    unsigned short* Qbf  = (unsigned short*)(ws + 12075008);      // 4,194,304 f
    unsigned short* Kbf  = (unsigned short*)(ws + 16269312);      // 4,194,304 f
    unsigned short* VTbf = (unsigned short*)(ws + 20463616);      // 4,194,304 f
    unsigned short* OPbf = (unsigned short*)(ws + 24657920);      // 4,194,304 f
    float* X1  = ws + 28852224;                                   // 7,372,800 f
    unsigned short* Wp = (unsigned short*)(ws + 36225024);        // 524,288 f
    float* biasx = ws + 36749312;                                 // 32,768 f
    unsigned short* H2bf = (unsigned short*)(ws + 36782080);      // 3,686,400 f
    unsigned short* AObf = Gq;                                    // alias (gathered q dead after proj)
    unsigned short* H1bf = Qbf;                                   // alias (Q/K/VT/OP dead in MLP phase)

    unsigned short* w_saq = Wp;            unsigned short* w_sak = Wp + 65536;
    unsigned short* w_sav = Wp + 131072;   unsigned short* w_sao = Wp + 196608;
    unsigned short* w_caq = Wp + 262144;   unsigned short* w_cak = Wp + 327680;
    unsigned short* w_cav = Wp + 393216;   unsigned short* w_cao = Wp + 458752;
    unsigned short* w_m1  = Wp + 524288;   unsigned short* w_m2  = Wp + 786432;

    float* OUT = (float*)d_out;

    dim3 blk(256);
    dim3 gLN(BN / 4);
    dim3 gGather(WROWS / 4);
    dim3 gProj(WROWS / 128, CC / 128);
    dim3 gAttn(WINS * 2);

    cvt_all<<<dim3(1024), blk, 0, stream>>>(saqw, sakw, savw, saow, caqw, cakw, cavw, caow, mw1, mw2, Wp);
    expand_bias<<<dim3(128), blk, 0, stream>>>(sabias, cabias, biasx);

    // ---- self attention ----
    ln_kernel<<<gLN, blk, 0, stream>>>(x, ln1w, ln1b, LNbf, BN);
    gather_win<<<gGather, blk, 0, stream>>>(LNbf, Gq);
    gemm_bf16<false,1><<<gProj, blk, 0, stream>>>(Gq, w_saq, saqb, Qbf, WROWS, CC, CC);
    gemm_bf16<false,1><<<gProj, blk, 0, stream>>>(Gq, w_sak, sakb, Kbf, WROWS, CC, CC);
    gemm_bf16<false,2><<<gProj, blk, 0, stream>>>(Gq, w_sav, savb, VTbf, WROWS, CC, CC);
    attn_mfma<<<gAttn, blk, 0, stream>>>(Qbf, Kbf, VTbf, biasx, AObf);
    gemm_bf16<false,1><<<gProj, blk, 0, stream>>>(AObf, w_sao, saob, OPbf, WROWS, CC, CC);
    add_win_kernel<<<gLN, blk, 0, stream>>>(x, OPbf, gamma1, X1);

    // ---- cross attention ----
    ln_kernel<<<gLN, blk, 0, stream>>>(X1, ln2w, ln2b, LNbf, BN);
    gather_win<<<gGather, blk, 0, stream>>>(LNbf, Gq);
    ln_kernel<<<gLN, blk, 0, stream>>>(ctx, lncw, lncb, LNbf, BN);
    gather_win<<<gGather, blk, 0, stream>>>(LNbf, Gkv);
    gemm_bf16<false,1><<<gProj, blk, 0, stream>>>(Gq,  w_caq, caqb, Qbf, WROWS, CC, CC);
    gemm_bf16<false,1><<<gProj, blk, 0, stream>>>(Gkv, w_cak, cakb, Kbf, WROWS, CC, CC);
    gemm_bf16<false,2><<<gProj, blk, 0, stream>>>(Gkv, w_cav, cavb, VTbf, WROWS, CC, CC);
    attn_mfma<<<gAttn, blk, 0, stream>>>(Qbf, Kbf, VTbf, biasx + 16384, AObf);
    gemm_bf16<false,1><<<gProj, blk, 0, stream>>>(AObf, w_cao, caob, OPbf, WROWS, CC, CC);
    add_win_kernel<<<gLN, blk, 0, stream>>>(X1, OPbf, gamma2, X1);

    // ---- MLP ----
    ln_kernel<<<gLN, blk, 0, stream>>>(X1, ln3w, ln3b, LNbf, BN);
    gemm_bf16<true,1><<<dim3(BN/128, HIDN/128), blk, 0, stream>>>(LNbf, w_m1, mb1, H1bf, BN, HIDN, CC);
    gemm_bf16<false,1><<<dim3(BN/128, CC/128), blk, 0, stream>>>(H1bf, w_m2, mb2, H2bf, BN, CC, HIDN);
    add_plain_kernel<<<dim3(BN * CC / 4 / 256), blk, 0, stream>>>(X1, H2bf, gammam, OUT, BN * CC / 4);
}

// Round 4
// 310.650 us; speedup vs baseline: 3.9800x; 1.0160x over previous
//
#include <hip/hip_runtime.h>
#include <math.h>

// ---- problem constants ----
#define BN    28800      // B*N tokens total
#define CC    256        // channels
#define HIDN  1024       // MLP hidden
#define WINS  512        // total windows (8 frames * 64)
#define WROWS (WINS*64)  // 32768 window rows
#define ATT_SCALE 0.1767766952966369f

typedef __bf16 bf16x8 __attribute__((ext_vector_type(8)));
typedef float  f32x4  __attribute__((ext_vector_type(4)));

__device__ __forceinline__ unsigned short f2bf(float f) {
    unsigned u = __float_as_uint(f);
    unsigned r = (u + 0x7FFFu + ((u >> 16) & 1u)) >> 16;
    return (unsigned short)r;
}
__device__ __forceinline__ float bf2f(unsigned short u) {
    return __uint_as_float((unsigned)u << 16);
}

__device__ __forceinline__ void gl_lds16(const void* g, void* l) {
    __builtin_amdgcn_global_load_lds(
        (const __attribute__((address_space(1))) void*)g,
        (__attribute__((address_space(3))) void*)l, 16, 0, 0);
}

// ---------------- LayerNorm (plain): one wave per token, bf16 out ----------------
__global__ void ln_kernel(const float* __restrict__ x, const float* __restrict__ w,
                          const float* __restrict__ b, unsigned short* __restrict__ out, int ntok) {
    int tok  = (int)((blockIdx.x * blockDim.x + threadIdx.x) >> 6);
    int lane = threadIdx.x & 63;
    if (tok >= ntok) return;
    float4 v = reinterpret_cast<const float4*>(x + (size_t)tok * CC)[lane];
    float s  = v.x + v.y + v.z + v.w;
    float s2 = v.x*v.x + v.y*v.y + v.z*v.z + v.w*v.w;
#pragma unroll
    for (int off = 32; off >= 1; off >>= 1) {
        s  += __shfl_xor(s, off);
        s2 += __shfl_xor(s2, off);
    }
    float mean = s * (1.0f / CC);
    float var  = s2 * (1.0f / CC) - mean * mean;
    float rs   = rsqrtf(var + 1e-5f);
    float4 wv = reinterpret_cast<const float4*>(w)[lane];
    float4 bv = reinterpret_cast<const float4*>(b)[lane];
    ushort4 o;
    o.x = f2bf((v.x - mean) * rs * wv.x + bv.x);
    o.y = f2bf((v.y - mean) * rs * wv.y + bv.y);
    o.z = f2bf((v.z - mean) * rs * wv.z + bv.z);
    o.w = f2bf((v.w - mean) * rs * wv.w + bv.w);
    reinterpret_cast<ushort4*>(out + (size_t)tok * CC)[lane] = o;
}

// ---------------- fused LayerNorm + window gather ----------------
// one wave per window row; window partition is a bijection on interior tokens
__global__ void ln_gather(const float* __restrict__ x, const float* __restrict__ w,
                          const float* __restrict__ b, unsigned short* __restrict__ dst) {
    int row  = (int)((blockIdx.x * blockDim.x + threadIdx.x) >> 6);
    int lane = threadIdx.x & 63;
    if (row >= WROWS) return;
    int win = row >> 6, l = row & 63;
    int f   = win >> 6;
    int wih = (win >> 3) & 7, wiw = win & 7;
    int r = l >> 3, s = l & 7;
    int h = wih * 8 + r, wc = wiw * 8 + s;
    if (h >= 60 || wc >= 60) {
        ushort4 z = {0, 0, 0, 0};
        reinterpret_cast<ushort4*>(dst + (size_t)row * CC)[lane] = z;
        return;
    }
    int oh = (h + 4) % 60, ow = (wc + 4) % 60;
    size_t tok = (size_t)f * 3600 + (size_t)oh * 60 + ow;
    float4 v = reinterpret_cast<const float4*>(x + tok * CC)[lane];
    float sm  = v.x + v.y + v.z + v.w;
    float s2 = v.x*v.x + v.y*v.y + v.z*v.z + v.w*v.w;
#pragma unroll
    for (int off = 32; off >= 1; off >>= 1) {
        sm += __shfl_xor(sm, off);
        s2 += __shfl_xor(s2, off);
    }
    float mean = sm * (1.0f / CC);
    float var  = s2 * (1.0f / CC) - mean * mean;
    float rs   = rsqrtf(var + 1e-5f);
    float4 wv = reinterpret_cast<const float4*>(w)[lane];
    float4 bv = reinterpret_cast<const float4*>(b)[lane];
    ushort4 o;
    o.x = f2bf((v.x - mean) * rs * wv.x + bv.x);
    o.y = f2bf((v.y - mean) * rs * wv.y + bv.y);
    o.z = f2bf((v.z - mean) * rs * wv.z + bv.z);
    o.w = f2bf((v.w - mean) * rs * wv.w + bv.w);
    reinterpret_cast<ushort4*>(dst + (size_t)row * CC)[lane] = o;
}

// ---------------- bf16 MFMA GEMM, weights-as-A (computes C^T, stores C row-major) ----
// D[ch][tok] = Wt[ch,:] . Act[tok,:] ; transposed ushort4 store -> out[tok][ch] 8B vec.
// Segments of 256 channels route to (out,bias) pairs; seg==vseg stores direct [ch][32768].
template <bool GELU>
__global__ __launch_bounds__(256) void gemm_wa(
        const unsigned short* __restrict__ Wt,   // [Mtot][K] bf16
        const unsigned short* __restrict__ Act,  // [Ntok][K] bf16
        const float* __restrict__ b0, const float* __restrict__ b1,
        const float* __restrict__ b2, const float* __restrict__ b3,
        unsigned short* __restrict__ o0, unsigned short* __restrict__ o1,
        unsigned short* __restrict__ o2, unsigned short* __restrict__ o3,
        int strideO, int vseg, int K) {
    __shared__ __align__(16) unsigned short As[128 * 32];
    __shared__ __align__(16) unsigned short Bs[128 * 32];
    const int t = threadIdx.x;
    const int w = t >> 6, l = t & 63;
    const int m0 = blockIdx.x * 128, n0 = blockIdx.y * 128;
    const int wr = w >> 1, wc = w & 1;
    const int r = l & 15, g = l >> 4;
    const int sw = (r >> 1) & 3;
    const int gp = (g ^ sw) * 8;
    f32x4 acc[4][4];
#pragma unroll
    for (int i = 0; i < 4; ++i)
#pragma unroll
        for (int j = 0; j < 4; ++j) { acc[i][j][0]=0.f; acc[i][j][1]=0.f; acc[i][j][2]=0.f; acc[i][j][3]=0.f; }

    for (int k0 = 0; k0 < K; k0 += 32) {
        __syncthreads();
#pragma unroll
        for (int p = 0; p < 2; ++p) {
            int c   = p * 256 + t;
            int row = c >> 2;
            int gl  = (c & 3) ^ ((row >> 1) & 3);
            gl_lds16(Wt  + (size_t)(m0 + row) * K + k0 + gl * 8,
                     (char*)As + (p * 256 + w * 64) * 16);
            gl_lds16(Act + (size_t)(n0 + row) * K + k0 + gl * 8,
                     (char*)Bs + (p * 256 + w * 64) * 16);
        }
        __syncthreads();
        bf16x8 af[4], bw[4];
#pragma unroll
        for (int m = 0; m < 4; ++m)
            af[m] = *reinterpret_cast<const bf16x8*>(&As[(wr * 64 + m * 16 + r) * 32 + gp]);
#pragma unroll
        for (int n = 0; n < 4; ++n)
            bw[n] = *reinterpret_cast<const bf16x8*>(&Bs[(wc * 64 + n * 16 + r) * 32 + gp]);
#pragma unroll
        for (int m = 0; m < 4; ++m)
#pragma unroll
            for (int n = 0; n < 4; ++n)
                acc[m][n] = __builtin_amdgcn_mfma_f32_16x16x32_bf16(af[m], bw[n], acc[m][n], 0, 0, 0);
    }
    // ---- epilogue: per-segment routing, transposed ushort4 stores ----
    const int seg = m0 >> 8;
    const float* bp = (seg == 0) ? b0 : (seg == 1) ? b1 : (seg == 2) ? b2 : b3;
    unsigned short* op = (seg == 0) ? o0 : (seg == 1) ? o1 : (seg == 2) ? o2 : o3;
    const bool vdir = (seg == vseg);
#pragma unroll
    for (int m = 0; m < 4; ++m) {
        const int ch0 = (m0 & 255) + wr * 64 + m * 16 + g * 4;
        float4 b4 = *reinterpret_cast<const float4*>(bp + ch0);
        const float bb[4] = {b4.x, b4.y, b4.z, b4.w};
#pragma unroll
        for (int n = 0; n < 4; ++n) {
            const int tok = n0 + wc * 64 + n * 16 + r;
            float cv[4];
#pragma unroll
            for (int j = 0; j < 4; ++j) {
                cv[j] = acc[m][n][j] + bb[j];
                if (GELU) cv[j] = 0.5f * cv[j] * (1.0f + erff(cv[j] * 0.70710678118654752f));
            }
            if (vdir) {
#pragma unroll
                for (int j = 0; j < 4; ++j)
                    op[(size_t)(ch0 + j) * 32768 + tok] = f2bf(cv[j]);
            } else {
                ushort4 pk;
                pk.x = f2bf(cv[0]); pk.y = f2bf(cv[1]); pk.z = f2bf(cv[2]); pk.w = f2bf(cv[3]);
                *reinterpret_cast<ushort4*>(op + (size_t)tok * strideO + ch0) = pk;
            }
        }
    }
}

// ---------------- bias table expansion: biasx[2][8][64][64] ----------------
__global__ void expand_bias(const float* __restrict__ sa, const float* __restrict__ ca,
                            float* __restrict__ dst) {
    int e = (int)(blockIdx.x * blockDim.x + threadIdx.x);   // 0..32767
    const float* src = (e < 16384) ? sa : ca;
    int e2 = e & 16383;
    int h = e2 >> 12, ij = e2 & 4095, i = ij >> 6, j = ij & 63;
    int ri = i >> 3, si = i & 7, rj = j >> 3, sj = j & 7;
    dst[e] = src[((ri - rj + 7) * 15 + (si - sj + 7)) * 8 + h];
}

// ---------------- MFMA attention: one wave per (window, head) ----------------
__global__ __launch_bounds__(256) void attn_mfma(
        const unsigned short* __restrict__ Q,   // [32768][256] bf16
        const unsigned short* __restrict__ K,   // [32768][256] bf16
        const unsigned short* __restrict__ VT,  // [256][32768] bf16
        const float* __restrict__ biasx,        // [8][64][64] f32
        unsigned short* __restrict__ AO) {      // [32768][256] bf16
    __shared__ __align__(16) unsigned short Pl[4][64 * 64];
    const int t = threadIdx.x;
    const int w = t >> 6, l = t & 63;
    const int win = blockIdx.x >> 1;
    const int h   = (blockIdx.x & 1) * 4 + w;
    const int c = l & 15, g = l >> 4;
    const int wih = (win >> 3) & 7, wiw = win & 7;
    const size_t qkbase = (size_t)win * 64 * CC + (size_t)h * 32;

    bf16x8 ka[4], qb[4];
#pragma unroll
    for (int mj = 0; mj < 4; ++mj)
        ka[mj] = *reinterpret_cast<const bf16x8*>(K + qkbase + (size_t)(mj * 16 + c) * CC + g * 8);
#pragma unroll
    for (int ni = 0; ni < 4; ++ni)
        qb[ni] = *reinterpret_cast<const bf16x8*>(Q + qkbase + (size_t)(ni * 16 + c) * CC + g * 8);
    f32x4 s[4][4];
#pragma unroll
    for (int mj = 0; mj < 4; ++mj)
#pragma unroll
        for (int ni = 0; ni < 4; ++ni) { s[mj][ni][0]=0.f; s[mj][ni][1]=0.f; s[mj][ni][2]=0.f; s[mj][ni][3]=0.f; }
#pragma unroll
    for (int mj = 0; mj < 4; ++mj)
#pragma unroll
        for (int ni = 0; ni < 4; ++ni)
            s[mj][ni] = __builtin_amdgcn_mfma_f32_16x16x32_bf16(ka[mj], qb[ni], s[mj][ni], 0, 0, 0);

    const float* bx = biasx + h * 4096;
    const bool modd = (wiw == 7) && (g & 1);
#pragma unroll
    for (int mj = 0; mj < 4; ++mj) {
        const bool mmj = (wih == 7) && (mj >= 2);
#pragma unroll
        for (int ni = 0; ni < 4; ++ni) {
            float4 b4 = *reinterpret_cast<const float4*>(bx + (ni * 16 + c) * 64 + mj * 16 + g * 4);
            const float bb[4] = {b4.x, b4.y, b4.z, b4.w};
#pragma unroll
            for (int jj = 0; jj < 4; ++jj) {
                float v = s[mj][ni][jj] * ATT_SCALE + bb[jj];
                s[mj][ni][jj] = (mmj || modd) ? -1e30f : v;
            }
        }
    }

#pragma unroll
    for (int ni = 0; ni < 4; ++ni) {
        float mx = -1e30f;
#pragma unroll
        for (int mj = 0; mj < 4; ++mj)
#pragma unroll
            for (int jj = 0; jj < 4; ++jj) mx = fmaxf(mx, s[mj][ni][jj]);
        mx = fmaxf(mx, __shfl_xor(mx, 16));
        mx = fmaxf(mx, __shfl_xor(mx, 32));
        float sum = 0.f;
#pragma unroll
        for (int mj = 0; mj < 4; ++mj)
#pragma unroll
            for (int jj = 0; jj < 4; ++jj) {
                float p = __expf(s[mj][ni][jj] - mx);
                s[mj][ni][jj] = p;
                sum += p;
            }
        sum += __shfl_xor(sum, 16);
        sum += __shfl_xor(sum, 32);
        float rinv = 1.0f / sum;
        const int i  = ni * 16 + c;
        const int ik = i & 7;
#pragma unroll
        for (int mj = 0; mj < 4; ++mj) {
            ushort4 pk;
            pk.x = f2bf(s[mj][ni][0] * rinv);
            pk.y = f2bf(s[mj][ni][1] * rinv);
            pk.z = f2bf(s[mj][ni][2] * rinv);
            pk.w = f2bf(s[mj][ni][3] * rinv);
            int chunk = (mj * 2 + (g >> 1)) ^ ik;
            *reinterpret_cast<ushort4*>((char*)&Pl[w][0] + i * 128 + chunk * 16 + (g & 1) * 8) = pk;
        }
    }

    bf16x8 vb[2][2];
#pragma unroll
    for (int nd = 0; nd < 2; ++nd)
#pragma unroll
        for (int kt = 0; kt < 2; ++kt)
            vb[nd][kt] = *reinterpret_cast<const bf16x8*>(
                VT + (size_t)(h * 32 + nd * 16 + c) * 32768 + win * 64 + kt * 32 + g * 8);
    f32x4 o[4][2];
#pragma unroll
    for (int mi = 0; mi < 4; ++mi)
#pragma unroll
        for (int nd = 0; nd < 2; ++nd) { o[mi][nd][0]=0.f; o[mi][nd][1]=0.f; o[mi][nd][2]=0.f; o[mi][nd][3]=0.f; }
#pragma unroll
    for (int mi = 0; mi < 4; ++mi) {
        const int i  = mi * 16 + c;
        const int ik = i & 7;
#pragma unroll
        for (int kt = 0; kt < 2; ++kt) {
            int chunk = (kt * 4 + g) ^ ik;
            bf16x8 pa = *reinterpret_cast<const bf16x8*>((char*)&Pl[w][0] + i * 128 + chunk * 16);
#pragma unroll
            for (int nd = 0; nd < 2; ++nd)
                o[mi][nd] = __builtin_amdgcn_mfma_f32_16x16x32_bf16(pa, vb[nd][kt], o[mi][nd], 0, 0, 0);
        }
    }

    unsigned short* aop = AO + qkbase;
#pragma unroll
    for (int mi = 0; mi < 4; ++mi)
#pragma unroll
        for (int nd = 0; nd < 2; ++nd)
#pragma unroll
            for (int jj = 0; jj < 4; ++jj)
                aop[(size_t)(mi * 16 + g * 4 + jj) * CC + nd * 16 + c] = f2bf(o[mi][nd][jj]);
}

// ---------------- residual add with inverse-window gather (bf16 delta) ----------------
__global__ void add_win_kernel(const float* __restrict__ xin, const unsigned short* __restrict__ OP,
                               const float* __restrict__ gamma, float* __restrict__ xout) {
    int tok  = (int)((blockIdx.x * blockDim.x + threadIdx.x) >> 6);
    int lane = threadIdx.x & 63;
    if (tok >= BN) return;
    int f  = tok / 3600;
    int p  = tok % 3600;
    int hi = p / 60, wi = p % 60;
    int hp = (hi + 56) % 60, wp = (wi + 56) % 60;
    int wih = hp >> 3, r = hp & 7, wiw = wp >> 3, s = wp & 7;
    size_t row = ((size_t)f * 64 + (size_t)(wih * 8 + wiw)) * 64 + (size_t)(r * 8 + s);
    float g = gamma[0];
    float4 a = reinterpret_cast<const float4*>(xin + (size_t)tok * CC)[lane];
    ushort4 ov = reinterpret_cast<const ushort4*>(OP + row * CC)[lane];
    float4 y = make_float4(a.x + g * bf2f(ov.x), a.y + g * bf2f(ov.y),
                           a.z + g * bf2f(ov.z), a.w + g * bf2f(ov.w));
    reinterpret_cast<float4*>(xout + (size_t)tok * CC)[lane] = y;
}

__global__ void add_plain_kernel(const float* __restrict__ xin, const unsigned short* __restrict__ hh,
                                 const float* __restrict__ gamma, float* __restrict__ xout, int nvec4) {
    int idx = (int)(blockIdx.x * blockDim.x + threadIdx.x);
    if (idx >= nvec4) return;
    float g = gamma[0];
    float4 a = reinterpret_cast<const float4*>(xin)[idx];
    ushort4 ov = reinterpret_cast<const ushort4*>(hh)[idx];
    reinterpret_cast<float4*>(xout)[idx] =
        make_float4(a.x + g * bf2f(ov.x), a.y + g * bf2f(ov.y),
                    a.z + g * bf2f(ov.z), a.w + g * bf2f(ov.w));
}

// ---------------- weight fp32 -> bf16 conversion ----------------
__global__ void cvt_all(const float* s0, const float* s1, const float* s2, const float* s3,
                        const float* s4, const float* s5, const float* s6, const float* s7,
                        const float* s8, const float* s9, unsigned short* __restrict__ dst) {
    const float* srcs[10] = {s0, s1, s2, s3, s4, s5, s6, s7, s8, s9};
    int blk = blockIdx.x;
    int wi = (blk < 512) ? (blk >> 6) : (blk < 768 ? 8 : 9);
    size_t start = (wi < 8) ? (size_t)wi * 65536 : (wi == 8 ? (size_t)524288 : (size_t)786432);
    size_t gidx = (size_t)blk * 1024 + (size_t)threadIdx.x * 4;
    float4 v = *reinterpret_cast<const float4*>(srcs[wi] + (gidx - start));
    ushort4 o;
    o.x = f2bf(v.x); o.y = f2bf(v.y); o.z = f2bf(v.z); o.w = f2bf(v.w);
    *reinterpret_cast<ushort4*>(dst + gidx) = o;
}

extern "C" void kernel_launch(void* const* d_in, const int* in_sizes, int n_in,
                              void* d_out, int out_size, void* d_ws, size_t ws_size,
                              hipStream_t stream) {
    const float* x    = (const float*)d_in[0];
    const float* ctx  = (const float*)d_in[1];
    const float* ln1w = (const float*)d_in[2];
    const float* ln1b = (const float*)d_in[3];
    const float* ln2w = (const float*)d_in[4];
    const float* ln2b = (const float*)d_in[5];
    const float* ln3w = (const float*)d_in[6];
    const float* ln3b = (const float*)d_in[7];
    const float* lncw = (const float*)d_in[8];
    const float* lncb = (const float*)d_in[9];
    const float* saqw = (const float*)d_in[10];
    const float* saqb = (const float*)d_in[11];
    const float* sakw = (const float*)d_in[12];
    const float* sakb = (const float*)d_in[13];
    const float* savw = (const float*)d_in[14];
    const float* savb = (const float*)d_in[15];
    const float* saow = (const float*)d_in[16];
    const float* saob = (const float*)d_in[17];
    const float* sabias = (const float*)d_in[18];
    const float* caqw = (const float*)d_in[19];
    const float* caqb = (const float*)d_in[20];
    const float* cakw = (const float*)d_in[21];
    const float* cakb = (const float*)d_in[22];
    const float* cavw = (const float*)d_in[23];
    const float* cavb = (const float*)d_in[24];
    const float* caow = (const float*)d_in[25];
    const float* caob = (const float*)d_in[26];
    const float* cabias = (const float*)d_in[27];
    const float* gamma1 = (const float*)d_in[28];
    const float* gamma2 = (const float*)d_in[29];
    const float* gammam = (const float*)d_in[30];
    const float* mw1 = (const float*)d_in[31];
    const float* mb1 = (const float*)d_in[32];
    const float* mw2 = (const float*)d_in[33];
    const float* mb2 = (const float*)d_in[34];

    float* ws = (float*)d_ws;
    unsigned short* LNbf = (unsigned short*)(ws);                 // 3,686,400 f
    unsigned short* Gq   = (unsigned short*)(ws + 3686400);       // 4,194,304 f
    unsigned short* Gkv  = (unsigned short*)(ws + 7880704);       // 4,194,304 f
    unsigned short* Qbf  = (unsigned short*)(ws + 12075008);      // 4,194,304 f
    unsigned short* Kbf  = (unsigned short*)(ws + 16269312);      // 4,194,304 f
    unsigned short* VTbf = (unsigned short*)(ws + 20463616);      // 4,194,304 f
    unsigned short* OPbf = (unsigned short*)(ws + 24657920);      // 4,194,304 f
    float* X1  = ws + 28852224;                                   // 7,372,800 f
    unsigned short* Wp = (unsigned short*)(ws + 36225024);        // 524,288 f
    float* biasx = ws + 36749312;                                 // 32,768 f
    unsigned short* H2bf = (unsigned short*)(ws + 36782080);      // 3,686,400 f
    unsigned short* AObf = Gq;                                    // alias (gathered act dead after proj)
    unsigned short* H1bf = Qbf;                                   // alias (Q/K/VT/OP dead in MLP phase)

    // cvt layout (contiguous): saq|sak|sav | sao | caq | cak|cav | cao | m1 | m2
    unsigned short* w_saqkv = Wp;                                 // [768][256]
    unsigned short* w_sao   = Wp + 196608;                        // [256][256]
    unsigned short* w_caq   = Wp + 262144;                        // [256][256]
    unsigned short* w_cakv  = Wp + 327680;                        // [512][256]
    unsigned short* w_cao   = Wp + 458752;                        // [256][256]
    unsigned short* w_m1    = Wp + 524288;                        // [1024][256]
    unsigned short* w_m2    = Wp + 786432;                        // [256][1024]

    float* OUT = (float*)d_out;

    dim3 blk(256);
    dim3 gLN(BN / 4);
    dim3 gGather(WROWS / 4);
    dim3 gAttn(WINS * 2);

    cvt_all<<<dim3(1024), blk, 0, stream>>>(saqw, sakw, savw, saow, caqw, cakw, cavw, caow, mw1, mw2, Wp);
    expand_bias<<<dim3(128), blk, 0, stream>>>(sabias, cabias, biasx);

    // ---- self attention ----
    ln_gather<<<gGather, blk, 0, stream>>>(x, ln1w, ln1b, Gq);
    gemm_wa<false><<<dim3(6, 256), blk, 0, stream>>>(w_saqkv, Gq, saqb, sakb, savb, savb,
                                                     Qbf, Kbf, VTbf, VTbf, CC, 2, CC);
    attn_mfma<<<gAttn, blk, 0, stream>>>(Qbf, Kbf, VTbf, biasx, AObf);
    gemm_wa<false><<<dim3(2, 256), blk, 0, stream>>>(w_sao, AObf, saob, saob, saob, saob,
                                                     OPbf, OPbf, OPbf, OPbf, CC, -1, CC);
    add_win_kernel<<<gLN, blk, 0, stream>>>(x, OPbf, gamma1, X1);

    // ---- cross attention ----
    ln_gather<<<gGather, blk, 0, stream>>>(X1, ln2w, ln2b, Gq);
    ln_gather<<<gGather, blk, 0, stream>>>(ctx, lncw, lncb, Gkv);
    gemm_wa<false><<<dim3(2, 256), blk, 0, stream>>>(w_caq, Gq, caqb, caqb, caqb, caqb,
                                                     Qbf, Qbf, Qbf, Qbf, CC, -1, CC);
    gemm_wa<false><<<dim3(4, 256), blk, 0, stream>>>(w_cakv, Gkv, cakb, cavb, cavb, cavb,
                                                     Kbf, VTbf, VTbf, VTbf, CC, 1, CC);
    attn_mfma<<<gAttn, blk, 0, stream>>>(Qbf, Kbf, VTbf, biasx + 16384, AObf);
    gemm_wa<false><<<dim3(2, 256), blk, 0, stream>>>(w_cao, AObf, caob, caob, caob, caob,
                                                     OPbf, OPbf, OPbf, OPbf, CC, -1, CC);
    add_win_kernel<<<gLN, blk, 0, stream>>>(X1, OPbf, gamma2, X1);

    // ---- MLP ----
    ln_kernel<<<gLN, blk, 0, stream>>>(X1, ln3w, ln3b, LNbf, BN);
    gemm_wa<true><<<dim3(8, 225), blk, 0, stream>>>(w_m1, LNbf, mb1, mb1 + 256, mb1 + 512, mb1 + 768,
                                                    H1bf, H1bf + 256, H1bf + 512, H1bf + 768,
                                                    HIDN, -1, CC);
    gemm_wa<false><<<dim3(2, 225), blk, 0, stream>>>(w_m2, H1bf, mb2, mb2, mb2, mb2,
                                                    H2bf, H2bf, H2bf, H2bf, CC, -1, HIDN);
    add_plain_kernel<<<dim3(BN * CC / 4 / 256), blk, 0, stream>>>(X1, H2bf, gammam, OUT, BN * CC / 4);
}

// Round 5
// 284.112 us; speedup vs baseline: 4.3518x; 1.0934x over previous
//
#include <hip/hip_runtime.h>
#include <math.h>

// ---- problem constants ----
#define BN    28800      // B*N tokens total
#define CC    256        // channels
#define HIDN  1024       // MLP hidden
#define WINS  512        // total windows (8 frames * 64)
#define WROWS (WINS*64)  // 32768 window rows
#define ATT_SCALE 0.1767766952966369f

typedef __bf16 bf16x8 __attribute__((ext_vector_type(8)));
typedef float  f32x4  __attribute__((ext_vector_type(4)));

__device__ __forceinline__ unsigned short f2bf(float f) {
    unsigned u = __float_as_uint(f);
    unsigned r = (u + 0x7FFFu + ((u >> 16) & 1u)) >> 16;
    return (unsigned short)r;
}
__device__ __forceinline__ float bf2f(unsigned short u) {
    return __uint_as_float((unsigned)u << 16);
}

__device__ __forceinline__ void gl_lds16(const void* g, void* l) {
    __builtin_amdgcn_global_load_lds(
        (const __attribute__((address_space(1))) void*)g,
        (__attribute__((address_space(3))) void*)l, 16, 0, 0);
}

// ---------------- LayerNorm (plain): one wave per token, bf16 out ----------------
__global__ void ln_kernel(const float* __restrict__ x, const float* __restrict__ w,
                          const float* __restrict__ b, unsigned short* __restrict__ out, int ntok) {
    int tok  = (int)((blockIdx.x * blockDim.x + threadIdx.x) >> 6);
    int lane = threadIdx.x & 63;
    if (tok >= ntok) return;
    float4 v = reinterpret_cast<const float4*>(x + (size_t)tok * CC)[lane];
    float s  = v.x + v.y + v.z + v.w;
    float s2 = v.x*v.x + v.y*v.y + v.z*v.z + v.w*v.w;
#pragma unroll
    for (int off = 32; off >= 1; off >>= 1) {
        s  += __shfl_xor(s, off);
        s2 += __shfl_xor(s2, off);
    }
    float mean = s * (1.0f / CC);
    float var  = s2 * (1.0f / CC) - mean * mean;
    float rs   = rsqrtf(var + 1e-5f);
    float4 wv = reinterpret_cast<const float4*>(w)[lane];
    float4 bv = reinterpret_cast<const float4*>(b)[lane];
    ushort4 o;
    o.x = f2bf((v.x - mean) * rs * wv.x + bv.x);
    o.y = f2bf((v.y - mean) * rs * wv.y + bv.y);
    o.z = f2bf((v.z - mean) * rs * wv.z + bv.z);
    o.w = f2bf((v.w - mean) * rs * wv.w + bv.w);
    reinterpret_cast<ushort4*>(out + (size_t)tok * CC)[lane] = o;
}

// ---------------- fused LayerNorm + window gather ----------------
__global__ void ln_gather(const float* __restrict__ x, const float* __restrict__ w,
                          const float* __restrict__ b, unsigned short* __restrict__ dst) {
    int row  = (int)((blockIdx.x * blockDim.x + threadIdx.x) >> 6);
    int lane = threadIdx.x & 63;
    if (row >= WROWS) return;
    int win = row >> 6, l = row & 63;
    int f   = win >> 6;
    int wih = (win >> 3) & 7, wiw = win & 7;
    int r = l >> 3, s = l & 7;
    int h = wih * 8 + r, wc = wiw * 8 + s;
    if (h >= 60 || wc >= 60) {
        ushort4 z = {0, 0, 0, 0};
        reinterpret_cast<ushort4*>(dst + (size_t)row * CC)[lane] = z;
        return;
    }
    int oh = (h + 4) % 60, ow = (wc + 4) % 60;
    size_t tok = (size_t)f * 3600 + (size_t)oh * 60 + ow;
    float4 v = reinterpret_cast<const float4*>(x + tok * CC)[lane];
    float sm  = v.x + v.y + v.z + v.w;
    float s2 = v.x*v.x + v.y*v.y + v.z*v.z + v.w*v.w;
#pragma unroll
    for (int off = 32; off >= 1; off >>= 1) {
        sm += __shfl_xor(sm, off);
        s2 += __shfl_xor(s2, off);
    }
    float mean = sm * (1.0f / CC);
    float var  = s2 * (1.0f / CC) - mean * mean;
    float rs   = rsqrtf(var + 1e-5f);
    float4 wv = reinterpret_cast<const float4*>(w)[lane];
    float4 bv = reinterpret_cast<const float4*>(b)[lane];
    ushort4 o;
    o.x = f2bf((v.x - mean) * rs * wv.x + bv.x);
    o.y = f2bf((v.y - mean) * rs * wv.y + bv.y);
    o.z = f2bf((v.z - mean) * rs * wv.z + bv.z);
    o.w = f2bf((v.w - mean) * rs * wv.w + bv.w);
    reinterpret_cast<ushort4*>(dst + (size_t)row * CC)[lane] = o;
}

// ---------------- bf16 MFMA GEMM, weights-as-A, LDS-transposed coalesced epilogue ----
// D[ch][tok] computed; stored as out[tok][ch] via 32KB LDS transpose (XOR-swizzled).
// Segments of 256 channels route to (out,bias) pairs; seg==vseg stores direct [ch][32768].
// XCD-bijective block remap: within an XCD, m varies fastest -> activation panel L2 reuse.
template <bool GELU>
__global__ __launch_bounds__(256) void gemm_wa(
        const unsigned short* __restrict__ Wt,   // [Mtot][K] bf16
        const unsigned short* __restrict__ Act,  // [Ntok][K] bf16
        const float* __restrict__ b0, const float* __restrict__ b1,
        const float* __restrict__ b2, const float* __restrict__ b3,
        unsigned short* __restrict__ o0, unsigned short* __restrict__ o1,
        unsigned short* __restrict__ o2, unsigned short* __restrict__ o3,
        int strideO, int vseg, int K) {
    __shared__ __align__(16) char pool[32768];
    unsigned short* As = (unsigned short*)pool;            // 8 KB
    unsigned short* Bs = (unsigned short*)(pool + 8192);   // 8 KB
    unsigned short* Cs = (unsigned short*)pool;            // 32 KB (after barrier)

    const int t = threadIdx.x;
    const int w = t >> 6, l = t & 63;
    // ---- bijective XCD swizzle (m204): m fastest within an XCD ----
    const int Mb = gridDim.x;
    int lin = blockIdx.y * Mb + blockIdx.x;
    int T = Mb * gridDim.y;
    int q = T >> 3, rr = T & 7;
    int xcd = lin & 7, slot = lin >> 3;
    int wid = (xcd < rr) ? (xcd * (q + 1) + slot)
                         : (rr * (q + 1) + (xcd - rr) * q + slot);
    const int m0 = (wid % Mb) * 128;
    const int n0 = (wid / Mb) * 128;

    const int wr = w >> 1, wc = w & 1;
    const int r = l & 15, g = l >> 4;
    const int sw = (r >> 1) & 3;
    const int gp = (g ^ sw) * 8;
    f32x4 acc[4][4];
#pragma unroll
    for (int i = 0; i < 4; ++i)
#pragma unroll
        for (int j = 0; j < 4; ++j) { acc[i][j][0]=0.f; acc[i][j][1]=0.f; acc[i][j][2]=0.f; acc[i][j][3]=0.f; }

    for (int k0 = 0; k0 < K; k0 += 32) {
        __syncthreads();
#pragma unroll
        for (int p = 0; p < 2; ++p) {
            int c   = p * 256 + t;
            int row = c >> 2;
            int gl  = (c & 3) ^ ((row >> 1) & 3);
            gl_lds16(Wt  + (size_t)(m0 + row) * K + k0 + gl * 8,
                     (char*)As + (p * 256 + w * 64) * 16);
            gl_lds16(Act + (size_t)(n0 + row) * K + k0 + gl * 8,
                     (char*)Bs + (p * 256 + w * 64) * 16);
        }
        __syncthreads();
        bf16x8 af[4], bw[4];
#pragma unroll
        for (int m = 0; m < 4; ++m)
            af[m] = *reinterpret_cast<const bf16x8*>(&As[(wr * 64 + m * 16 + r) * 32 + gp]);
#pragma unroll
        for (int n = 0; n < 4; ++n)
            bw[n] = *reinterpret_cast<const bf16x8*>(&Bs[(wc * 64 + n * 16 + r) * 32 + gp]);
#pragma unroll
        for (int m = 0; m < 4; ++m)
#pragma unroll
            for (int n = 0; n < 4; ++n)
                acc[m][n] = __builtin_amdgcn_mfma_f32_16x16x32_bf16(af[m], bw[n], acc[m][n], 0, 0, 0);
    }

    // ---- epilogue ----
    const int seg = m0 >> 8;
    const float* bp = (seg == 0) ? b0 : (seg == 1) ? b1 : (seg == 2) ? b2 : b3;
    unsigned short* op = (seg == 0) ? o0 : (seg == 1) ? o1 : (seg == 2) ? o2 : o3;
    const int chseg = m0 & 255;

    if (seg == vseg) {
        // direct transposed store [ch][32768] (V^T for attention)
#pragma unroll
        for (int m = 0; m < 4; ++m) {
            const int ch0 = chseg + wr * 64 + m * 16 + g * 4;
            float4 b4 = *reinterpret_cast<const float4*>(bp + ch0);
            const float bb[4] = {b4.x, b4.y, b4.z, b4.w};
#pragma unroll
            for (int n = 0; n < 4; ++n) {
                const int tok = n0 + wc * 64 + n * 16 + r;
#pragma unroll
                for (int j = 0; j < 4; ++j)
                    op[(size_t)(ch0 + j) * 32768 + tok] = f2bf(acc[m][n][j] + bb[j]);
            }
        }
        return;
    }

    __syncthreads();   // all waves done reading As/Bs before Cs overwrite
#pragma unroll
    for (int m = 0; m < 4; ++m) {
        const int ch0 = wr * 64 + m * 16 + g * 4;       // local 0..127
        float4 b4 = *reinterpret_cast<const float4*>(bp + chseg + ch0);
        const float bb[4] = {b4.x, b4.y, b4.z, b4.w};
#pragma unroll
        for (int n = 0; n < 4; ++n) {
            const int tok_l = wc * 64 + n * 16 + r;     // local 0..127
            float cv[4];
#pragma unroll
            for (int j = 0; j < 4; ++j) {
                cv[j] = acc[m][n][j] + bb[j];
                if (GELU) cv[j] = 0.5f * cv[j] * (1.0f + erff(cv[j] * 0.70710678118654752f));
            }
            ushort4 pk;
            pk.x = f2bf(cv[0]); pk.y = f2bf(cv[1]); pk.z = f2bf(cv[2]); pk.w = f2bf(cv[3]);
            int gran = (ch0 >> 2) ^ ((tok_l & 15) << 1);
            reinterpret_cast<ushort4*>(Cs)[tok_l * 32 + gran] = pk;
        }
    }
    __syncthreads();
    // coalesced store: 16 lanes x 16B = 256 B contiguous per token row
    const int u = t & 15, trow = t >> 4;
#pragma unroll
    for (int it = 0; it < 8; ++it) {
        int tok_l = it * 16 + trow;
        int up = u ^ (tok_l & 15);
        uint4 v = reinterpret_cast<const uint4*>(Cs)[tok_l * 16 + up];
        *reinterpret_cast<uint4*>(op + (size_t)(n0 + tok_l) * strideO + chseg + u * 8) = v;
    }
}

// ---------------- bias table expansion: biasx[2][8][64][64] ----------------
__global__ void expand_bias(const float* __restrict__ sa, const float* __restrict__ ca,
                            float* __restrict__ dst) {
    int e = (int)(blockIdx.x * blockDim.x + threadIdx.x);   // 0..32767
    const float* src = (e < 16384) ? sa : ca;
    int e2 = e & 16383;
    int h = e2 >> 12, ij = e2 & 4095, i = ij >> 6, j = ij & 63;
    int ri = i >> 3, si = i & 7, rj = j >> 3, sj = j & 7;
    dst[e] = src[((ri - rj + 7) * 15 + (si - sj + 7)) * 8 + h];
}

// ---------------- MFMA attention: one wave per (window, head) ----------------
__global__ __launch_bounds__(256) void attn_mfma(
        const unsigned short* __restrict__ Q,   // [32768][256] bf16
        const unsigned short* __restrict__ K,   // [32768][256] bf16
        const unsigned short* __restrict__ VT,  // [256][32768] bf16
        const float* __restrict__ biasx,        // [8][64][64] f32
        unsigned short* __restrict__ AO) {      // [32768][256] bf16
    __shared__ __align__(16) unsigned short Pl[4][64 * 64];
    const int t = threadIdx.x;
    const int w = t >> 6, l = t & 63;
    const int win = blockIdx.x >> 1;
    const int h   = (blockIdx.x & 1) * 4 + w;
    const int c = l & 15, g = l >> 4;
    const int wih = (win >> 3) & 7, wiw = win & 7;
    const size_t qkbase = (size_t)win * 64 * CC + (size_t)h * 32;

    bf16x8 ka[4], qb[4];
#pragma unroll
    for (int mj = 0; mj < 4; ++mj)
        ka[mj] = *reinterpret_cast<const bf16x8*>(K + qkbase + (size_t)(mj * 16 + c) * CC + g * 8);
#pragma unroll
    for (int ni = 0; ni < 4; ++ni)
        qb[ni] = *reinterpret_cast<const bf16x8*>(Q + qkbase + (size_t)(ni * 16 + c) * CC + g * 8);
    f32x4 s[4][4];
#pragma unroll
    for (int mj = 0; mj < 4; ++mj)
#pragma unroll
        for (int ni = 0; ni < 4; ++ni) { s[mj][ni][0]=0.f; s[mj][ni][1]=0.f; s[mj][ni][2]=0.f; s[mj][ni][3]=0.f; }
#pragma unroll
    for (int mj = 0; mj < 4; ++mj)
#pragma unroll
        for (int ni = 0; ni < 4; ++ni)
            s[mj][ni] = __builtin_amdgcn_mfma_f32_16x16x32_bf16(ka[mj], qb[ni], s[mj][ni], 0, 0, 0);

    const float* bx = biasx + h * 4096;
    const bool modd = (wiw == 7) && (g & 1);
#pragma unroll
    for (int mj = 0; mj < 4; ++mj) {
        const bool mmj = (wih == 7) && (mj >= 2);
#pragma unroll
        for (int ni = 0; ni < 4; ++ni) {
            float4 b4 = *reinterpret_cast<const float4*>(bx + (ni * 16 + c) * 64 + mj * 16 + g * 4);
            const float bb[4] = {b4.x, b4.y, b4.z, b4.w};
#pragma unroll
            for (int jj = 0; jj < 4; ++jj) {
                float v = s[mj][ni][jj] * ATT_SCALE + bb[jj];
                s[mj][ni][jj] = (mmj || modd) ? -1e30f : v;
            }
        }
    }

#pragma unroll
    for (int ni = 0; ni < 4; ++ni) {
        float mx = -1e30f;
#pragma unroll
        for (int mj = 0; mj < 4; ++mj)
#pragma unroll
            for (int jj = 0; jj < 4; ++jj) mx = fmaxf(mx, s[mj][ni][jj]);
        mx = fmaxf(mx, __shfl_xor(mx, 16));
        mx = fmaxf(mx, __shfl_xor(mx, 32));
        float sum = 0.f;
#pragma unroll
        for (int mj = 0; mj < 4; ++mj)
#pragma unroll
            for (int jj = 0; jj < 4; ++jj) {
                float p = __expf(s[mj][ni][jj] - mx);
                s[mj][ni][jj] = p;
                sum += p;
            }
        sum += __shfl_xor(sum, 16);
        sum += __shfl_xor(sum, 32);
        float rinv = 1.0f / sum;
        const int i  = ni * 16 + c;
        const int ik = i & 7;
#pragma unroll
        for (int mj = 0; mj < 4; ++mj) {
            ushort4 pk;
            pk.x = f2bf(s[mj][ni][0] * rinv);
            pk.y = f2bf(s[mj][ni][1] * rinv);
            pk.z = f2bf(s[mj][ni][2] * rinv);
            pk.w = f2bf(s[mj][ni][3] * rinv);
            int chunk = (mj * 2 + (g >> 1)) ^ ik;
            *reinterpret_cast<ushort4*>((char*)&Pl[w][0] + i * 128 + chunk * 16 + (g & 1) * 8) = pk;
        }
    }

    bf16x8 vb[2][2];
#pragma unroll
    for (int nd = 0; nd < 2; ++nd)
#pragma unroll
        for (int kt = 0; kt < 2; ++kt)
            vb[nd][kt] = *reinterpret_cast<const bf16x8*>(
                VT + (size_t)(h * 32 + nd * 16 + c) * 32768 + win * 64 + kt * 32 + g * 8);
    f32x4 o[4][2];
#pragma unroll
    for (int mi = 0; mi < 4; ++mi)
#pragma unroll
        for (int nd = 0; nd < 2; ++nd) { o[mi][nd][0]=0.f; o[mi][nd][1]=0.f; o[mi][nd][2]=0.f; o[mi][nd][3]=0.f; }
#pragma unroll
    for (int mi = 0; mi < 4; ++mi) {
        const int i  = mi * 16 + c;
        const int ik = i & 7;
#pragma unroll
        for (int kt = 0; kt < 2; ++kt) {
            int chunk = (kt * 4 + g) ^ ik;
            bf16x8 pa = *reinterpret_cast<const bf16x8*>((char*)&Pl[w][0] + i * 128 + chunk * 16);
#pragma unroll
            for (int nd = 0; nd < 2; ++nd)
                o[mi][nd] = __builtin_amdgcn_mfma_f32_16x16x32_bf16(pa, vb[nd][kt], o[mi][nd], 0, 0, 0);
        }
    }

    unsigned short* aop = AO + qkbase;
#pragma unroll
    for (int mi = 0; mi < 4; ++mi)
#pragma unroll
        for (int nd = 0; nd < 2; ++nd)
#pragma unroll
            for (int jj = 0; jj < 4; ++jj)
                aop[(size_t)(mi * 16 + g * 4 + jj) * CC + nd * 16 + c] = f2bf(o[mi][nd][jj]);
}

// ---------------- residual add with inverse-window gather (bf16 delta) ----------------
__global__ void add_win_kernel(const float* __restrict__ xin, const unsigned short* __restrict__ OP,
                               const float* __restrict__ gamma, float* __restrict__ xout) {
    int tok  = (int)((blockIdx.x * blockDim.x + threadIdx.x) >> 6);
    int lane = threadIdx.x & 63;
    if (tok >= BN) return;
    int f  = tok / 3600;
    int p  = tok % 3600;
    int hi = p / 60, wi = p % 60;
    int hp = (hi + 56) % 60, wp = (wi + 56) % 60;
    int wih = hp >> 3, r = hp & 7, wiw = wp >> 3, s = wp & 7;
    size_t row = ((size_t)f * 64 + (size_t)(wih * 8 + wiw)) * 64 + (size_t)(r * 8 + s);
    float g = gamma[0];
    float4 a = reinterpret_cast<const float4*>(xin + (size_t)tok * CC)[lane];
    ushort4 ov = reinterpret_cast<const ushort4*>(OP + row * CC)[lane];
    float4 y = make_float4(a.x + g * bf2f(ov.x), a.y + g * bf2f(ov.y),
                           a.z + g * bf2f(ov.z), a.w + g * bf2f(ov.w));
    reinterpret_cast<float4*>(xout + (size_t)tok * CC)[lane] = y;
}

__global__ void add_plain_kernel(const float* __restrict__ xin, const unsigned short* __restrict__ hh,
                                 const float* __restrict__ gamma, float* __restrict__ xout, int nvec4) {
    int idx = (int)(blockIdx.x * blockDim.x + threadIdx.x);
    if (idx >= nvec4) return;
    float g = gamma[0];
    float4 a = reinterpret_cast<const float4*>(xin)[idx];
    ushort4 ov = reinterpret_cast<const ushort4*>(hh)[idx];
    reinterpret_cast<float4*>(xout)[idx] =
        make_float4(a.x + g * bf2f(ov.x), a.y + g * bf2f(ov.y),
                    a.z + g * bf2f(ov.z), a.w + g * bf2f(ov.w));
}

// ---------------- weight fp32 -> bf16 conversion ----------------
__global__ void cvt_all(const float* s0, const float* s1, const float* s2, const float* s3,
                        const float* s4, const float* s5, const float* s6, const float* s7,
                        const float* s8, const float* s9, unsigned short* __restrict__ dst) {
    const float* srcs[10] = {s0, s1, s2, s3, s4, s5, s6, s7, s8, s9};
    int blk = blockIdx.x;
    int wi = (blk < 512) ? (blk >> 6) : (blk < 768 ? 8 : 9);
    size_t start = (wi < 8) ? (size_t)wi * 65536 : (wi == 8 ? (size_t)524288 : (size_t)786432);
    size_t gidx = (size_t)blk * 1024 + (size_t)threadIdx.x * 4;
    float4 v = *reinterpret_cast<const float4*>(srcs[wi] + (gidx - start));
    ushort4 o;
    o.x = f2bf(v.x); o.y = f2bf(v.y); o.z = f2bf(v.z); o.w = f2bf(v.w);
    *reinterpret_cast<ushort4*>(dst + gidx) = o;
}

extern "C" void kernel_launch(void* const* d_in, const int* in_sizes, int n_in,
                              void* d_out, int out_size, void* d_ws, size_t ws_size,
                              hipStream_t stream) {
    const float* x    = (const float*)d_in[0];
    const float* ctx  = (const float*)d_in[1];
    const float* ln1w = (const float*)d_in[2];
    const float* ln1b = (const float*)d_in[3];
    const float* ln2w = (const float*)d_in[4];
    const float* ln2b = (const float*)d_in[5];
    const float* ln3w = (const float*)d_in[6];
    const float* ln3b = (const float*)d_in[7];
    const float* lncw = (const float*)d_in[8];
    const float* lncb = (const float*)d_in[9];
    const float* saqw = (const float*)d_in[10];
    const float* saqb = (const float*)d_in[11];
    const float* sakw = (const float*)d_in[12];
    const float* sakb = (const float*)d_in[13];
    const float* savw = (const float*)d_in[14];
    const float* savb = (const float*)d_in[15];
    const float* saow = (const float*)d_in[16];
    const float* saob = (const float*)d_in[17];
    const float* sabias = (const float*)d_in[18];
    const float* caqw = (const float*)d_in[19];
    const float* caqb = (const float*)d_in[20];
    const float* cakw = (const float*)d_in[21];
    const float* cakb = (const float*)d_in[22];
    const float* cavw = (const float*)d_in[23];
    const float* cavb = (const float*)d_in[24];
    const float* caow = (const float*)d_in[25];
    const float* caob = (const float*)d_in[26];
    const float* cabias = (const float*)d_in[27];
    const float* gamma1 = (const float*)d_in[28];
    const float* gamma2 = (const float*)d_in[29];
    const float* gammam = (const float*)d_in[30];
    const float* mw1 = (const float*)d_in[31];
    const float* mb1 = (const float*)d_in[32];
    const float* mw2 = (const float*)d_in[33];
    const float* mb2 = (const float*)d_in[34];

    float* ws = (float*)d_ws;
    unsigned short* LNbf = (unsigned short*)(ws);                 // 3,686,400 f
    unsigned short* Gq   = (unsigned short*)(ws + 3686400);       // 4,194,304 f
    unsigned short* Gkv  = (unsigned short*)(ws + 7880704);       // 4,194,304 f
    unsigned short* Qbf  = (unsigned short*)(ws + 12075008);      // 4,194,304 f
    unsigned short* Kbf  = (unsigned short*)(ws + 16269312);      // 4,194,304 f
    unsigned short* VTbf = (unsigned short*)(ws + 20463616);      // 4,194,304 f
    unsigned short* OPbf = (unsigned short*)(ws + 24657920);      // 4,194,304 f
    float* X1  = ws + 28852224;                                   // 7,372,800 f
    unsigned short* Wp = (unsigned short*)(ws + 36225024);        // 524,288 f
    float* biasx = ws + 36749312;                                 // 32,768 f
    unsigned short* H2bf = (unsigned short*)(ws + 36782080);      // 3,686,400 f
    unsigned short* AObf = Gq;                                    // alias (gathered act dead after proj)
    unsigned short* H1bf = Qbf;                                   // alias (Q/K/VT/OP dead in MLP phase)

    // cvt layout (contiguous): saq|sak|sav | sao | caq | cak|cav | cao | m1 | m2
    unsigned short* w_saqkv = Wp;                                 // [768][256]
    unsigned short* w_sao   = Wp + 196608;                        // [256][256]
    unsigned short* w_caq   = Wp + 262144;                        // [256][256]
    unsigned short* w_cakv  = Wp + 327680;                        // [512][256]
    unsigned short* w_cao   = Wp + 458752;                        // [256][256]
    unsigned short* w_m1    = Wp + 524288;                        // [1024][256]
    unsigned short* w_m2    = Wp + 786432;                        // [256][1024]

    float* OUT = (float*)d_out;

    dim3 blk(256);
    dim3 gLN(BN / 4);
    dim3 gGather(WROWS / 4);
    dim3 gAttn(WINS * 2);

    cvt_all<<<dim3(1024), blk, 0, stream>>>(saqw, sakw, savw, saow, caqw, cakw, cavw, caow, mw1, mw2, Wp);
    expand_bias<<<dim3(128), blk, 0, stream>>>(sabias, cabias, biasx);

    // ---- self attention ----
    ln_gather<<<gGather, blk, 0, stream>>>(x, ln1w, ln1b, Gq);
    gemm_wa<false><<<dim3(6, 256), blk, 0, stream>>>(w_saqkv, Gq, saqb, sakb, savb, savb,
                                                     Qbf, Kbf, VTbf, VTbf, CC, 2, CC);
    attn_mfma<<<gAttn, blk, 0, stream>>>(Qbf, Kbf, VTbf, biasx, AObf);
    gemm_wa<false><<<dim3(2, 256), blk, 0, stream>>>(w_sao, AObf, saob, saob, saob, saob,
                                                     OPbf, OPbf, OPbf, OPbf, CC, -1, CC);
    add_win_kernel<<<gLN, blk, 0, stream>>>(x, OPbf, gamma1, X1);

    // ---- cross attention ----
    ln_gather<<<gGather, blk, 0, stream>>>(X1, ln2w, ln2b, Gq);
    ln_gather<<<gGather, blk, 0, stream>>>(ctx, lncw, lncb, Gkv);
    gemm_wa<false><<<dim3(2, 256), blk, 0, stream>>>(w_caq, Gq, caqb, caqb, caqb, caqb,
                                                     Qbf, Qbf, Qbf, Qbf, CC, -1, CC);
    gemm_wa<false><<<dim3(4, 256), blk, 0, stream>>>(w_cakv, Gkv, cakb, cavb, cavb, cavb,
                                                     Kbf, VTbf, VTbf, VTbf, CC, 1, CC);
    attn_mfma<<<gAttn, blk, 0, stream>>>(Qbf, Kbf, VTbf, biasx + 16384, AObf);
    gemm_wa<false><<<dim3(2, 256), blk, 0, stream>>>(w_cao, AObf, caob, caob, caob, caob,
                                                     OPbf, OPbf, OPbf, OPbf, CC, -1, CC);
    add_win_kernel<<<gLN, blk, 0, stream>>>(X1, OPbf, gamma2, X1);

    // ---- MLP ----
    ln_kernel<<<gLN, blk, 0, stream>>>(X1, ln3w, ln3b, LNbf, BN);
    gemm_wa<true><<<dim3(8, 225), blk, 0, stream>>>(w_m1, LNbf, mb1, mb1 + 256, mb1 + 512, mb1 + 768,
                                                    H1bf, H1bf + 256, H1bf + 512, H1bf + 768,
                                                    HIDN, -1, CC);
    gemm_wa<false><<<dim3(2, 225), blk, 0, stream>>>(w_m2, H1bf, mb2, mb2, mb2, mb2,
                                                    H2bf, H2bf, H2bf, H2bf, CC, -1, HIDN);
    add_plain_kernel<<<dim3(BN * CC / 4 / 256), blk, 0, stream>>>(X1, H2bf, gammam, OUT, BN * CC / 4);
}

// Round 6
// 269.980 us; speedup vs baseline: 4.5795x; 1.0523x over previous
//
#include <hip/hip_runtime.h>
#include <math.h>

// ---- problem constants ----
#define BN    28800      // B*N tokens total
#define CC    256        // channels
#define HIDN  1024       // MLP hidden
#define WINS  512        // total windows (8 frames * 64)
#define WROWS (WINS*64)  // 32768 window rows
#define ATT_SCALE 0.1767766952966369f

typedef __bf16 bf16x8 __attribute__((ext_vector_type(8)));
typedef float  f32x4  __attribute__((ext_vector_type(4)));

__device__ __forceinline__ unsigned short f2bf(float f) {
    unsigned u = __float_as_uint(f);
    unsigned r = (u + 0x7FFFu + ((u >> 16) & 1u)) >> 16;
    return (unsigned short)r;
}
__device__ __forceinline__ float bf2f(unsigned short u) {
    return __uint_as_float((unsigned)u << 16);
}

// fast GELU (tanh form), overflow-safe: tanh(y) = 1 - 2/(exp(2y)+1)
__device__ __forceinline__ float gelu_f(float x) {
    float x3 = x * x * x;
    float e  = __expf(1.5957691216057308f * (x + 0.044715f * x3));  // exp(2y)
    float th = 1.0f - 2.0f / (e + 1.0f);
    return 0.5f * x * (1.0f + th);
}

__device__ __forceinline__ void gl_lds16(const void* g, void* l) {
    __builtin_amdgcn_global_load_lds(
        (const __attribute__((address_space(1))) void*)g,
        (__attribute__((address_space(3))) void*)l, 16, 0, 0);
}

// ---------------- LayerNorm (plain): one wave per token, bf16 out ----------------
__global__ void ln_kernel(const float* __restrict__ x, const float* __restrict__ w,
                          const float* __restrict__ b, unsigned short* __restrict__ out, int ntok) {
    int tok  = (int)((blockIdx.x * blockDim.x + threadIdx.x) >> 6);
    int lane = threadIdx.x & 63;
    if (tok >= ntok) return;
    float4 v = reinterpret_cast<const float4*>(x + (size_t)tok * CC)[lane];
    float s  = v.x + v.y + v.z + v.w;
    float s2 = v.x*v.x + v.y*v.y + v.z*v.z + v.w*v.w;
#pragma unroll
    for (int off = 32; off >= 1; off >>= 1) {
        s  += __shfl_xor(s, off);
        s2 += __shfl_xor(s2, off);
    }
    float mean = s * (1.0f / CC);
    float var  = s2 * (1.0f / CC) - mean * mean;
    float rs   = rsqrtf(var + 1e-5f);
    float4 wv = reinterpret_cast<const float4*>(w)[lane];
    float4 bv = reinterpret_cast<const float4*>(b)[lane];
    ushort4 o;
    o.x = f2bf((v.x - mean) * rs * wv.x + bv.x);
    o.y = f2bf((v.y - mean) * rs * wv.y + bv.y);
    o.z = f2bf((v.z - mean) * rs * wv.z + bv.z);
    o.w = f2bf((v.w - mean) * rs * wv.w + bv.w);
    reinterpret_cast<ushort4*>(out + (size_t)tok * CC)[lane] = o;
}

// ---------------- fused LayerNorm + window gather ----------------
__global__ void ln_gather(const float* __restrict__ x, const float* __restrict__ w,
                          const float* __restrict__ b, unsigned short* __restrict__ dst) {
    int row  = (int)((blockIdx.x * blockDim.x + threadIdx.x) >> 6);
    int lane = threadIdx.x & 63;
    if (row >= WROWS) return;
    int win = row >> 6, l = row & 63;
    int f   = win >> 6;
    int wih = (win >> 3) & 7, wiw = win & 7;
    int r = l >> 3, s = l & 7;
    int h = wih * 8 + r, wc = wiw * 8 + s;
    if (h >= 60 || wc >= 60) {
        ushort4 z = {0, 0, 0, 0};
        reinterpret_cast<ushort4*>(dst + (size_t)row * CC)[lane] = z;
        return;
    }
    int oh = (h + 4) % 60, ow = (wc + 4) % 60;
    size_t tok = (size_t)f * 3600 + (size_t)oh * 60 + ow;
    float4 v = reinterpret_cast<const float4*>(x + tok * CC)[lane];
    float sm  = v.x + v.y + v.z + v.w;
    float s2 = v.x*v.x + v.y*v.y + v.z*v.z + v.w*v.w;
#pragma unroll
    for (int off = 32; off >= 1; off >>= 1) {
        sm += __shfl_xor(sm, off);
        s2 += __shfl_xor(s2, off);
    }
    float mean = sm * (1.0f / CC);
    float var  = s2 * (1.0f / CC) - mean * mean;
    float rs   = rsqrtf(var + 1e-5f);
    float4 wv = reinterpret_cast<const float4*>(w)[lane];
    float4 bv = reinterpret_cast<const float4*>(b)[lane];
    ushort4 o;
    o.x = f2bf((v.x - mean) * rs * wv.x + bv.x);
    o.y = f2bf((v.y - mean) * rs * wv.y + bv.y);
    o.z = f2bf((v.z - mean) * rs * wv.z + bv.z);
    o.w = f2bf((v.w - mean) * rs * wv.w + bv.w);
    reinterpret_cast<ushort4*>(dst + (size_t)row * CC)[lane] = o;
}

// stage one 128x32 A-tile + B-tile into LDS (global_load_lds, pre-swizzled source)
__device__ __forceinline__ void stage_tile(const unsigned short* __restrict__ Wt,
                                           const unsigned short* __restrict__ Act,
                                           int m0, int n0, int K, int k0,
                                           unsigned short* dA, unsigned short* dB,
                                           int t, int w) {
#pragma unroll
    for (int p = 0; p < 2; ++p) {
        int c   = p * 256 + t;
        int row = c >> 2;
        int gl  = (c & 3) ^ ((row >> 1) & 3);
        gl_lds16(Wt  + (size_t)(m0 + row) * K + k0 + gl * 8,
                 (char*)dA + (p * 256 + w * 64) * 16);
        gl_lds16(Act + (size_t)(n0 + row) * K + k0 + gl * 8,
                 (char*)dB + (p * 256 + w * 64) * 16);
    }
}

// ---------------- bf16 MFMA GEMM, weights-as-A, double-buffered, LDS-transposed epilogue
template <bool GELU>
__global__ __launch_bounds__(256) void gemm_wa(
        const unsigned short* __restrict__ Wt,   // [Mtot][K] bf16
        const unsigned short* __restrict__ Act,  // [Ntok][K] bf16
        const float* __restrict__ b0, const float* __restrict__ b1,
        const float* __restrict__ b2, const float* __restrict__ b3,
        unsigned short* __restrict__ o0, unsigned short* __restrict__ o1,
        unsigned short* __restrict__ o2, unsigned short* __restrict__ o3,
        int strideO, int vseg, int K) {
    __shared__ __align__(16) char pool[32768];
    unsigned short* A0 = (unsigned short*)pool;
    unsigned short* B0 = (unsigned short*)(pool + 8192);
    unsigned short* A1 = (unsigned short*)(pool + 16384);
    unsigned short* B1 = (unsigned short*)(pool + 24576);
    unsigned short* Cs = (unsigned short*)pool;            // 32 KB (after final barrier)

    const int t = threadIdx.x;
    const int w = t >> 6, l = t & 63;
    // ---- bijective XCD swizzle: m fastest within an XCD ----
    const int Mb = gridDim.x;
    int lin = blockIdx.y * Mb + blockIdx.x;
    int T = Mb * gridDim.y;
    int q = T >> 3, rr = T & 7;
    int xcd = lin & 7, slot = lin >> 3;
    int wid = (xcd < rr) ? (xcd * (q + 1) + slot)
                         : (rr * (q + 1) + (xcd - rr) * q + slot);
    const int m0 = (wid % Mb) * 128;
    const int n0 = (wid / Mb) * 128;

    const int wr = w >> 1, wc = w & 1;
    const int r = l & 15, g = l >> 4;
    const int sw = (r >> 1) & 3;
    const int gp = (g ^ sw) * 8;
    f32x4 acc[4][4];
#pragma unroll
    for (int i = 0; i < 4; ++i)
#pragma unroll
        for (int j = 0; j < 4; ++j) { acc[i][j][0]=0.f; acc[i][j][1]=0.f; acc[i][j][2]=0.f; acc[i][j][3]=0.f; }

    // ---- double-buffered K-loop ----
    stage_tile(Wt, Act, m0, n0, K, 0, A0, B0, t, w);
    unsigned short *cA = A0, *cB = B0, *nA = A1, *nB = B1;
    __syncthreads();
    const int nt = K >> 5;
    for (int kt = 0; kt < nt; ++kt) {
        if (kt + 1 < nt)
            stage_tile(Wt, Act, m0, n0, K, (kt + 1) * 32, nA, nB, t, w);
        bf16x8 af[4], bw[4];
#pragma unroll
        for (int m = 0; m < 4; ++m)
            af[m] = *reinterpret_cast<const bf16x8*>(&cA[(wr * 64 + m * 16 + r) * 32 + gp]);
#pragma unroll
        for (int n = 0; n < 4; ++n)
            bw[n] = *reinterpret_cast<const bf16x8*>(&cB[(wc * 64 + n * 16 + r) * 32 + gp]);
#pragma unroll
        for (int m = 0; m < 4; ++m)
#pragma unroll
            for (int n = 0; n < 4; ++n)
                acc[m][n] = __builtin_amdgcn_mfma_f32_16x16x32_bf16(af[m], bw[n], acc[m][n], 0, 0, 0);
        __syncthreads();   // drains this iteration's stage (vmcnt 0) + read fences
        unsigned short* sA = cA; cA = nA; nA = sA;
        unsigned short* sB = cB; cB = nB; nB = sB;
    }

    // ---- epilogue ----
    const int seg = m0 >> 8;
    const float* bp = (seg == 0) ? b0 : (seg == 1) ? b1 : (seg == 2) ? b2 : b3;
    unsigned short* op = (seg == 0) ? o0 : (seg == 1) ? o1 : (seg == 2) ? o2 : o3;
    const int chseg = m0 & 255;

    if (seg == vseg) {
        // direct transposed store [ch][32768] (V^T for attention)
#pragma unroll
        for (int m = 0; m < 4; ++m) {
            const int ch0 = chseg + wr * 64 + m * 16 + g * 4;
            float4 b4 = *reinterpret_cast<const float4*>(bp + ch0);
            const float bb[4] = {b4.x, b4.y, b4.z, b4.w};
#pragma unroll
            for (int n = 0; n < 4; ++n) {
                const int tok = n0 + wc * 64 + n * 16 + r;
#pragma unroll
                for (int j = 0; j < 4; ++j)
                    op[(size_t)(ch0 + j) * 32768 + tok] = f2bf(acc[m][n][j] + bb[j]);
            }
        }
        return;
    }

    // (last K-iteration ended with __syncthreads: safe to overwrite pool with Cs)
#pragma unroll
    for (int m = 0; m < 4; ++m) {
        const int ch0 = wr * 64 + m * 16 + g * 4;       // local 0..127
        float4 b4 = *reinterpret_cast<const float4*>(bp + chseg + ch0);
        const float bb[4] = {b4.x, b4.y, b4.z, b4.w};
#pragma unroll
        for (int n = 0; n < 4; ++n) {
            const int tok_l = wc * 64 + n * 16 + r;     // local 0..127
            float cv[4];
#pragma unroll
            for (int j = 0; j < 4; ++j) {
                cv[j] = acc[m][n][j] + bb[j];
                if (GELU) cv[j] = gelu_f(cv[j]);
            }
            ushort4 pk;
            pk.x = f2bf(cv[0]); pk.y = f2bf(cv[1]); pk.z = f2bf(cv[2]); pk.w = f2bf(cv[3]);
            int gran = (ch0 >> 2) ^ ((tok_l & 15) << 1);
            reinterpret_cast<ushort4*>(Cs)[tok_l * 32 + gran] = pk;
        }
    }
    __syncthreads();
    // coalesced store: 16 lanes x 16B = 256 B contiguous per token row
    const int u = t & 15, trow = t >> 4;
#pragma unroll
    for (int it = 0; it < 8; ++it) {
        int tok_l = it * 16 + trow;
        int up = u ^ (tok_l & 15);
        uint4 v = reinterpret_cast<const uint4*>(Cs)[tok_l * 16 + up];
        *reinterpret_cast<uint4*>(op + (size_t)(n0 + tok_l) * strideO + chseg + u * 8) = v;
    }
}

// ---------------- bias table expansion: biasx[2][8][64][64] ----------------
__global__ void expand_bias(const float* __restrict__ sa, const float* __restrict__ ca,
                            float* __restrict__ dst) {
    int e = (int)(blockIdx.x * blockDim.x + threadIdx.x);   // 0..32767
    const float* src = (e < 16384) ? sa : ca;
    int e2 = e & 16383;
    int h = e2 >> 12, ij = e2 & 4095, i = ij >> 6, j = ij & 63;
    int ri = i >> 3, si = i & 7, rj = j >> 3, sj = j & 7;
    dst[e] = src[((ri - rj + 7) * 15 + (si - sj + 7)) * 8 + h];
}

// ---------------- MFMA attention: one wave per (window, head) ----------------
__global__ __launch_bounds__(256) void attn_mfma(
        const unsigned short* __restrict__ Q,   // [32768][256] bf16
        const unsigned short* __restrict__ K,   // [32768][256] bf16
        const unsigned short* __restrict__ VT,  // [256][32768] bf16
        const float* __restrict__ biasx,        // [8][64][64] f32
        unsigned short* __restrict__ AO) {      // [32768][256] bf16
    __shared__ __align__(16) unsigned short Pl[4][64 * 64];
    const int t = threadIdx.x;
    const int w = t >> 6, l = t & 63;
    const int win = blockIdx.x >> 1;
    const int h   = (blockIdx.x & 1) * 4 + w;
    const int c = l & 15, g = l >> 4;
    const int wih = (win >> 3) & 7, wiw = win & 7;
    const size_t qkbase = (size_t)win * 64 * CC + (size_t)h * 32;

    bf16x8 ka[4], qb[4];
#pragma unroll
    for (int mj = 0; mj < 4; ++mj)
        ka[mj] = *reinterpret_cast<const bf16x8*>(K + qkbase + (size_t)(mj * 16 + c) * CC + g * 8);
#pragma unroll
    for (int ni = 0; ni < 4; ++ni)
        qb[ni] = *reinterpret_cast<const bf16x8*>(Q + qkbase + (size_t)(ni * 16 + c) * CC + g * 8);
    f32x4 s[4][4];
#pragma unroll
    for (int mj = 0; mj < 4; ++mj)
#pragma unroll
        for (int ni = 0; ni < 4; ++ni) { s[mj][ni][0]=0.f; s[mj][ni][1]=0.f; s[mj][ni][2]=0.f; s[mj][ni][3]=0.f; }
#pragma unroll
    for (int mj = 0; mj < 4; ++mj)
#pragma unroll
        for (int ni = 0; ni < 4; ++ni)
            s[mj][ni] = __builtin_amdgcn_mfma_f32_16x16x32_bf16(ka[mj], qb[ni], s[mj][ni], 0, 0, 0);

    const float* bx = biasx + h * 4096;
    const bool modd = (wiw == 7) && (g & 1);
#pragma unroll
    for (int mj = 0; mj < 4; ++mj) {
        const bool mmj = (wih == 7) && (mj >= 2);
#pragma unroll
        for (int ni = 0; ni < 4; ++ni) {
            float4 b4 = *reinterpret_cast<const float4*>(bx + (ni * 16 + c) * 64 + mj * 16 + g * 4);
            const float bb[4] = {b4.x, b4.y, b4.z, b4.w};
#pragma unroll
            for (int jj = 0; jj < 4; ++jj) {
                float v = s[mj][ni][jj] * ATT_SCALE + bb[jj];
                s[mj][ni][jj] = (mmj || modd) ? -1e30f : v;
            }
        }
    }

#pragma unroll
    for (int ni = 0; ni < 4; ++ni) {
        float mx = -1e30f;
#pragma unroll
        for (int mj = 0; mj < 4; ++mj)
#pragma unroll
            for (int jj = 0; jj < 4; ++jj) mx = fmaxf(mx, s[mj][ni][jj]);
        mx = fmaxf(mx, __shfl_xor(mx, 16));
        mx = fmaxf(mx, __shfl_xor(mx, 32));
        float sum = 0.f;
#pragma unroll
        for (int mj = 0; mj < 4; ++mj)
#pragma unroll
            for (int jj = 0; jj < 4; ++jj) {
                float p = __expf(s[mj][ni][jj] - mx);
                s[mj][ni][jj] = p;
                sum += p;
            }
        sum += __shfl_xor(sum, 16);
        sum += __shfl_xor(sum, 32);
        float rinv = 1.0f / sum;
        const int i  = ni * 16 + c;
        const int ik = i & 7;
#pragma unroll
        for (int mj = 0; mj < 4; ++mj) {
            ushort4 pk;
            pk.x = f2bf(s[mj][ni][0] * rinv);
            pk.y = f2bf(s[mj][ni][1] * rinv);
            pk.z = f2bf(s[mj][ni][2] * rinv);
            pk.w = f2bf(s[mj][ni][3] * rinv);
            int chunk = (mj * 2 + (g >> 1)) ^ ik;
            *reinterpret_cast<ushort4*>((char*)&Pl[w][0] + i * 128 + chunk * 16 + (g & 1) * 8) = pk;
        }
    }

    bf16x8 vb[2][2];
#pragma unroll
    for (int nd = 0; nd < 2; ++nd)
#pragma unroll
        for (int kt = 0; kt < 2; ++kt)
            vb[nd][kt] = *reinterpret_cast<const bf16x8*>(
                VT + (size_t)(h * 32 + nd * 16 + c) * 32768 + win * 64 + kt * 32 + g * 8);
    f32x4 o[4][2];
#pragma unroll
    for (int mi = 0; mi < 4; ++mi)
#pragma unroll
        for (int nd = 0; nd < 2; ++nd) { o[mi][nd][0]=0.f; o[mi][nd][1]=0.f; o[mi][nd][2]=0.f; o[mi][nd][3]=0.f; }
#pragma unroll
    for (int mi = 0; mi < 4; ++mi) {
        const int i  = mi * 16 + c;
        const int ik = i & 7;
#pragma unroll
        for (int kt = 0; kt < 2; ++kt) {
            int chunk = (kt * 4 + g) ^ ik;
            bf16x8 pa = *reinterpret_cast<const bf16x8*>((char*)&Pl[w][0] + i * 128 + chunk * 16);
#pragma unroll
            for (int nd = 0; nd < 2; ++nd)
                o[mi][nd] = __builtin_amdgcn_mfma_f32_16x16x32_bf16(pa, vb[nd][kt], o[mi][nd], 0, 0, 0);
        }
    }

    unsigned short* aop = AO + qkbase;
#pragma unroll
    for (int mi = 0; mi < 4; ++mi)
#pragma unroll
        for (int nd = 0; nd < 2; ++nd)
#pragma unroll
            for (int jj = 0; jj < 4; ++jj)
                aop[(size_t)(mi * 16 + g * 4 + jj) * CC + nd * 16 + c] = f2bf(o[mi][nd][jj]);
}

// ---------------- residual add with inverse-window gather (bf16 delta) ----------------
__global__ void add_win_kernel(const float* __restrict__ xin, const unsigned short* __restrict__ OP,
                               const float* __restrict__ gamma, float* __restrict__ xout) {
    int tok  = (int)((blockIdx.x * blockDim.x + threadIdx.x) >> 6);
    int lane = threadIdx.x & 63;
    if (tok >= BN) return;
    int f  = tok / 3600;
    int p  = tok % 3600;
    int hi = p / 60, wi = p % 60;
    int hp = (hi + 56) % 60, wp = (wi + 56) % 60;
    int wih = hp >> 3, r = hp & 7, wiw = wp >> 3, s = wp & 7;
    size_t row = ((size_t)f * 64 + (size_t)(wih * 8 + wiw)) * 64 + (size_t)(r * 8 + s);
    float g = gamma[0];
    float4 a = reinterpret_cast<const float4*>(xin + (size_t)tok * CC)[lane];
    ushort4 ov = reinterpret_cast<const ushort4*>(OP + row * CC)[lane];
    float4 y = make_float4(a.x + g * bf2f(ov.x), a.y + g * bf2f(ov.y),
                           a.z + g * bf2f(ov.z), a.w + g * bf2f(ov.w));
    reinterpret_cast<float4*>(xout + (size_t)tok * CC)[lane] = y;
}

__global__ void add_plain_kernel(const float* __restrict__ xin, const unsigned short* __restrict__ hh,
                                 const float* __restrict__ gamma, float* __restrict__ xout, int nvec4) {
    int idx = (int)(blockIdx.x * blockDim.x + threadIdx.x);
    if (idx >= nvec4) return;
    float g = gamma[0];
    float4 a = reinterpret_cast<const float4*>(xin)[idx];
    ushort4 ov = reinterpret_cast<const ushort4*>(hh)[idx];
    reinterpret_cast<float4*>(xout)[idx] =
        make_float4(a.x + g * bf2f(ov.x), a.y + g * bf2f(ov.y),
                    a.z + g * bf2f(ov.z), a.w + g * bf2f(ov.w));
}

// ---------------- weight fp32 -> bf16 conversion ----------------
__global__ void cvt_all(const float* s0, const float* s1, const float* s2, const float* s3,
                        const float* s4, const float* s5, const float* s6, const float* s7,
                        const float* s8, const float* s9, unsigned short* __restrict__ dst) {
    const float* srcs[10] = {s0, s1, s2, s3, s4, s5, s6, s7, s8, s9};
    int blk = blockIdx.x;
    int wi = (blk < 512) ? (blk >> 6) : (blk < 768 ? 8 : 9);
    size_t start = (wi < 8) ? (size_t)wi * 65536 : (wi == 8 ? (size_t)524288 : (size_t)786432);
    size_t gidx = (size_t)blk * 1024 + (size_t)threadIdx.x * 4;
    float4 v = *reinterpret_cast<const float4*>(srcs[wi] + (gidx - start));
    ushort4 o;
    o.x = f2bf(v.x); o.y = f2bf(v.y); o.z = f2bf(v.z); o.w = f2bf(v.w);
    *reinterpret_cast<ushort4*>(dst + gidx) = o;
}

extern "C" void kernel_launch(void* const* d_in, const int* in_sizes, int n_in,
                              void* d_out, int out_size, void* d_ws, size_t ws_size,
                              hipStream_t stream) {
    const float* x    = (const float*)d_in[0];
    const float* ctx  = (const float*)d_in[1];
    const float* ln1w = (const float*)d_in[2];
    const float* ln1b = (const float*)d_in[3];
    const float* ln2w = (const float*)d_in[4];
    const float* ln2b = (const float*)d_in[5];
    const float* ln3w = (const float*)d_in[6];
    const float* ln3b = (const float*)d_in[7];
    const float* lncw = (const float*)d_in[8];
    const float* lncb = (const float*)d_in[9];
    const float* saqw = (const float*)d_in[10];
    const float* saqb = (const float*)d_in[11];
    const float* sakw = (const float*)d_in[12];
    const float* sakb = (const float*)d_in[13];
    const float* savw = (const float*)d_in[14];
    const float* savb = (const float*)d_in[15];
    const float* saow = (const float*)d_in[16];
    const float* saob = (const float*)d_in[17];
    const float* sabias = (const float*)d_in[18];
    const float* caqw = (const float*)d_in[19];
    const float* caqb = (const float*)d_in[20];
    const float* cakw = (const float*)d_in[21];
    const float* cakb = (const float*)d_in[22];
    const float* cavw = (const float*)d_in[23];
    const float* cavb = (const float*)d_in[24];
    const float* caow = (const float*)d_in[25];
    const float* caob = (const float*)d_in[26];
    const float* cabias = (const float*)d_in[27];
    const float* gamma1 = (const float*)d_in[28];
    const float* gamma2 = (const float*)d_in[29];
    const float* gammam = (const float*)d_in[30];
    const float* mw1 = (const float*)d_in[31];
    const float* mb1 = (const float*)d_in[32];
    const float* mw2 = (const float*)d_in[33];
    const float* mb2 = (const float*)d_in[34];

    float* ws = (float*)d_ws;
    unsigned short* LNbf = (unsigned short*)(ws);                 // 3,686,400 f
    unsigned short* Gq   = (unsigned short*)(ws + 3686400);       // 4,194,304 f
    unsigned short* Gkv  = (unsigned short*)(ws + 7880704);       // 4,194,304 f
    unsigned short* Qbf  = (unsigned short*)(ws + 12075008);      // 4,194,304 f
    unsigned short* Kbf  = (unsigned short*)(ws + 16269312);      // 4,194,304 f
    unsigned short* VTbf = (unsigned short*)(ws + 20463616);      // 4,194,304 f
    unsigned short* OPbf = (unsigned short*)(ws + 24657920);      // 4,194,304 f
    float* X1  = ws + 28852224;                                   // 7,372,800 f
    unsigned short* Wp = (unsigned short*)(ws + 36225024);        // 524,288 f
    float* biasx = ws + 36749312;                                 // 32,768 f
    unsigned short* H2bf = (unsigned short*)(ws + 36782080);      // 3,686,400 f
    unsigned short* AObf = Gq;                                    // alias (gathered act dead after proj)
    unsigned short* H1bf = Qbf;                                   // alias (Q/K/VT/OP dead in MLP phase)

    // cvt layout (contiguous): saq|sak|sav | sao | caq | cak|cav | cao | m1 | m2
    unsigned short* w_saqkv = Wp;                                 // [768][256]
    unsigned short* w_sao   = Wp + 196608;                        // [256][256]
    unsigned short* w_caq   = Wp + 262144;                        // [256][256]
    unsigned short* w_cakv  = Wp + 327680;                        // [512][256]
    unsigned short* w_cao   = Wp + 458752;                        // [256][256]
    unsigned short* w_m1    = Wp + 524288;                        // [1024][256]
    unsigned short* w_m2    = Wp + 786432;                        // [256][1024]

    float* OUT = (float*)d_out;

    dim3 blk(256);
    dim3 gLN(BN / 4);
    dim3 gGather(WROWS / 4);
    dim3 gAttn(WINS * 2);

    cvt_all<<<dim3(1024), blk, 0, stream>>>(saqw, sakw, savw, saow, caqw, cakw, cavw, caow, mw1, mw2, Wp);
    expand_bias<<<dim3(128), blk, 0, stream>>>(sabias, cabias, biasx);

    // ---- self attention ----
    ln_gather<<<gGather, blk, 0, stream>>>(x, ln1w, ln1b, Gq);
    gemm_wa<false><<<dim3(6, 256), blk, 0, stream>>>(w_saqkv, Gq, saqb, sakb, savb, savb,
                                                     Qbf, Kbf, VTbf, VTbf, CC, 2, CC);
    attn_mfma<<<gAttn, blk, 0, stream>>>(Qbf, Kbf, VTbf, biasx, AObf);
    gemm_wa<false><<<dim3(2, 256), blk, 0, stream>>>(w_sao, AObf, saob, saob, saob, saob,
                                                     OPbf, OPbf, OPbf, OPbf, CC, -1, CC);
    add_win_kernel<<<gLN, blk, 0, stream>>>(x, OPbf, gamma1, X1);

    // ---- cross attention ----
    ln_gather<<<gGather, blk, 0, stream>>>(X1, ln2w, ln2b, Gq);
    ln_gather<<<gGather, blk, 0, stream>>>(ctx, lncw, lncb, Gkv);
    gemm_wa<false><<<dim3(2, 256), blk, 0, stream>>>(w_caq, Gq, caqb, caqb, caqb, caqb,
                                                     Qbf, Qbf, Qbf, Qbf, CC, -1, CC);
    gemm_wa<false><<<dim3(4, 256), blk, 0, stream>>>(w_cakv, Gkv, cakb, cavb, cavb, cavb,
                                                     Kbf, VTbf, VTbf, VTbf, CC, 1, CC);
    attn_mfma<<<gAttn, blk, 0, stream>>>(Qbf, Kbf, VTbf, biasx + 16384, AObf);
    gemm_wa<false><<<dim3(2, 256), blk, 0, stream>>>(w_cao, AObf, caob, caob, caob, caob,
                                                     OPbf, OPbf, OPbf, OPbf, CC, -1, CC);
    add_win_kernel<<<gLN, blk, 0, stream>>>(X1, OPbf, gamma2, X1);

    // ---- MLP ----
    ln_kernel<<<gLN, blk, 0, stream>>>(X1, ln3w, ln3b, LNbf, BN);
    gemm_wa<true><<<dim3(8, 225), blk, 0, stream>>>(w_m1, LNbf, mb1, mb1 + 256, mb1 + 512, mb1 + 768,
                                                    H1bf, H1bf + 256, H1bf + 512, H1bf + 768,
                                                    HIDN, -1, CC);
    gemm_wa<false><<<dim3(2, 225), blk, 0, stream>>>(w_m2, H1bf, mb2, mb2, mb2, mb2,
                                                    H2bf, H2bf, H2bf, H2bf, CC, -1, HIDN);
    add_plain_kernel<<<dim3(BN * CC / 4 / 256), blk, 0, stream>>>(X1, H2bf, gammam, OUT, BN * CC / 4);
}

// Round 7
// 247.679 us; speedup vs baseline: 4.9919x; 1.0900x over previous
//
#include <hip/hip_runtime.h>
#include <math.h>

// ---- problem constants ----
#define BN    28800      // B*N tokens total
#define CC    256        // channels
#define HIDN  1024       // MLP hidden
#define WINS  512        // total windows (8 frames * 64)
#define WROWS (WINS*64)  // 32768 window rows
#define ATT_SCALE 0.1767766952966369f

typedef __bf16 bf16x8 __attribute__((ext_vector_type(8)));
typedef float  f32x4  __attribute__((ext_vector_type(4)));

__device__ __forceinline__ unsigned short f2bf(float f) {
    unsigned u = __float_as_uint(f);
    unsigned r = (u + 0x7FFFu + ((u >> 16) & 1u)) >> 16;
    return (unsigned short)r;
}
__device__ __forceinline__ float bf2f(unsigned short u) {
    return __uint_as_float((unsigned)u << 16);
}

// fast GELU (tanh form), overflow-safe: tanh(y) = 1 - 2/(exp(2y)+1)
__device__ __forceinline__ float gelu_f(float x) {
    float x3 = x * x * x;
    float e  = __expf(1.5957691216057308f * (x + 0.044715f * x3));  // exp(2y)
    float th = 1.0f - 2.0f / (e + 1.0f);
    return 0.5f * x * (1.0f + th);
}

__device__ __forceinline__ void gl_lds16(const void* g, void* l) {
    __builtin_amdgcn_global_load_lds(
        (const __attribute__((address_space(1))) void*)g,
        (__attribute__((address_space(3))) void*)l, 16, 0, 0);
}

// ---------------- LayerNorm (plain): one wave per token, bf16 out ----------------
__global__ void ln_kernel(const float* __restrict__ x, const float* __restrict__ w,
                          const float* __restrict__ b, unsigned short* __restrict__ out, int ntok) {
    int tok  = (int)((blockIdx.x * blockDim.x + threadIdx.x) >> 6);
    int lane = threadIdx.x & 63;
    if (tok >= ntok) return;
    float4 v = reinterpret_cast<const float4*>(x + (size_t)tok * CC)[lane];
    float s  = v.x + v.y + v.z + v.w;
    float s2 = v.x*v.x + v.y*v.y + v.z*v.z + v.w*v.w;
#pragma unroll
    for (int off = 32; off >= 1; off >>= 1) {
        s  += __shfl_xor(s, off);
        s2 += __shfl_xor(s2, off);
    }
    float mean = s * (1.0f / CC);
    float var  = s2 * (1.0f / CC) - mean * mean;
    float rs   = rsqrtf(var + 1e-5f);
    float4 wv = reinterpret_cast<const float4*>(w)[lane];
    float4 bv = reinterpret_cast<const float4*>(b)[lane];
    ushort4 o;
    o.x = f2bf((v.x - mean) * rs * wv.x + bv.x);
    o.y = f2bf((v.y - mean) * rs * wv.y + bv.y);
    o.z = f2bf((v.z - mean) * rs * wv.z + bv.z);
    o.w = f2bf((v.w - mean) * rs * wv.w + bv.w);
    reinterpret_cast<ushort4*>(out + (size_t)tok * CC)[lane] = o;
}

// ---------------- fused LayerNorm + window gather ----------------
__global__ void ln_gather(const float* __restrict__ x, const float* __restrict__ w,
                          const float* __restrict__ b, unsigned short* __restrict__ dst) {
    int row  = (int)((blockIdx.x * blockDim.x + threadIdx.x) >> 6);
    int lane = threadIdx.x & 63;
    if (row >= WROWS) return;
    int win = row >> 6, l = row & 63;
    int f   = win >> 6;
    int wih = (win >> 3) & 7, wiw = win & 7;
    int r = l >> 3, s = l & 7;
    int h = wih * 8 + r, wc = wiw * 8 + s;
    if (h >= 60 || wc >= 60) {
        ushort4 z = {0, 0, 0, 0};
        reinterpret_cast<ushort4*>(dst + (size_t)row * CC)[lane] = z;
        return;
    }
    int oh = (h + 4) % 60, ow = (wc + 4) % 60;
    size_t tok = (size_t)f * 3600 + (size_t)oh * 60 + ow;
    float4 v = reinterpret_cast<const float4*>(x + tok * CC)[lane];
    float sm  = v.x + v.y + v.z + v.w;
    float s2 = v.x*v.x + v.y*v.y + v.z*v.z + v.w*v.w;
#pragma unroll
    for (int off = 32; off >= 1; off >>= 1) {
        sm += __shfl_xor(sm, off);
        s2 += __shfl_xor(s2, off);
    }
    float mean = sm * (1.0f / CC);
    float var  = s2 * (1.0f / CC) - mean * mean;
    float rs   = rsqrtf(var + 1e-5f);
    float4 wv = reinterpret_cast<const float4*>(w)[lane];
    float4 bv = reinterpret_cast<const float4*>(b)[lane];
    ushort4 o;
    o.x = f2bf((v.x - mean) * rs * wv.x + bv.x);
    o.y = f2bf((v.y - mean) * rs * wv.y + bv.y);
    o.z = f2bf((v.z - mean) * rs * wv.z + bv.z);
    o.w = f2bf((v.w - mean) * rs * wv.w + bv.w);
    reinterpret_cast<ushort4*>(dst + (size_t)row * CC)[lane] = o;
}

// stage one 128x32 A-tile + B-tile into LDS (global_load_lds, pre-swizzled source)
__device__ __forceinline__ void stage_tile(const unsigned short* __restrict__ Wt,
                                           const unsigned short* __restrict__ Act,
                                           int m0, int n0, int K, int k0,
                                           unsigned short* dA, unsigned short* dB,
                                           int t, int w) {
#pragma unroll
    for (int p = 0; p < 2; ++p) {
        int c   = p * 256 + t;
        int row = c >> 2;
        int gl  = (c & 3) ^ ((row >> 1) & 3);
        gl_lds16(Wt  + (size_t)(m0 + row) * K + k0 + gl * 8,
                 (char*)dA + (p * 256 + w * 64) * 16);
        gl_lds16(Act + (size_t)(n0 + row) * K + k0 + gl * 8,
                 (char*)dB + (p * 256 + w * 64) * 16);
    }
}

// ---------------- bf16 MFMA GEMM, weights-as-A, counted-vmcnt pipeline ----------------
// FUSE: 0 = bf16 out [tok][strideO] (vseg segment stores V^T [ch][32768]);
//       1 = f32 residual out with inverse-window scatter (fout = xres + gamma*val);
//       2 = f32 plain residual out.
template <bool GELU, int FUSE>
__global__ __launch_bounds__(256) void gemm_wa(
        const unsigned short* __restrict__ Wt,   // [Mtot][K] bf16
        const unsigned short* __restrict__ Act,  // [Ntok][K] bf16
        const float* __restrict__ b0, const float* __restrict__ b1,
        const float* __restrict__ b2, const float* __restrict__ b3,
        unsigned short* __restrict__ o0, unsigned short* __restrict__ o1,
        unsigned short* __restrict__ o2, unsigned short* __restrict__ o3,
        int strideO, int vseg, int K,
        const float* __restrict__ xres, const float* __restrict__ gammap,
        float* __restrict__ fout) {
    __shared__ __align__(16) char pool[32768];
    unsigned short* A0 = (unsigned short*)pool;
    unsigned short* B0 = (unsigned short*)(pool + 8192);
    unsigned short* A1 = (unsigned short*)(pool + 16384);
    unsigned short* B1 = (unsigned short*)(pool + 24576);
    unsigned short* Cs = (unsigned short*)pool;            // 32 KB (after final barrier)

    const int t = threadIdx.x;
    const int w = t >> 6, l = t & 63;
    // ---- bijective XCD swizzle: m fastest within an XCD ----
    const int Mb = gridDim.x;
    int lin = blockIdx.y * Mb + blockIdx.x;
    int T = Mb * gridDim.y;
    int q = T >> 3, rr = T & 7;
    int xcd = lin & 7, slot = lin >> 3;
    int wid = (xcd < rr) ? (xcd * (q + 1) + slot)
                         : (rr * (q + 1) + (xcd - rr) * q + slot);
    const int m0 = (wid % Mb) * 128;
    const int n0 = (wid / Mb) * 128;

    const int wr = w >> 1, wc = w & 1;
    const int r = l & 15, g = l >> 4;
    const int sw = (r >> 1) & 3;
    const int gp = (g ^ sw) * 8;
    f32x4 acc[4][4];
#pragma unroll
    for (int i = 0; i < 4; ++i)
#pragma unroll
        for (int j = 0; j < 4; ++j) { acc[i][j][0]=0.f; acc[i][j][1]=0.f; acc[i][j][2]=0.f; acc[i][j][3]=0.f; }

    // ---- counted-vmcnt 2-deep pipelined K-loop (T3+T4) ----
    stage_tile(Wt, Act, m0, n0, K, 0,  A0, B0, t, w);
    stage_tile(Wt, Act, m0, n0, K, 32, A1, B1, t, w);
    const int nt = K >> 5;
    for (int kt = 0; kt < nt; ++kt) {
        if (kt < nt - 1)
            asm volatile("s_waitcnt vmcnt(4)" ::: "memory");   // this tile's 4 gl_lds done; next 4 in flight
        else
            asm volatile("s_waitcnt vmcnt(0)" ::: "memory");
        __builtin_amdgcn_s_barrier();
        __builtin_amdgcn_sched_barrier(0);
        const unsigned short* cA = (kt & 1) ? A1 : A0;
        const unsigned short* cB = (kt & 1) ? B1 : B0;
        bf16x8 af[4], bw[4];
#pragma unroll
        for (int m = 0; m < 4; ++m)
            af[m] = *reinterpret_cast<const bf16x8*>(&cA[(wr * 64 + m * 16 + r) * 32 + gp]);
#pragma unroll
        for (int n = 0; n < 4; ++n)
            bw[n] = *reinterpret_cast<const bf16x8*>(&cB[(wc * 64 + n * 16 + r) * 32 + gp]);
#pragma unroll
        for (int m = 0; m < 4; ++m)
#pragma unroll
            for (int n = 0; n < 4; ++n)
                acc[m][n] = __builtin_amdgcn_mfma_f32_16x16x32_bf16(af[m], bw[n], acc[m][n], 0, 0, 0);
        __builtin_amdgcn_sched_barrier(0);
        asm volatile("s_waitcnt lgkmcnt(0)" ::: "memory");     // all ds_reads of this buffer retired
        __builtin_amdgcn_s_barrier();
        __builtin_amdgcn_sched_barrier(0);
        if (kt + 2 < nt) {
            unsigned short* sA = (kt & 1) ? A1 : A0;
            unsigned short* sB = (kt & 1) ? B1 : B0;
            stage_tile(Wt, Act, m0, n0, K, (kt + 2) * 32, sA, sB, t, w);
        }
    }

    // ---- epilogue ----
    const int seg = m0 >> 8;
    const float* bp = (seg == 0) ? b0 : (seg == 1) ? b1 : (seg == 2) ? b2 : b3;
    unsigned short* op = (seg == 0) ? o0 : (seg == 1) ? o1 : (seg == 2) ? o2 : o3;
    const int chseg = m0 & 255;

    if (FUSE == 0 && seg == vseg) {
        // direct transposed store [ch][32768] (V^T for attention)
#pragma unroll
        for (int m = 0; m < 4; ++m) {
            const int ch0 = chseg + wr * 64 + m * 16 + g * 4;
            float4 b4 = *reinterpret_cast<const float4*>(bp + ch0);
            const float bb[4] = {b4.x, b4.y, b4.z, b4.w};
#pragma unroll
            for (int n = 0; n < 4; ++n) {
                const int tok = n0 + wc * 64 + n * 16 + r;
#pragma unroll
                for (int j = 0; j < 4; ++j)
                    op[(size_t)(ch0 + j) * 32768 + tok] = f2bf(acc[m][n][j] + bb[j]);
            }
        }
        return;
    }

    // (loop ended with lgkmcnt(0)+barrier: safe to overwrite pool with Cs)
#pragma unroll
    for (int m = 0; m < 4; ++m) {
        const int ch0 = wr * 64 + m * 16 + g * 4;       // local 0..127
        float4 b4 = *reinterpret_cast<const float4*>(bp + chseg + ch0);
        const float bb[4] = {b4.x, b4.y, b4.z, b4.w};
#pragma unroll
        for (int n = 0; n < 4; ++n) {
            const int tok_l = wc * 64 + n * 16 + r;     // local 0..127
            float cv[4];
#pragma unroll
            for (int j = 0; j < 4; ++j) {
                cv[j] = acc[m][n][j] + bb[j];
                if (GELU) cv[j] = gelu_f(cv[j]);
            }
            ushort4 pk;
            pk.x = f2bf(cv[0]); pk.y = f2bf(cv[1]); pk.z = f2bf(cv[2]); pk.w = f2bf(cv[3]);
            int gran = (ch0 >> 2) ^ ((tok_l & 15) << 1);
            reinterpret_cast<ushort4*>(Cs)[tok_l * 32 + gran] = pk;
        }
    }
    __syncthreads();
    const int u = t & 15, trow = t >> 4;
    if (FUSE == 0) {
        // coalesced bf16 store: 16 lanes x 16B = 256 B contiguous per token row
#pragma unroll
        for (int it = 0; it < 8; ++it) {
            int tok_l = it * 16 + trow;
            int up = u ^ (tok_l & 15);
            uint4 v = reinterpret_cast<const uint4*>(Cs)[tok_l * 16 + up];
            *reinterpret_cast<uint4*>(op + (size_t)(n0 + tok_l) * strideO + chseg + u * 8) = v;
        }
    } else {
        const float gsc = gammap[0];
#pragma unroll
        for (int it = 0; it < 8; ++it) {
            int tok_l = it * 16 + trow;
            int wrow = n0 + tok_l;
            int tok;
            if (FUSE == 1) {
                int win = wrow >> 6, l2 = wrow & 63;
                int f = win >> 6, wih = (win >> 3) & 7, wiw = win & 7;
                int r2 = l2 >> 3, s2 = l2 & 7;
                int h = wih * 8 + r2, wcol = wiw * 8 + s2;
                if (h >= 60 || wcol >= 60) continue;     // padding rows dropped
                int oh = h + 4; if (oh >= 60) oh -= 60;
                int ow = wcol + 4; if (ow >= 60) ow -= 60;
                tok = f * 3600 + oh * 60 + ow;
            } else {
                tok = wrow;
            }
            int up = u ^ (tok_l & 15);
            uint4 v = reinterpret_cast<const uint4*>(Cs)[tok_l * 16 + up];
            const unsigned short* pu = (const unsigned short*)&v;
            const float* xr = xres + (size_t)tok * CC + chseg + u * 8;
            float4 xa = *reinterpret_cast<const float4*>(xr);
            float4 xb = *reinterpret_cast<const float4*>(xr + 4);
            float4 oa, ob;
            oa.x = xa.x + gsc * bf2f(pu[0]);
            oa.y = xa.y + gsc * bf2f(pu[1]);
            oa.z = xa.z + gsc * bf2f(pu[2]);
            oa.w = xa.w + gsc * bf2f(pu[3]);
            ob.x = xb.x + gsc * bf2f(pu[4]);
            ob.y = xb.y + gsc * bf2f(pu[5]);
            ob.z = xb.z + gsc * bf2f(pu[6]);
            ob.w = xb.w + gsc * bf2f(pu[7]);
            float* fo = fout + (size_t)tok * CC + chseg + u * 8;
            *reinterpret_cast<float4*>(fo) = oa;
            *reinterpret_cast<float4*>(fo + 4) = ob;
        }
    }
}

// ---------------- bias table expansion: biasx[2][8][64][64] ----------------
__global__ void expand_bias(const float* __restrict__ sa, const float* __restrict__ ca,
                            float* __restrict__ dst) {
    int e = (int)(blockIdx.x * blockDim.x + threadIdx.x);   // 0..32767
    const float* src = (e < 16384) ? sa : ca;
    int e2 = e & 16383;
    int h = e2 >> 12, ij = e2 & 4095, i = ij >> 6, j = ij & 63;
    int ri = i >> 3, si = i & 7, rj = j >> 3, sj = j & 7;
    dst[e] = src[((ri - rj + 7) * 15 + (si - sj + 7)) * 8 + h];
}

// ---------------- MFMA attention: one wave per (window, head) ----------------
__global__ __launch_bounds__(256) void attn_mfma(
        const unsigned short* __restrict__ Q,   // [32768][256] bf16
        const unsigned short* __restrict__ K,   // [32768][256] bf16
        const unsigned short* __restrict__ VT,  // [256][32768] bf16
        const float* __restrict__ biasx,        // [8][64][64] f32
        unsigned short* __restrict__ AO) {      // [32768][256] bf16
    __shared__ __align__(16) unsigned short Pl[4][64 * 64];
    const int t = threadIdx.x;
    const int w = t >> 6, l = t & 63;
    const int win = blockIdx.x >> 1;
    const int h   = (blockIdx.x & 1) * 4 + w;
    const int c = l & 15, g = l >> 4;
    const int wih = (win >> 3) & 7, wiw = win & 7;
    const size_t qkbase = (size_t)win * 64 * CC + (size_t)h * 32;

    bf16x8 ka[4], qb[4];
#pragma unroll
    for (int mj = 0; mj < 4; ++mj)
        ka[mj] = *reinterpret_cast<const bf16x8*>(K + qkbase + (size_t)(mj * 16 + c) * CC + g * 8);
#pragma unroll
    for (int ni = 0; ni < 4; ++ni)
        qb[ni] = *reinterpret_cast<const bf16x8*>(Q + qkbase + (size_t)(ni * 16 + c) * CC + g * 8);
    f32x4 s[4][4];
#pragma unroll
    for (int mj = 0; mj < 4; ++mj)
#pragma unroll
        for (int ni = 0; ni < 4; ++ni) { s[mj][ni][0]=0.f; s[mj][ni][1]=0.f; s[mj][ni][2]=0.f; s[mj][ni][3]=0.f; }
#pragma unroll
    for (int mj = 0; mj < 4; ++mj)
#pragma unroll
        for (int ni = 0; ni < 4; ++ni)
            s[mj][ni] = __builtin_amdgcn_mfma_f32_16x16x32_bf16(ka[mj], qb[ni], s[mj][ni], 0, 0, 0);

    const float* bx = biasx + h * 4096;
    const bool modd = (wiw == 7) && (g & 1);
#pragma unroll
    for (int mj = 0; mj < 4; ++mj) {
        const bool mmj = (wih == 7) && (mj >= 2);
#pragma unroll
        for (int ni = 0; ni < 4; ++ni) {
            float4 b4 = *reinterpret_cast<const float4*>(bx + (ni * 16 + c) * 64 + mj * 16 + g * 4);
            const float bb[4] = {b4.x, b4.y, b4.z, b4.w};
#pragma unroll
            for (int jj = 0; jj < 4; ++jj) {
                float v = s[mj][ni][jj] * ATT_SCALE + bb[jj];
                s[mj][ni][jj] = (mmj || modd) ? -1e30f : v;
            }
        }
    }

#pragma unroll
    for (int ni = 0; ni < 4; ++ni) {
        float mx = -1e30f;
#pragma unroll
        for (int mj = 0; mj < 4; ++mj)
#pragma unroll
            for (int jj = 0; jj < 4; ++jj) mx = fmaxf(mx, s[mj][ni][jj]);
        mx = fmaxf(mx, __shfl_xor(mx, 16));
        mx = fmaxf(mx, __shfl_xor(mx, 32));
        float sum = 0.f;
#pragma unroll
        for (int mj = 0; mj < 4; ++mj)
#pragma unroll
            for (int jj = 0; jj < 4; ++jj) {
                float p = __expf(s[mj][ni][jj] - mx);
                s[mj][ni][jj] = p;
                sum += p;
            }
        sum += __shfl_xor(sum, 16);
        sum += __shfl_xor(sum, 32);
        float rinv = 1.0f / sum;
        const int i  = ni * 16 + c;
        const int ik = i & 7;
#pragma unroll
        for (int mj = 0; mj < 4; ++mj) {
            ushort4 pk;
            pk.x = f2bf(s[mj][ni][0] * rinv);
            pk.y = f2bf(s[mj][ni][1] * rinv);
            pk.z = f2bf(s[mj][ni][2] * rinv);
            pk.w = f2bf(s[mj][ni][3] * rinv);
            int chunk = (mj * 2 + (g >> 1)) ^ ik;
            *reinterpret_cast<ushort4*>((char*)&Pl[w][0] + i * 128 + chunk * 16 + (g & 1) * 8) = pk;
        }
    }

    bf16x8 vb[2][2];
#pragma unroll
    for (int nd = 0; nd < 2; ++nd)
#pragma unroll
        for (int kt = 0; kt < 2; ++kt)
            vb[nd][kt] = *reinterpret_cast<const bf16x8*>(
                VT + (size_t)(h * 32 + nd * 16 + c) * 32768 + win * 64 + kt * 32 + g * 8);
    f32x4 o[4][2];
#pragma unroll
    for (int mi = 0; mi < 4; ++mi)
#pragma unroll
        for (int nd = 0; nd < 2; ++nd) { o[mi][nd][0]=0.f; o[mi][nd][1]=0.f; o[mi][nd][2]=0.f; o[mi][nd][3]=0.f; }
#pragma unroll
    for (int mi = 0; mi < 4; ++mi) {
        const int i  = mi * 16 + c;
        const int ik = i & 7;
#pragma unroll
        for (int kt = 0; kt < 2; ++kt) {
            int chunk = (kt * 4 + g) ^ ik;
            bf16x8 pa = *reinterpret_cast<const bf16x8*>((char*)&Pl[w][0] + i * 128 + chunk * 16);
#pragma unroll
            for (int nd = 0; nd < 2; ++nd)
                o[mi][nd] = __builtin_amdgcn_mfma_f32_16x16x32_bf16(pa, vb[nd][kt], o[mi][nd], 0, 0, 0);
        }
    }

    unsigned short* aop = AO + qkbase;
#pragma unroll
    for (int mi = 0; mi < 4; ++mi)
#pragma unroll
        for (int nd = 0; nd < 2; ++nd)
#pragma unroll
            for (int jj = 0; jj < 4; ++jj)
                aop[(size_t)(mi * 16 + g * 4 + jj) * CC + nd * 16 + c] = f2bf(o[mi][nd][jj]);
}

// ---------------- weight fp32 -> bf16 conversion ----------------
__global__ void cvt_all(const float* s0, const float* s1, const float* s2, const float* s3,
                        const float* s4, const float* s5, const float* s6, const float* s7,
                        const float* s8, const float* s9, unsigned short* __restrict__ dst) {
    const float* srcs[10] = {s0, s1, s2, s3, s4, s5, s6, s7, s8, s9};
    int blk = blockIdx.x;
    int wi = (blk < 512) ? (blk >> 6) : (blk < 768 ? 8 : 9);
    size_t start = (wi < 8) ? (size_t)wi * 65536 : (wi == 8 ? (size_t)524288 : (size_t)786432);
    size_t gidx = (size_t)blk * 1024 + (size_t)threadIdx.x * 4;
    float4 v = *reinterpret_cast<const float4*>(srcs[wi] + (gidx - start));
    ushort4 o;
    o.x = f2bf(v.x); o.y = f2bf(v.y); o.z = f2bf(v.z); o.w = f2bf(v.w);
    *reinterpret_cast<ushort4*>(dst + gidx) = o;
}

extern "C" void kernel_launch(void* const* d_in, const int* in_sizes, int n_in,
                              void* d_out, int out_size, void* d_ws, size_t ws_size,
                              hipStream_t stream) {
    const float* x    = (const float*)d_in[0];
    const float* ctx  = (const float*)d_in[1];
    const float* ln1w = (const float*)d_in[2];
    const float* ln1b = (const float*)d_in[3];
    const float* ln2w = (const float*)d_in[4];
    const float* ln2b = (const float*)d_in[5];
    const float* ln3w = (const float*)d_in[6];
    const float* ln3b = (const float*)d_in[7];
    const float* lncw = (const float*)d_in[8];
    const float* lncb = (const float*)d_in[9];
    const float* saqw = (const float*)d_in[10];
    const float* saqb = (const float*)d_in[11];
    const float* sakw = (const float*)d_in[12];
    const float* sakb = (const float*)d_in[13];
    const float* savw = (const float*)d_in[14];
    const float* savb = (const float*)d_in[15];
    const float* saow = (const float*)d_in[16];
    const float* saob = (const float*)d_in[17];
    const float* sabias = (const float*)d_in[18];
    const float* caqw = (const float*)d_in[19];
    const float* caqb = (const float*)d_in[20];
    const float* cakw = (const float*)d_in[21];
    const float* cakb = (const float*)d_in[22];
    const float* cavw = (const float*)d_in[23];
    const float* cavb = (const float*)d_in[24];
    const float* caow = (const float*)d_in[25];
    const float* caob = (const float*)d_in[26];
    const float* cabias = (const float*)d_in[27];
    const float* gamma1 = (const float*)d_in[28];
    const float* gamma2 = (const float*)d_in[29];
    const float* gammam = (const float*)d_in[30];
    const float* mw1 = (const float*)d_in[31];
    const float* mb1 = (const float*)d_in[32];
    const float* mw2 = (const float*)d_in[33];
    const float* mb2 = (const float*)d_in[34];

    float* ws = (float*)d_ws;
    unsigned short* LNbf = (unsigned short*)(ws);                 // 3,686,400 f
    unsigned short* Gq   = (unsigned short*)(ws + 3686400);       // 4,194,304 f
    unsigned short* Gkv  = (unsigned short*)(ws + 7880704);       // 4,194,304 f
    unsigned short* Qbf  = (unsigned short*)(ws + 12075008);      // 4,194,304 f
    unsigned short* Kbf  = (unsigned short*)(ws + 16269312);      // 4,194,304 f
    unsigned short* VTbf = (unsigned short*)(ws + 20463616);      // 4,194,304 f
    float* X1  = ws + 28852224;                                   // 7,372,800 f
    unsigned short* Wp = (unsigned short*)(ws + 36225024);        // 524,288 f
    float* biasx = ws + 36749312;                                 // 32,768 f
    unsigned short* AObf = Gq;                                    // alias (gathered act dead after proj)
    unsigned short* H1bf = Qbf;                                   // alias (Q/K/VT dead in MLP phase)

    // cvt layout (contiguous): saq|sak|sav | sao | caq | cak|cav | cao | m1 | m2
    unsigned short* w_saqkv = Wp;                                 // [768][256]
    unsigned short* w_sao   = Wp + 196608;                        // [256][256]
    unsigned short* w_caq   = Wp + 262144;                        // [256][256]
    unsigned short* w_cakv  = Wp + 327680;                        // [512][256]
    unsigned short* w_cao   = Wp + 458752;                        // [256][256]
    unsigned short* w_m1    = Wp + 524288;                        // [1024][256]
    unsigned short* w_m2    = Wp + 786432;                        // [256][1024]

    float* OUT = (float*)d_out;

    dim3 blk(256);
    dim3 gLN(BN / 4);
    dim3 gGather(WROWS / 4);
    dim3 gAttn(WINS * 2);

    cvt_all<<<dim3(1024), blk, 0, stream>>>(saqw, sakw, savw, saow, caqw, cakw, cavw, caow, mw1, mw2, Wp);
    expand_bias<<<dim3(128), blk, 0, stream>>>(sabias, cabias, biasx);

    // ---- self attention ----
    ln_gather<<<gGather, blk, 0, stream>>>(x, ln1w, ln1b, Gq);
    gemm_wa<false,0><<<dim3(6, 256), blk, 0, stream>>>(w_saqkv, Gq, saqb, sakb, savb, savb,
                                                       Qbf, Kbf, VTbf, VTbf, CC, 2, CC,
                                                       nullptr, nullptr, nullptr);
    attn_mfma<<<gAttn, blk, 0, stream>>>(Qbf, Kbf, VTbf, biasx, AObf);
    gemm_wa<false,1><<<dim3(2, 256), blk, 0, stream>>>(w_sao, AObf, saob, saob, saob, saob,
                                                       Qbf, Qbf, Qbf, Qbf, CC, -1, CC,
                                                       x, gamma1, X1);
    // ---- cross attention ----
    ln_gather<<<gGather, blk, 0, stream>>>(X1, ln2w, ln2b, Gq);
    ln_gather<<<gGather, blk, 0, stream>>>(ctx, lncw, lncb, Gkv);
    gemm_wa<false,0><<<dim3(2, 256), blk, 0, stream>>>(w_caq, Gq, caqb, caqb, caqb, caqb,
                                                       Qbf, Qbf, Qbf, Qbf, CC, -1, CC,
                                                       nullptr, nullptr, nullptr);
    gemm_wa<false,0><<<dim3(4, 256), blk, 0, stream>>>(w_cakv, Gkv, cakb, cavb, cavb, cavb,
                                                       Kbf, VTbf, VTbf, VTbf, CC, 1, CC,
                                                       nullptr, nullptr, nullptr);
    attn_mfma<<<gAttn, blk, 0, stream>>>(Qbf, Kbf, VTbf, biasx + 16384, AObf);
    gemm_wa<false,1><<<dim3(2, 256), blk, 0, stream>>>(w_cao, AObf, caob, caob, caob, caob,
                                                       Qbf, Qbf, Qbf, Qbf, CC, -1, CC,
                                                       X1, gamma2, X1);
    // ---- MLP ----
    ln_kernel<<<gLN, blk, 0, stream>>>(X1, ln3w, ln3b, LNbf, BN);
    gemm_wa<true,0><<<dim3(8, 225), blk, 0, stream>>>(w_m1, LNbf, mb1, mb1 + 256, mb1 + 512, mb1 + 768,
                                                      H1bf, H1bf + 256, H1bf + 512, H1bf + 768,
                                                      HIDN, -1, CC, nullptr, nullptr, nullptr);
    gemm_wa<false,2><<<dim3(2, 225), blk, 0, stream>>>(w_m2, H1bf, mb2, mb2, mb2, mb2,
                                                      Qbf, Qbf, Qbf, Qbf, CC, -1, HIDN,
                                                      X1, gammam, OUT);
}

// Round 8
// 240.520 us; speedup vs baseline: 5.1405x; 1.0298x over previous
//
#include <hip/hip_runtime.h>
#include <math.h>

// ---- problem constants ----
#define BN    28800      // B*N tokens total
#define CC    256        // channels
#define HIDN  1024       // MLP hidden
#define WINS  512        // total windows (8 frames * 64)
#define WROWS (WINS*64)  // 32768 window rows
#define ATT_SCALE 0.1767766952966369f

typedef __bf16 bf16x8 __attribute__((ext_vector_type(8)));
typedef float  f32x4  __attribute__((ext_vector_type(4)));

__device__ __forceinline__ unsigned short f2bf(float f) {
    unsigned u = __float_as_uint(f);
    unsigned r = (u + 0x7FFFu + ((u >> 16) & 1u)) >> 16;
    return (unsigned short)r;
}
__device__ __forceinline__ float bf2f(unsigned short u) {
    return __uint_as_float((unsigned)u << 16);
}

// fast GELU (tanh form) with fast rcp; overflow-safe
__device__ __forceinline__ float gelu_f(float x) {
    float x3 = x * x * x;
    float e  = __expf(1.5957691216057308f * (x + 0.044715f * x3));  // exp(2y)
    float th = 1.0f - 2.0f * __builtin_amdgcn_rcpf(e + 1.0f);
    return 0.5f * x * (1.0f + th);
}

__device__ __forceinline__ void gl_lds16(const void* g, void* l) {
    __builtin_amdgcn_global_load_lds(
        (const __attribute__((address_space(1))) void*)g,
        (__attribute__((address_space(3))) void*)l, 16, 0, 0);
}

// ---------------- LayerNorm (plain): one wave per token, bf16 out ----------------
__global__ void ln_kernel(const float* __restrict__ x, const float* __restrict__ w,
                          const float* __restrict__ b, unsigned short* __restrict__ out, int ntok) {
    int tok  = (int)((blockIdx.x * blockDim.x + threadIdx.x) >> 6);
    int lane = threadIdx.x & 63;
    if (tok >= ntok) return;
    float4 v = reinterpret_cast<const float4*>(x + (size_t)tok * CC)[lane];
    float s  = v.x + v.y + v.z + v.w;
    float s2 = v.x*v.x + v.y*v.y + v.z*v.z + v.w*v.w;
#pragma unroll
    for (int off = 32; off >= 1; off >>= 1) {
        s  += __shfl_xor(s, off);
        s2 += __shfl_xor(s2, off);
    }
    float mean = s * (1.0f / CC);
    float var  = s2 * (1.0f / CC) - mean * mean;
    float rs   = rsqrtf(var + 1e-5f);
    float4 wv = reinterpret_cast<const float4*>(w)[lane];
    float4 bv = reinterpret_cast<const float4*>(b)[lane];
    ushort4 o;
    o.x = f2bf((v.x - mean) * rs * wv.x + bv.x);
    o.y = f2bf((v.y - mean) * rs * wv.y + bv.y);
    o.z = f2bf((v.z - mean) * rs * wv.z + bv.z);
    o.w = f2bf((v.w - mean) * rs * wv.w + bv.w);
    reinterpret_cast<ushort4*>(out + (size_t)tok * CC)[lane] = o;
}

// ---------------- fused LayerNorm + window gather ----------------
__global__ void ln_gather(const float* __restrict__ x, const float* __restrict__ w,
                          const float* __restrict__ b, unsigned short* __restrict__ dst) {
    int row  = (int)((blockIdx.x * blockDim.x + threadIdx.x) >> 6);
    int lane = threadIdx.x & 63;
    if (row >= WROWS) return;
    int win = row >> 6, l = row & 63;
    int f   = win >> 6;
    int wih = (win >> 3) & 7, wiw = win & 7;
    int r = l >> 3, s = l & 7;
    int h = wih * 8 + r, wc = wiw * 8 + s;
    if (h >= 60 || wc >= 60) {
        ushort4 z = {0, 0, 0, 0};
        reinterpret_cast<ushort4*>(dst + (size_t)row * CC)[lane] = z;
        return;
    }
    int oh = (h + 4) % 60, ow = (wc + 4) % 60;
    size_t tok = (size_t)f * 3600 + (size_t)oh * 60 + ow;
    float4 v = reinterpret_cast<const float4*>(x + tok * CC)[lane];
    float sm  = v.x + v.y + v.z + v.w;
    float s2 = v.x*v.x + v.y*v.y + v.z*v.z + v.w*v.w;
#pragma unroll
    for (int off = 32; off >= 1; off >>= 1) {
        sm += __shfl_xor(sm, off);
        s2 += __shfl_xor(s2, off);
    }
    float mean = sm * (1.0f / CC);
    float var  = s2 * (1.0f / CC) - mean * mean;
    float rs   = rsqrtf(var + 1e-5f);
    float4 wv = reinterpret_cast<const float4*>(w)[lane];
    float4 bv = reinterpret_cast<const float4*>(b)[lane];
    ushort4 o;
    o.x = f2bf((v.x - mean) * rs * wv.x + bv.x);
    o.y = f2bf((v.y - mean) * rs * wv.y + bv.y);
    o.z = f2bf((v.z - mean) * rs * wv.z + bv.z);
    o.w = f2bf((v.w - mean) * rs * wv.w + bv.w);
    reinterpret_cast<ushort4*>(dst + (size_t)row * CC)[lane] = o;
}

// ---------------- bf16 MFMA GEMM: 512 threads, 8 waves (2x4), 128x128 tile ----------------
// FUSE: 0 = bf16 out [tok][strideO] (vseg segment stores V^T [ch][32768]);
//       1 = f32 residual out with inverse-window scatter (fout = xres + gamma*val);
//       2 = f32 plain residual out.
template <bool GELU, int FUSE>
__global__ __launch_bounds__(512, 4) void gemm_wa(
        const unsigned short* __restrict__ Wt,   // [Mtot][K] bf16
        const unsigned short* __restrict__ Act,  // [Ntok][K] bf16
        const float* __restrict__ b0, const float* __restrict__ b1,
        const float* __restrict__ b2, const float* __restrict__ b3,
        unsigned short* __restrict__ o0, unsigned short* __restrict__ o1,
        unsigned short* __restrict__ o2, unsigned short* __restrict__ o3,
        int strideO, int vseg, int K,
        const float* __restrict__ xres, const float* __restrict__ gammap,
        float* __restrict__ fout) {
    __shared__ __align__(16) char pool[32768];
    unsigned short* A0 = (unsigned short*)pool;
    unsigned short* B0 = (unsigned short*)(pool + 8192);
    unsigned short* A1 = (unsigned short*)(pool + 16384);
    unsigned short* B1 = (unsigned short*)(pool + 24576);
    unsigned short* Cs = (unsigned short*)pool;            // 32 KB (after final barrier)

    const int t = threadIdx.x;          // 0..511
    const int w = t >> 6;               // 0..7
    const int l = t & 63;
    // ---- bijective XCD swizzle: m fastest within an XCD ----
    const int Mb = gridDim.x;
    int lin = blockIdx.y * Mb + blockIdx.x;
    int T = Mb * gridDim.y;
    int q = T >> 3, rr = T & 7;
    int xcd = lin & 7, slot = lin >> 3;
    int wid = (xcd < rr) ? (xcd * (q + 1) + slot)
                         : (rr * (q + 1) + (xcd - rr) * q + slot);
    const int m0 = (wid % Mb) * 128;
    const int n0 = (wid / Mb) * 128;

    const int wr = w >> 2, wc = w & 3;  // wave tile: rows wr*64, cols wc*32
    const int r = l & 15, g = l >> 4;
    const int sw = (r >> 1) & 3;
    const int gp = (g ^ sw) * 8;
    // staging: thread t covers row t>>2, source pre-swizzled chunk
    const int srow = t >> 2;
    const int sgl  = (t & 3) ^ ((srow >> 1) & 3);

    f32x4 acc[4][2];
#pragma unroll
    for (int i = 0; i < 4; ++i)
#pragma unroll
        for (int j = 0; j < 2; ++j) { acc[i][j][0]=0.f; acc[i][j][1]=0.f; acc[i][j][2]=0.f; acc[i][j][3]=0.f; }

    // ---- counted-vmcnt 2-deep pipelined K-loop ----
#define STAGE(k0, dA, dB)                                                          \
    do {                                                                           \
        gl_lds16(Wt  + (size_t)(m0 + srow) * K + (k0) + sgl * 8, (char*)(dA) + w * 1024); \
        gl_lds16(Act + (size_t)(n0 + srow) * K + (k0) + sgl * 8, (char*)(dB) + w * 1024); \
    } while (0)

    STAGE(0,  A0, B0);
    STAGE(32, A1, B1);
    const int nt = K >> 5;
    for (int kt = 0; kt < nt; ++kt) {
        if (kt < nt - 1)
            asm volatile("s_waitcnt vmcnt(2)" ::: "memory");   // this tile's 2 gl_lds done; next 2 in flight
        else
            asm volatile("s_waitcnt vmcnt(0)" ::: "memory");
        __builtin_amdgcn_s_barrier();
        __builtin_amdgcn_sched_barrier(0);
        const unsigned short* cA = (kt & 1) ? A1 : A0;
        const unsigned short* cB = (kt & 1) ? B1 : B0;
        bf16x8 af[4], bw[2];
#pragma unroll
        for (int m = 0; m < 4; ++m)
            af[m] = *reinterpret_cast<const bf16x8*>(&cA[(wr * 64 + m * 16 + r) * 32 + gp]);
#pragma unroll
        for (int n = 0; n < 2; ++n)
            bw[n] = *reinterpret_cast<const bf16x8*>(&cB[(wc * 32 + n * 16 + r) * 32 + gp]);
#pragma unroll
        for (int m = 0; m < 4; ++m)
#pragma unroll
            for (int n = 0; n < 2; ++n)
                acc[m][n] = __builtin_amdgcn_mfma_f32_16x16x32_bf16(af[m], bw[n], acc[m][n], 0, 0, 0);
        __builtin_amdgcn_sched_barrier(0);
        asm volatile("s_waitcnt lgkmcnt(0)" ::: "memory");     // all ds_reads of this buffer retired
        __builtin_amdgcn_s_barrier();
        __builtin_amdgcn_sched_barrier(0);
        if (kt + 2 < nt) {
            unsigned short* sA = (kt & 1) ? A1 : A0;
            unsigned short* sB = (kt & 1) ? B1 : B0;
            STAGE((kt + 2) * 32, sA, sB);
        }
    }
#undef STAGE

    // ---- epilogue ----
    const int seg = m0 >> 8;
    const float* bp = (seg == 0) ? b0 : (seg == 1) ? b1 : (seg == 2) ? b2 : b3;
    unsigned short* op = (seg == 0) ? o0 : (seg == 1) ? o1 : (seg == 2) ? o2 : o3;
    const int chseg = m0 & 255;

    if (FUSE == 0 && seg == vseg) {
        // direct transposed store [ch][32768] (V^T for attention)
#pragma unroll
        for (int m = 0; m < 4; ++m) {
            const int ch0 = chseg + wr * 64 + m * 16 + g * 4;
            float4 b4 = *reinterpret_cast<const float4*>(bp + ch0);
            const float bb[4] = {b4.x, b4.y, b4.z, b4.w};
#pragma unroll
            for (int n = 0; n < 2; ++n) {
                const int tok = n0 + wc * 32 + n * 16 + r;
#pragma unroll
                for (int j = 0; j < 4; ++j)
                    op[(size_t)(ch0 + j) * 32768 + tok] = f2bf(acc[m][n][j] + bb[j]);
            }
        }
        return;
    }

    // (loop ended with lgkmcnt(0)+barrier: safe to overwrite pool with Cs)
#pragma unroll
    for (int m = 0; m < 4; ++m) {
        const int ch0 = wr * 64 + m * 16 + g * 4;       // local 0..127
        float4 b4 = *reinterpret_cast<const float4*>(bp + chseg + ch0);
        const float bb[4] = {b4.x, b4.y, b4.z, b4.w};
#pragma unroll
        for (int n = 0; n < 2; ++n) {
            const int tok_l = wc * 32 + n * 16 + r;     // local 0..127
            float cv[4];
#pragma unroll
            for (int j = 0; j < 4; ++j) {
                cv[j] = acc[m][n][j] + bb[j];
                if (GELU) cv[j] = gelu_f(cv[j]);
            }
            ushort4 pk;
            pk.x = f2bf(cv[0]); pk.y = f2bf(cv[1]); pk.z = f2bf(cv[2]); pk.w = f2bf(cv[3]);
            int gran = (ch0 >> 2) ^ ((tok_l & 15) << 1);
            reinterpret_cast<ushort4*>(Cs)[tok_l * 32 + gran] = pk;
        }
    }
    __syncthreads();
    const int u = t & 15, trow = t >> 4;   // trow 0..31
    if (FUSE == 0) {
        // coalesced bf16 store: 16 lanes x 16B = 256 B contiguous per token row
#pragma unroll
        for (int it = 0; it < 4; ++it) {
            int tok_l = it * 32 + trow;
            int up = u ^ (tok_l & 15);
            uint4 v = reinterpret_cast<const uint4*>(Cs)[tok_l * 16 + up];
            *reinterpret_cast<uint4*>(op + (size_t)(n0 + tok_l) * strideO + chseg + u * 8) = v;
        }
    } else {
        const float gsc = gammap[0];
#pragma unroll
        for (int it = 0; it < 4; ++it) {
            int tok_l = it * 32 + trow;
            int wrow = n0 + tok_l;
            int tok;
            if (FUSE == 1) {
                int win = wrow >> 6, l2 = wrow & 63;
                int f = win >> 6, wih = (win >> 3) & 7, wiw = win & 7;
                int r2 = l2 >> 3, s2 = l2 & 7;
                int h = wih * 8 + r2, wcol = wiw * 8 + s2;
                if (h >= 60 || wcol >= 60) continue;     // padding rows dropped
                int oh = h + 4; if (oh >= 60) oh -= 60;
                int ow = wcol + 4; if (ow >= 60) ow -= 60;
                tok = f * 3600 + oh * 60 + ow;
            } else {
                tok = wrow;
            }
            int up = u ^ (tok_l & 15);
            uint4 v = reinterpret_cast<const uint4*>(Cs)[tok_l * 16 + up];
            const unsigned short* pu = (const unsigned short*)&v;
            const float* xr = xres + (size_t)tok * CC + chseg + u * 8;
            float4 xa = *reinterpret_cast<const float4*>(xr);
            float4 xb = *reinterpret_cast<const float4*>(xr + 4);
            float4 oa, ob;
            oa.x = xa.x + gsc * bf2f(pu[0]);
            oa.y = xa.y + gsc * bf2f(pu[1]);
            oa.z = xa.z + gsc * bf2f(pu[2]);
            oa.w = xa.w + gsc * bf2f(pu[3]);
            ob.x = xb.x + gsc * bf2f(pu[4]);
            ob.y = xb.y + gsc * bf2f(pu[5]);
            ob.z = xb.z + gsc * bf2f(pu[6]);
            ob.w = xb.w + gsc * bf2f(pu[7]);
            float* fo = fout + (size_t)tok * CC + chseg + u * 8;
            *reinterpret_cast<float4*>(fo) = oa;
            *reinterpret_cast<float4*>(fo + 4) = ob;
        }
    }
}

// ---------------- bias table expansion: biasx[2][8][64][64] ----------------
__global__ void expand_bias(const float* __restrict__ sa, const float* __restrict__ ca,
                            float* __restrict__ dst) {
    int e = (int)(blockIdx.x * blockDim.x + threadIdx.x);   // 0..32767
    const float* src = (e < 16384) ? sa : ca;
    int e2 = e & 16383;
    int h = e2 >> 12, ij = e2 & 4095, i = ij >> 6, j = ij & 63;
    int ri = i >> 3, si = i & 7, rj = j >> 3, sj = j & 7;
    dst[e] = src[((ri - rj + 7) * 15 + (si - sj + 7)) * 8 + h];
}

// ---------------- MFMA attention: one wave per (window, head) ----------------
__global__ __launch_bounds__(256) void attn_mfma(
        const unsigned short* __restrict__ Q,   // [32768][256] bf16
        const unsigned short* __restrict__ K,   // [32768][256] bf16
        const unsigned short* __restrict__ VT,  // [256][32768] bf16
        const float* __restrict__ biasx,        // [8][64][64] f32
        unsigned short* __restrict__ AO) {      // [32768][256] bf16
    __shared__ __align__(16) unsigned short Pl[4][64 * 64];
    const int t = threadIdx.x;
    const int w = t >> 6, l = t & 63;
    const int win = blockIdx.x >> 1;
    const int h   = (blockIdx.x & 1) * 4 + w;
    const int c = l & 15, g = l >> 4;
    const int wih = (win >> 3) & 7, wiw = win & 7;
    const size_t qkbase = (size_t)win * 64 * CC + (size_t)h * 32;

    bf16x8 ka[4], qb[4];
#pragma unroll
    for (int mj = 0; mj < 4; ++mj)
        ka[mj] = *reinterpret_cast<const bf16x8*>(K + qkbase + (size_t)(mj * 16 + c) * CC + g * 8);
#pragma unroll
    for (int ni = 0; ni < 4; ++ni)
        qb[ni] = *reinterpret_cast<const bf16x8*>(Q + qkbase + (size_t)(ni * 16 + c) * CC + g * 8);
    f32x4 s[4][4];
#pragma unroll
    for (int mj = 0; mj < 4; ++mj)
#pragma unroll
        for (int ni = 0; ni < 4; ++ni) { s[mj][ni][0]=0.f; s[mj][ni][1]=0.f; s[mj][ni][2]=0.f; s[mj][ni][3]=0.f; }
#pragma unroll
    for (int mj = 0; mj < 4; ++mj)
#pragma unroll
        for (int ni = 0; ni < 4; ++ni)
            s[mj][ni] = __builtin_amdgcn_mfma_f32_16x16x32_bf16(ka[mj], qb[ni], s[mj][ni], 0, 0, 0);

    const float* bx = biasx + h * 4096;
    const bool modd = (wiw == 7) && (g & 1);
#pragma unroll
    for (int mj = 0; mj < 4; ++mj) {
        const bool mmj = (wih == 7) && (mj >= 2);
#pragma unroll
        for (int ni = 0; ni < 4; ++ni) {
            float4 b4 = *reinterpret_cast<const float4*>(bx + (ni * 16 + c) * 64 + mj * 16 + g * 4);
            const float bb[4] = {b4.x, b4.y, b4.z, b4.w};
#pragma unroll
            for (int jj = 0; jj < 4; ++jj) {
                float v = s[mj][ni][jj] * ATT_SCALE + bb[jj];
                s[mj][ni][jj] = (mmj || modd) ? -1e30f : v;
            }
        }
    }

#pragma unroll
    for (int ni = 0; ni < 4; ++ni) {
        float mx = -1e30f;
#pragma unroll
        for (int mj = 0; mj < 4; ++mj)
#pragma unroll
            for (int jj = 0; jj < 4; ++jj) mx = fmaxf(mx, s[mj][ni][jj]);
        mx = fmaxf(mx, __shfl_xor(mx, 16));
        mx = fmaxf(mx, __shfl_xor(mx, 32));
        float sum = 0.f;
#pragma unroll
        for (int mj = 0; mj < 4; ++mj)
#pragma unroll
            for (int jj = 0; jj < 4; ++jj) {
                float p = __expf(s[mj][ni][jj] - mx);
                s[mj][ni][jj] = p;
                sum += p;
            }
        sum += __shfl_xor(sum, 16);
        sum += __shfl_xor(sum, 32);
        float rinv = __builtin_amdgcn_rcpf(sum);
        const int i  = ni * 16 + c;
        const int ik = i & 7;
#pragma unroll
        for (int mj = 0; mj < 4; ++mj) {
            ushort4 pk;
            pk.x = f2bf(s[mj][ni][0] * rinv);
            pk.y = f2bf(s[mj][ni][1] * rinv);
            pk.z = f2bf(s[mj][ni][2] * rinv);
            pk.w = f2bf(s[mj][ni][3] * rinv);
            int chunk = (mj * 2 + (g >> 1)) ^ ik;
            *reinterpret_cast<ushort4*>((char*)&Pl[w][0] + i * 128 + chunk * 16 + (g & 1) * 8) = pk;
        }
    }

    bf16x8 vb[2][2];
#pragma unroll
    for (int nd = 0; nd < 2; ++nd)
#pragma unroll
        for (int kt = 0; kt < 2; ++kt)
            vb[nd][kt] = *reinterpret_cast<const bf16x8*>(
                VT + (size_t)(h * 32 + nd * 16 + c) * 32768 + win * 64 + kt * 32 + g * 8);
    f32x4 o[4][2];
#pragma unroll
    for (int mi = 0; mi < 4; ++mi)
#pragma unroll
        for (int nd = 0; nd < 2; ++nd) { o[mi][nd][0]=0.f; o[mi][nd][1]=0.f; o[mi][nd][2]=0.f; o[mi][nd][3]=0.f; }
#pragma unroll
    for (int mi = 0; mi < 4; ++mi) {
        const int i  = mi * 16 + c;
        const int ik = i & 7;
#pragma unroll
        for (int kt = 0; kt < 2; ++kt) {
            int chunk = (kt * 4 + g) ^ ik;
            bf16x8 pa = *reinterpret_cast<const bf16x8*>((char*)&Pl[w][0] + i * 128 + chunk * 16);
#pragma unroll
            for (int nd = 0; nd < 2; ++nd)
                o[mi][nd] = __builtin_amdgcn_mfma_f32_16x16x32_bf16(pa, vb[nd][kt], o[mi][nd], 0, 0, 0);
        }
    }

    unsigned short* aop = AO + qkbase;
#pragma unroll
    for (int mi = 0; mi < 4; ++mi)
#pragma unroll
        for (int nd = 0; nd < 2; ++nd)
#pragma unroll
            for (int jj = 0; jj < 4; ++jj)
                aop[(size_t)(mi * 16 + g * 4 + jj) * CC + nd * 16 + c] = f2bf(o[mi][nd][jj]);
}

// ---------------- weight fp32 -> bf16 conversion ----------------
__global__ void cvt_all(const float* s0, const float* s1, const float* s2, const float* s3,
                        const float* s4, const float* s5, const float* s6, const float* s7,
                        const float* s8, const float* s9, unsigned short* __restrict__ dst) {
    const float* srcs[10] = {s0, s1, s2, s3, s4, s5, s6, s7, s8, s9};
    int blk = blockIdx.x;
    int wi = (blk < 512) ? (blk >> 6) : (blk < 768 ? 8 : 9);
    size_t start = (wi < 8) ? (size_t)wi * 65536 : (wi == 8 ? (size_t)524288 : (size_t)786432);
    size_t gidx = (size_t)blk * 1024 + (size_t)threadIdx.x * 4;
    float4 v = *reinterpret_cast<const float4*>(srcs[wi] + (gidx - start));
    ushort4 o;
    o.x = f2bf(v.x); o.y = f2bf(v.y); o.z = f2bf(v.z); o.w = f2bf(v.w);
    *reinterpret_cast<ushort4*>(dst + gidx) = o;
}

extern "C" void kernel_launch(void* const* d_in, const int* in_sizes, int n_in,
                              void* d_out, int out_size, void* d_ws, size_t ws_size,
                              hipStream_t stream) {
    const float* x    = (const float*)d_in[0];
    const float* ctx  = (const float*)d_in[1];
    const float* ln1w = (const float*)d_in[2];
    const float* ln1b = (const float*)d_in[3];
    const float* ln2w = (const float*)d_in[4];
    const float* ln2b = (const float*)d_in[5];
    const float* ln3w = (const float*)d_in[6];
    const float* ln3b = (const float*)d_in[7];
    const float* lncw = (const float*)d_in[8];
    const float* lncb = (const float*)d_in[9];
    const float* saqw = (const float*)d_in[10];
    const float* saqb = (const float*)d_in[11];
    const float* sakw = (const float*)d_in[12];
    const float* sakb = (const float*)d_in[13];
    const float* savw = (const float*)d_in[14];
    const float* savb = (const float*)d_in[15];
    const float* saow = (const float*)d_in[16];
    const float* saob = (const float*)d_in[17];
    const float* sabias = (const float*)d_in[18];
    const float* caqw = (const float*)d_in[19];
    const float* caqb = (const float*)d_in[20];
    const float* cakw = (const float*)d_in[21];
    const float* cakb = (const float*)d_in[22];
    const float* cavw = (const float*)d_in[23];
    const float* cavb = (const float*)d_in[24];
    const float* caow = (const float*)d_in[25];
    const float* caob = (const float*)d_in[26];
    const float* cabias = (const float*)d_in[27];
    const float* gamma1 = (const float*)d_in[28];
    const float* gamma2 = (const float*)d_in[29];
    const float* gammam = (const float*)d_in[30];
    const float* mw1 = (const float*)d_in[31];
    const float* mb1 = (const float*)d_in[32];
    const float* mw2 = (const float*)d_in[33];
    const float* mb2 = (const float*)d_in[34];

    float* ws = (float*)d_ws;
    unsigned short* LNbf = (unsigned short*)(ws);                 // 3,686,400 f
    unsigned short* Gq   = (unsigned short*)(ws + 3686400);       // 4,194,304 f
    unsigned short* Gkv  = (unsigned short*)(ws + 7880704);       // 4,194,304 f
    unsigned short* Qbf  = (unsigned short*)(ws + 12075008);      // 4,194,304 f
    unsigned short* Kbf  = (unsigned short*)(ws + 16269312);      // 4,194,304 f
    unsigned short* VTbf = (unsigned short*)(ws + 20463616);      // 4,194,304 f
    float* X1  = ws + 28852224;                                   // 7,372,800 f
    unsigned short* Wp = (unsigned short*)(ws + 36225024);        // 524,288 f
    float* biasx = ws + 36749312;                                 // 32,768 f
    unsigned short* AObf = Gq;                                    // alias (gathered act dead after proj)
    unsigned short* H1bf = Qbf;                                   // alias (Q/K/VT dead in MLP phase)

    // cvt layout (contiguous): saq|sak|sav | sao | caq | cak|cav | cao | m1 | m2
    unsigned short* w_saqkv = Wp;                                 // [768][256]
    unsigned short* w_sao   = Wp + 196608;                        // [256][256]
    unsigned short* w_caq   = Wp + 262144;                        // [256][256]
    unsigned short* w_cakv  = Wp + 327680;                        // [512][256]
    unsigned short* w_cao   = Wp + 458752;                        // [256][256]
    unsigned short* w_m1    = Wp + 524288;                        // [1024][256]
    unsigned short* w_m2    = Wp + 786432;                        // [256][1024]

    float* OUT = (float*)d_out;

    dim3 blk(256);
    dim3 blk512(512);
    dim3 gLN(BN / 4);
    dim3 gGather(WROWS / 4);
    dim3 gAttn(WINS * 2);

    cvt_all<<<dim3(1024), blk, 0, stream>>>(saqw, sakw, savw, saow, caqw, cakw, cavw, caow, mw1, mw2, Wp);
    expand_bias<<<dim3(128), blk, 0, stream>>>(sabias, cabias, biasx);

    // ---- self attention ----
    ln_gather<<<gGather, blk, 0, stream>>>(x, ln1w, ln1b, Gq);
    gemm_wa<false,0><<<dim3(6, 256), blk512, 0, stream>>>(w_saqkv, Gq, saqb, sakb, savb, savb,
                                                          Qbf, Kbf, VTbf, VTbf, CC, 2, CC,
                                                          nullptr, nullptr, nullptr);
    attn_mfma<<<gAttn, blk, 0, stream>>>(Qbf, Kbf, VTbf, biasx, AObf);
    gemm_wa<false,1><<<dim3(2, 256), blk512, 0, stream>>>(w_sao, AObf, saob, saob, saob, saob,
                                                          Qbf, Qbf, Qbf, Qbf, CC, -1, CC,
                                                          x, gamma1, X1);
    // ---- cross attention ----
    ln_gather<<<gGather, blk, 0, stream>>>(X1, ln2w, ln2b, Gq);
    ln_gather<<<gGather, blk, 0, stream>>>(ctx, lncw, lncb, Gkv);
    gemm_wa<false,0><<<dim3(2, 256), blk512, 0, stream>>>(w_caq, Gq, caqb, caqb, caqb, caqb,
                                                          Qbf, Qbf, Qbf, Qbf, CC, -1, CC,
                                                          nullptr, nullptr, nullptr);
    gemm_wa<false,0><<<dim3(4, 256), blk512, 0, stream>>>(w_cakv, Gkv, cakb, cavb, cavb, cavb,
                                                          Kbf, VTbf, VTbf, VTbf, CC, 1, CC,
                                                          nullptr, nullptr, nullptr);
    attn_mfma<<<gAttn, blk, 0, stream>>>(Qbf, Kbf, VTbf, biasx + 16384, AObf);
    gemm_wa<false,1><<<dim3(2, 256), blk512, 0, stream>>>(w_cao, AObf, caob, caob, caob, caob,
                                                          Qbf, Qbf, Qbf, Qbf, CC, -1, CC,
                                                          X1, gamma2, X1);
    // ---- MLP ----
    ln_kernel<<<gLN, blk, 0, stream>>>(X1, ln3w, ln3b, LNbf, BN);
    gemm_wa<true,0><<<dim3(8, 225), blk512, 0, stream>>>(w_m1, LNbf, mb1, mb1 + 256, mb1 + 512, mb1 + 768,
                                                         H1bf, H1bf + 256, H1bf + 512, H1bf + 768,
                                                         HIDN, -1, CC, nullptr, nullptr, nullptr);
    gemm_wa<false,2><<<dim3(2, 225), blk512, 0, stream>>>(w_m2, H1bf, mb2, mb2, mb2, mb2,
                                                         Qbf, Qbf, Qbf, Qbf, CC, -1, HIDN,
                                                         X1, gammam, OUT);
}